// Round 1
// baseline (798.513 us; speedup 1.0000x reference)
//
#include <hip/hip_runtime.h>

#define TOKENS 22506
#define SLEN   11253

// ---------------------------------------------------------------------------
// Tiled f32 GEMM: C[M,N] = op(A)[M,K] @ W[N,K]^T + bias[N]
// op(A) = A (+ A2 if FUSE_ADD). Optional ReLU epilogue.
// Tile 64x64, BK=16, 256 threads, 4x4 microtile per thread.
// ---------------------------------------------------------------------------
template<bool FUSE_ADD, bool RELU>
__global__ __launch_bounds__(256) void gemm_bias(
    const float* __restrict__ A, const float* __restrict__ A2,
    const float* __restrict__ W, const float* __restrict__ bias,
    float* __restrict__ C, int M, int N, int K)
{
    __shared__ float As[16][64];
    __shared__ float Ws[16][64];
    const int tid = threadIdx.x;
    const int tx = tid & 15, ty = tid >> 4;
    const int m0 = blockIdx.x * 64;
    const int n0 = blockIdx.y * 64;
    const int sr = tid >> 2;          // 0..63 row within tile
    const int sc = (tid & 3) << 2;    // 0,4,8,12 k-offset

    float acc[4][4] = {};

    for (int k0 = 0; k0 < K; k0 += 16) {
        // global loads (issued before the barrier so they overlap the sync)
        float4 va = make_float4(0.f, 0.f, 0.f, 0.f);
        const int gm = m0 + sr;
        if (gm < M) {
            va = *reinterpret_cast<const float4*>(A + (size_t)gm * K + k0 + sc);
            if (FUSE_ADD) {
                float4 v2 = *reinterpret_cast<const float4*>(A2 + (size_t)gm * K + k0 + sc);
                va.x += v2.x; va.y += v2.y; va.z += v2.z; va.w += v2.w;
            }
        }
        const float4 vw = *reinterpret_cast<const float4*>(W + (size_t)(n0 + sr) * K + k0 + sc);

        __syncthreads();   // previous iteration's reads complete
        As[sc+0][sr] = va.x; As[sc+1][sr] = va.y; As[sc+2][sr] = va.z; As[sc+3][sr] = va.w;
        Ws[sc+0][sr] = vw.x; Ws[sc+1][sr] = vw.y; Ws[sc+2][sr] = vw.z; Ws[sc+3][sr] = vw.w;
        __syncthreads();

        #pragma unroll
        for (int kk = 0; kk < 16; ++kk) {
            const float4 a4 = *reinterpret_cast<const float4*>(&As[kk][ty << 2]);
            const float4 w4 = *reinterpret_cast<const float4*>(&Ws[kk][tx << 2]);
            const float av[4] = {a4.x, a4.y, a4.z, a4.w};
            const float wv[4] = {w4.x, w4.y, w4.z, w4.w};
            #pragma unroll
            for (int i = 0; i < 4; ++i)
                #pragma unroll
                for (int j = 0; j < 4; ++j)
                    acc[i][j] = fmaf(av[i], wv[j], acc[i][j]);
        }
    }

    #pragma unroll
    for (int i = 0; i < 4; ++i) {
        const int gm = m0 + (ty << 2) + i;
        if (gm >= M) break;
        float4 o;
        float* po = &o.x;
        #pragma unroll
        for (int j = 0; j < 4; ++j) {
            const int gn = n0 + (tx << 2) + j;
            float v = acc[i][j] + bias[gn];
            if (RELU) v = fmaxf(v, 0.f);
            po[j] = v;
        }
        *reinterpret_cast<float4*>(C + (size_t)gm * N + n0 + (tx << 2)) = o;
    }
}

// ---------------------------------------------------------------------------
// Box-attention sampling.
// Block = one token (256 threads = 8 heads x 32 dims).
// Each thread: softmax over its head's 16 logits (redundant across 32 lanes,
// cheap), then 4 levels x 4 points x 4 bilinear corners gathered from value.
// Corner gathers are coalesced 128B per 32-lane head group.
// ---------------------------------------------------------------------------
__global__ __launch_bounds__(256) void box_sample(
    const float* __restrict__ value,    // (B*S, 256) = (.., h*32+d)
    const float* __restrict__ off,      // (B*S, 128) = (.., h*16 + lvl*4 + k)
    const float* __restrict__ attnlog,  // (B*S, 128)
    const float* __restrict__ refw,     // (B*S, 4)
    const float* __restrict__ vratio,   // (B, 4, 2)
    float* __restrict__ outp)           // (B*S, 256)
{
    const int t = blockIdx.x;
    const int b = t / SLEN;
    const int h = threadIdx.x >> 5;
    const int d = threadIdx.x & 31;

    const float rcx = refw[t * 4 + 0], rcy = refw[t * 4 + 1];
    const float rww = refw[t * 4 + 2], rwh = refw[t * 4 + 3];

    // softmax over the 16 attention logits of this head
    const float* al = attnlog + (size_t)t * 128 + h * 16;
    float lo[16];
    float mx = -1e30f;
    #pragma unroll
    for (int i = 0; i < 16; ++i) { lo[i] = al[i]; mx = fmaxf(mx, lo[i]); }
    float ssum = 0.f;
    #pragma unroll
    for (int i = 0; i < 16; ++i) { lo[i] = __expf(lo[i] - mx); ssum += lo[i]; }
    const float inv = 1.f / ssum;

    const float* ofp = off + (size_t)t * 128 + h * 16;

    const int LH[4]  = {92, 46, 23, 12};
    const int LS0[4] = {0, 8464, 10580, 11109};

    float acc = 0.f;
    #pragma unroll
    for (int lvl = 0; lvl < 4; ++lvl) {
        const int Hh = LH[lvl], Ww = LH[lvl];
        const int s0 = LS0[lvl];
        const float vrx = vratio[(b * 4 + lvl) * 2 + 0];
        const float vry = vratio[(b * 4 + lvl) * 2 + 1];
        const float o0 = ofp[lvl * 4 + 0] * 0.125f;
        const float o1 = ofp[lvl * 4 + 1] * 0.125f;
        const float o2 = ofp[lvl * 4 + 2] * 0.125f;
        const float o3 = ofp[lvl * 4 + 3] * 0.125f;
        const float bx = rcx + o0 * rww;
        const float by = rcy + o1 * rwh;
        const float bw = fmaxf(rww + o2 * rww, 0.f);   // relu(size)
        const float bh = fmaxf(rwh + o3 * rwh, 0.f);
        const float* vbase = value + ((size_t)(b * SLEN + s0)) * 256 + h * 32 + d;

        #pragma unroll
        for (int p = 0; p < 4; ++p) {
            const float jx = (p & 1) ? 0.25f : -0.25f;
            const float iy = (p & 2) ? 0.25f : -0.25f;
            const float gx = (bx + jx * bw) * vrx;
            const float gy = (by + iy * bh) * vry;
            const float px = gx * (float)Ww - 0.5f;
            const float py = gy * (float)Hh - 0.5f;
            const float x0f = floorf(px), y0f = floorf(py);
            const int x0 = (int)x0f, y0 = (int)y0f;
            const float wx = px - x0f, wy = py - y0f;

            auto fetch = [&](int ix, int iyy) -> float {
                if (ix < 0 || ix >= Ww || iyy < 0 || iyy >= Hh) return 0.f;
                return vbase[(size_t)(iyy * Ww + ix) * 256];
            };
            const float s =
                fetch(x0,     y0    ) * (1.f - wx) * (1.f - wy) +
                fetch(x0 + 1, y0    ) * wx         * (1.f - wy) +
                fetch(x0,     y0 + 1) * (1.f - wx) * wy +
                fetch(x0 + 1, y0 + 1) * wx         * wy;
            acc += lo[lvl * 4 + p] * inv * s;
        }
    }
    outp[(size_t)t * 256 + threadIdx.x] = acc;
}

// ---------------------------------------------------------------------------
// out = LayerNorm(a + b) * w + bias   (row of 256, one block per row)
// ---------------------------------------------------------------------------
__global__ __launch_bounds__(256) void ln_add(
    const float* __restrict__ a, const float* __restrict__ b,
    const float* __restrict__ w, const float* __restrict__ bias,
    float* __restrict__ out)
{
    const int row = blockIdx.x;
    const int tid = threadIdx.x;
    const size_t idx = (size_t)row * 256 + tid;
    const float v = a[idx] + b[idx];

    __shared__ float redA[4], redB[4];
    float s = v;
    #pragma unroll
    for (int o = 32; o; o >>= 1) s += __shfl_xor(s, o);
    if ((tid & 63) == 0) redA[tid >> 6] = s;
    __syncthreads();
    const float mu = (redA[0] + redA[1] + redA[2] + redA[3]) * (1.f / 256.f);
    const float dv = v - mu;
    float s2 = dv * dv;
    #pragma unroll
    for (int o = 32; o; o >>= 1) s2 += __shfl_xor(s2, o);
    if ((tid & 63) == 0) redB[tid >> 6] = s2;
    __syncthreads();
    const float var = (redB[0] + redB[1] + redB[2] + redB[3]) * (1.f / 256.f);
    out[idx] = dv * rsqrtf(var + 1e-5f) * w[tid] + bias[tid];
}

// ---------------------------------------------------------------------------
extern "C" void kernel_launch(void* const* d_in, const int* in_sizes, int n_in,
                              void* d_out, int out_size, void* d_ws, size_t ws_size,
                              hipStream_t stream)
{
    const float* src     = (const float*)d_in[0];
    const float* pos     = (const float*)d_in[1];
    // d_in[2] src_shape, d_in[3] src_mask (all-false), d_in[4] src_start_index: constants baked in
    const float* vratio  = (const float*)d_in[5];
    const float* refw    = (const float*)d_in[6];
    const float* value_w = (const float*)d_in[7];
    const float* value_b = (const float*)d_in[8];
    const float* out_w   = (const float*)d_in[9];
    const float* out_b   = (const float*)d_in[10];
    const float* box_w   = (const float*)d_in[11];
    const float* box_b   = (const float*)d_in[12];
    const float* attn_w  = (const float*)d_in[13];
    const float* attn_b  = (const float*)d_in[14];
    const float* lin1_w  = (const float*)d_in[15];
    const float* lin1_b  = (const float*)d_in[16];
    const float* lin2_w  = (const float*)d_in[17];
    const float* lin2_b  = (const float*)d_in[18];
    const float* n1w     = (const float*)d_in[19];
    const float* n1b     = (const float*)d_in[20];
    const float* n2w     = (const float*)d_in[21];
    const float* n2b     = (const float*)d_in[22];

    // workspace layout (floats), with reuse:
    //   o0: attnout, later y          (5,761,536)
    //   o1: value                     (5,761,536)
    //   o2: off (2.88M)+attnlog(2.88M), later src2 (5,761,536 total)
    //   o4: x                         (5,761,536)
    //   o5: FFN hidden chunk          (CH*1024)
    const size_t NV = (size_t)TOKENS * 256;   // 5,761,536
    const size_t NH = (size_t)TOKENS * 128;   // 2,880,768
    float* ws = (float*)d_ws;
    float* attnout = ws;                 // o0 (also y later)
    float* valbuf  = ws + NV;            // o1
    float* offbuf  = ws + 2 * NV;        // o2
    float* attnbuf = offbuf + NH;        // o2 + NH
    float* src2    = offbuf;             // reuse o2 region after sampling
    float* xbuf    = ws + 3 * NV;        // o4
    float* hbuf    = ws + 4 * NV;        // o5
    float* ybuf    = attnout;            // reuse o0 after out-proj consumed it

    // FFN row-chunk sized to the workspace we actually have
    long cap = (long)(ws_size / 4) - (long)(4 * NV);
    long ch = cap / 1024;
    if (ch > TOKENS) ch = TOKENS;
    ch &= ~63L;
    if (ch < 64) ch = 64;
    const int CH = (int)ch;

    const dim3 blk(256);
    const int mt = (TOKENS + 63) / 64;

    // 1. value projection
    gemm_bias<false, false><<<dim3(mt, 4), blk, 0, stream>>>(
        src, nullptr, value_w, value_b, valbuf, TOKENS, 256, 256);
    // 2. box offsets from q = src + pos
    gemm_bias<true, false><<<dim3(mt, 2), blk, 0, stream>>>(
        src, pos, box_w, box_b, offbuf, TOKENS, 128, 256);
    // 3. attention logits from q
    gemm_bias<true, false><<<dim3(mt, 2), blk, 0, stream>>>(
        src, pos, attn_w, attn_b, attnbuf, TOKENS, 128, 256);
    // 4. box sampling
    box_sample<<<dim3(TOKENS), blk, 0, stream>>>(
        valbuf, offbuf, attnbuf, refw, vratio, attnout);
    // 5. output projection
    gemm_bias<false, false><<<dim3(mt, 4), blk, 0, stream>>>(
        attnout, nullptr, out_w, out_b, src2, TOKENS, 256, 256);
    // 6. x = LN1(src + src2)
    ln_add<<<dim3(TOKENS), blk, 0, stream>>>(src, src2, n1w, n1b, xbuf);
    // 7. FFN, chunked over rows
    for (int c0 = 0; c0 < TOKENS; c0 += CH) {
        const int rows = (TOKENS - c0 < CH) ? (TOKENS - c0) : CH;
        const int rmt = (rows + 63) / 64;
        gemm_bias<false, true><<<dim3(rmt, 16), blk, 0, stream>>>(
            xbuf + (size_t)c0 * 256, nullptr, lin1_w, lin1_b, hbuf, rows, 1024, 256);
        gemm_bias<false, false><<<dim3(rmt, 4), blk, 0, stream>>>(
            hbuf, nullptr, lin2_w, lin2_b, ybuf + (size_t)c0 * 256, rows, 256, 1024);
    }
    // 8. out = LN2(x + y)
    ln_add<<<dim3(TOKENS), blk, 0, stream>>>(xbuf, ybuf, n2w, n2b, (float*)d_out);
}

// Round 2
// 294.237 us; speedup vs baseline: 2.7138x; 2.7138x over previous
//
#include <hip/hip_runtime.h>
#include <hip/hip_bf16.h>

#define TOKENS 22506
#define SLEN   11253

typedef __bf16 bf16x8 __attribute__((ext_vector_type(8)));
typedef float  f32x4  __attribute__((ext_vector_type(4)));

__device__ __forceinline__ ushort f2bu(float f) {
    __hip_bfloat16 h = __float2bfloat16(f);   // RNE
    return *reinterpret_cast<ushort*>(&h);
}
__device__ __forceinline__ float bu2f(ushort u) {
    return __uint_as_float((uint)u << 16);
}

// ---------------------------------------------------------------------------
// MFMA bf16 GEMM: C[M,N] = op(A)[M,K] @ W[N,K]^T + bias[N]
// AMODE: 0 = A f32 (cvt in staging), 1 = (A+A2) f32, 2 = A bf16.
// Tile 128x128, BK=32, 256 threads = 4 waves (2x2), each wave 64x64 via
// 4x4 fragments of mfma_f32_16x16x32_bf16. LDS rows padded to 40 halves
// (80 B) -> 2-way bank aliasing only (free).
// ---------------------------------------------------------------------------
#define LDSP 40

template<int AMODE, bool RELU, bool OUTBF16>
__global__ __launch_bounds__(256) void mfma_gemm(
    const void* __restrict__ Aptr, const float* __restrict__ A2,
    const ushort* __restrict__ W, const float* __restrict__ bias,
    void* __restrict__ Cptr, int M, int N, int K)
{
    __shared__ ushort As[128 * LDSP];
    __shared__ ushort Bs[128 * LDSP];
    const int tid  = threadIdx.x;
    const int lane = tid & 63;
    const int wid  = tid >> 6;
    const int wr = wid >> 1, wc = wid & 1;
    const int m0 = blockIdx.x * 128, n0 = blockIdx.y * 128;
    const int lrow = lane & 15, lhi = lane >> 4;

    f32x4 acc[4][4] = {};

    const float*  Af = (const float*)Aptr;
    const ushort* Ab = (const ushort*)Aptr;

    for (int k0 = 0; k0 < K; k0 += 32) {
        // ---- issue global loads into regs (before barrier) ----
        float4 ra[4];
        uint4  rab[2];
        if (AMODE != 2) {
            #pragma unroll
            for (int i = 0; i < 4; ++i) {
                const int e = tid + i * 256;          // float4 slot
                const int row = e >> 3, c4 = (e & 7) << 2;
                const int gr = m0 + row;
                float4 v = make_float4(0.f, 0.f, 0.f, 0.f);
                if (gr < M) {
                    v = *reinterpret_cast<const float4*>(Af + (size_t)gr * K + k0 + c4);
                    if (AMODE == 1) {
                        const float4 v2 = *reinterpret_cast<const float4*>(A2 + (size_t)gr * K + k0 + c4);
                        v.x += v2.x; v.y += v2.y; v.z += v2.z; v.w += v2.w;
                    }
                }
                ra[i] = v;
            }
        } else {
            #pragma unroll
            for (int i = 0; i < 2; ++i) {
                const int e = tid + i * 256;          // 16B chunk slot
                const int row = e >> 2, ch = (e & 3) << 3;
                const int gr = m0 + row;
                uint4 v = make_uint4(0u, 0u, 0u, 0u);
                if (gr < M)
                    v = *reinterpret_cast<const uint4*>(Ab + (size_t)gr * K + k0 + ch);
                rab[i] = v;
            }
        }
        uint4 rb[2];
        #pragma unroll
        for (int i = 0; i < 2; ++i) {
            const int e = tid + i * 256;
            const int row = e >> 2, ch = (e & 3) << 3;
            rb[i] = *reinterpret_cast<const uint4*>(W + (size_t)(n0 + row) * K + k0 + ch);
        }

        __syncthreads();   // previous iteration's frag reads done

        if (AMODE != 2) {
            #pragma unroll
            for (int i = 0; i < 4; ++i) {
                const int e = tid + i * 256;
                const int row = e >> 3, c4 = (e & 7) << 2;
                ushort4 u;
                u.x = f2bu(ra[i].x); u.y = f2bu(ra[i].y);
                u.z = f2bu(ra[i].z); u.w = f2bu(ra[i].w);
                *reinterpret_cast<ushort4*>(&As[row * LDSP + c4]) = u;
            }
        } else {
            #pragma unroll
            for (int i = 0; i < 2; ++i) {
                const int e = tid + i * 256;
                const int row = e >> 2, ch = (e & 3) << 3;
                *reinterpret_cast<uint4*>(&As[row * LDSP + ch]) = rab[i];
            }
        }
        #pragma unroll
        for (int i = 0; i < 2; ++i) {
            const int e = tid + i * 256;
            const int row = e >> 2, ch = (e & 3) << 3;
            *reinterpret_cast<uint4*>(&Bs[row * LDSP + ch]) = rb[i];
        }

        __syncthreads();

        bf16x8 afr[4], bfr[4];
        #pragma unroll
        for (int m = 0; m < 4; ++m)
            afr[m] = *reinterpret_cast<const bf16x8*>(
                &As[(wr * 64 + m * 16 + lrow) * LDSP + lhi * 8]);
        #pragma unroll
        for (int n = 0; n < 4; ++n)
            bfr[n] = *reinterpret_cast<const bf16x8*>(
                &Bs[(wc * 64 + n * 16 + lrow) * LDSP + lhi * 8]);
        #pragma unroll
        for (int m = 0; m < 4; ++m)
            #pragma unroll
            for (int n = 0; n < 4; ++n)
                acc[m][n] = __builtin_amdgcn_mfma_f32_16x16x32_bf16(
                    afr[m], bfr[n], acc[m][n], 0, 0, 0);
    }

    // ---- epilogue ----
    #pragma unroll
    for (int m = 0; m < 4; ++m) {
        #pragma unroll
        for (int n = 0; n < 4; ++n) {
            const int gcol = n0 + wc * 64 + n * 16 + lrow;
            const float bv = bias[gcol];
            #pragma unroll
            for (int r = 0; r < 4; ++r) {
                const int grow = m0 + wr * 64 + m * 16 + lhi * 4 + r;
                if (grow < M) {
                    float v = acc[m][n][r] + bv;
                    if (RELU) v = fmaxf(v, 0.f);
                    if (OUTBF16)
                        ((ushort*)Cptr)[(size_t)grow * N + gcol] = f2bu(v);
                    else
                        ((float*)Cptr)[(size_t)grow * N + gcol] = v;
                }
            }
        }
    }
}

// ---------------------------------------------------------------------------
// Weight conversion f32 -> bf16 into one packed buffer + concatenated
// box/attn bias. Layout (ushort units):
//   [0,65536) value_w | [65536,131072) box_w(32768)+attn_w(32768)
//   [131072,196608) out_w | [196608,458752) lin1_w | [458752,720896) lin2_w
// ---------------------------------------------------------------------------
__global__ __launch_bounds__(256) void wconv(
    const float* __restrict__ vw, const float* __restrict__ bw,
    const float* __restrict__ aw, const float* __restrict__ ow,
    const float* __restrict__ l1, const float* __restrict__ l2,
    const float* __restrict__ bb, const float* __restrict__ ab,
    ushort* __restrict__ dstW, float* __restrict__ dstQB)
{
    const int i = blockIdx.x * 256 + threadIdx.x;
    if (i < 720896) {
        float v;
        if      (i <  65536) v = vw[i];
        else if (i <  98304) v = bw[i -  65536];
        else if (i < 131072) v = aw[i -  98304];
        else if (i < 196608) v = ow[i - 131072];
        else if (i < 458752) v = l1[i - 196608];
        else                 v = l2[i - 458752];
        dstW[i] = f2bu(v);
    } else if (i < 721152) {
        const int j = i - 720896;
        dstQB[j] = (j < 128) ? bb[j] : ab[j - 128];
    }
}

// ---------------------------------------------------------------------------
// Box prep: one thread per (token, head). Softmax over 16 logits, box &
// bilinear math once; emit per point: 4x int16 value-row idx + 4x bf16
// corner weights (softmax-premultiplied, zeroed if out of bounds).
// ---------------------------------------------------------------------------
__global__ __launch_bounds__(256) void box_prep(
    const ushort* __restrict__ qout,   // (t,256): [0,128)=off, [128,256)=logits
    const float* __restrict__ refw, const float* __restrict__ vratio,
    uint4* __restrict__ prep)          // (t*8+h, 16)
{
    const int gid = blockIdx.x * 256 + threadIdx.x;
    if (gid >= TOKENS * 8) return;
    const int t = gid >> 3, h = gid & 7;
    const int b = (t >= SLEN) ? 1 : 0;
    const ushort* qr = qout + (size_t)t * 256;

    float pr[16];
    float mx = -1e30f;
    #pragma unroll
    for (int i = 0; i < 16; ++i) { pr[i] = bu2f(qr[128 + h * 16 + i]); mx = fmaxf(mx, pr[i]); }
    float ss = 0.f;
    #pragma unroll
    for (int i = 0; i < 16; ++i) { pr[i] = __expf(pr[i] - mx); ss += pr[i]; }
    const float inv = 1.f / ss;

    const float rcx = refw[t * 4 + 0], rcy = refw[t * 4 + 1];
    const float rww = refw[t * 4 + 2], rwh = refw[t * 4 + 3];

    const int LH[4]  = {92, 46, 23, 12};
    const int LS0[4] = {0, 8464, 10580, 11109};
    uint4* op = prep + (size_t)gid * 16;

    #pragma unroll
    for (int lvl = 0; lvl < 4; ++lvl) {
        const int Ww = LH[lvl], Hh = LH[lvl], s0 = LS0[lvl];
        const float vrx = vratio[(b * 4 + lvl) * 2 + 0];
        const float vry = vratio[(b * 4 + lvl) * 2 + 1];
        const float o0 = bu2f(qr[h * 16 + lvl * 4 + 0]) * 0.125f;
        const float o1 = bu2f(qr[h * 16 + lvl * 4 + 1]) * 0.125f;
        const float o2 = bu2f(qr[h * 16 + lvl * 4 + 2]) * 0.125f;
        const float o3 = bu2f(qr[h * 16 + lvl * 4 + 3]) * 0.125f;
        const float bx = rcx + o0 * rww;
        const float by = rcy + o1 * rwh;
        const float bwd = fmaxf(rww + o2 * rww, 0.f);
        const float bhd = fmaxf(rwh + o3 * rwh, 0.f);

        #pragma unroll
        for (int p = 0; p < 4; ++p) {
            const float jx = (p & 1) ? 0.25f : -0.25f;
            const float iy = (p & 2) ? 0.25f : -0.25f;
            const float px = (bx + jx * bwd) * vrx * (float)Ww - 0.5f;
            const float py = (by + iy * bhd) * vry * (float)Hh - 0.5f;
            const float x0f = floorf(px), y0f = floorf(py);
            const int x0 = (int)x0f, y0 = (int)y0f;
            const float wx = px - x0f, wy = py - y0f;
            const float aw = pr[lvl * 4 + p] * inv;

            const bool vx0 = (x0 >= 0)     && (x0 < Ww);
            const bool vx1 = (x0 + 1 >= 0) && (x0 + 1 < Ww);
            const bool vy0 = (y0 >= 0)     && (y0 < Hh);
            const bool vy1 = (y0 + 1 >= 0) && (y0 + 1 < Hh);
            const int cx0 = min(max(x0, 0), Ww - 1);
            const int cx1 = min(max(x0 + 1, 0), Ww - 1);
            const int cy0 = min(max(y0, 0), Hh - 1);
            const int cy1 = min(max(y0 + 1, 0), Hh - 1);

            const float w00 = (vx0 && vy0) ? aw * (1.f - wx) * (1.f - wy) : 0.f;
            const float w01 = (vx1 && vy0) ? aw * wx         * (1.f - wy) : 0.f;
            const float w10 = (vx0 && vy1) ? aw * (1.f - wx) * wy         : 0.f;
            const float w11 = (vx1 && vy1) ? aw * wx         * wy         : 0.f;

            const uint i00 = (uint)(s0 + cy0 * Ww + cx0);
            const uint i01 = (uint)(s0 + cy0 * Ww + cx1);
            const uint i10 = (uint)(s0 + cy1 * Ww + cx0);
            const uint i11 = (uint)(s0 + cy1 * Ww + cx1);

            uint4 q;
            q.x = i00 | (i01 << 16);
            q.y = i10 | (i11 << 16);
            q.z = (uint)f2bu(w00) | ((uint)f2bu(w01) << 16);
            q.w = (uint)f2bu(w10) | ((uint)f2bu(w11) << 16);
            op[lvl * 4 + p] = q;
        }
    }
}

// ---------------------------------------------------------------------------
// Box sample: pure gather. Block = 2 tokens; thread = (token, head, dim-pair).
// Point data staged to LDS (broadcast reads). value is bf16.
// ---------------------------------------------------------------------------
__global__ __launch_bounds__(256) void box_sample2(
    const ushort* __restrict__ val, const uint4* __restrict__ prep,
    ushort* __restrict__ attnout)
{
    __shared__ uint4 pd[256];
    const int tid = threadIdx.x;
    const int t0 = blockIdx.x * 2;
    pd[tid] = prep[(size_t)t0 * 128 + tid];
    __syncthreads();

    const int tl = tid >> 7, h = (tid >> 4) & 7, dl = tid & 15;
    const int t = t0 + tl;
    const int b = (t >= SLEN) ? 1 : 0;
    const ushort* vb = val + (size_t)b * SLEN * 256 + h * 32 + dl * 2;
    const uint4* pp = &pd[(tl << 7) + (h << 4)];

    float a0 = 0.f, a1 = 0.f;
    #pragma unroll
    for (int p = 0; p < 16; ++p) {
        const uint4 q = pp[p];
        const int i0 = (int)(q.x & 0xFFFFu);
        const int i1 = (int)(q.x >> 16);
        const int i2 = (int)(q.y & 0xFFFFu);
        const int i3 = (int)(q.y >> 16);
        const float w0 = __uint_as_float(q.z << 16);
        const float w1 = __uint_as_float(q.z & 0xFFFF0000u);
        const float w2 = __uint_as_float(q.w << 16);
        const float w3 = __uint_as_float(q.w & 0xFFFF0000u);
        const uint v0 = *reinterpret_cast<const uint*>(vb + (size_t)i0 * 256);
        const uint v1 = *reinterpret_cast<const uint*>(vb + (size_t)i1 * 256);
        const uint v2 = *reinterpret_cast<const uint*>(vb + (size_t)i2 * 256);
        const uint v3 = *reinterpret_cast<const uint*>(vb + (size_t)i3 * 256);
        a0 = fmaf(w0, __uint_as_float(v0 << 16), a0);
        a1 = fmaf(w0, __uint_as_float(v0 & 0xFFFF0000u), a1);
        a0 = fmaf(w1, __uint_as_float(v1 << 16), a0);
        a1 = fmaf(w1, __uint_as_float(v1 & 0xFFFF0000u), a1);
        a0 = fmaf(w2, __uint_as_float(v2 << 16), a0);
        a1 = fmaf(w2, __uint_as_float(v2 & 0xFFFF0000u), a1);
        a0 = fmaf(w3, __uint_as_float(v3 << 16), a0);
        a1 = fmaf(w3, __uint_as_float(v3 & 0xFFFF0000u), a1);
    }
    const uint o = (uint)f2bu(a0) | ((uint)f2bu(a1) << 16);
    *reinterpret_cast<uint*>(attnout + (size_t)t * 256 + h * 32 + dl * 2) = o;
}

// ---------------------------------------------------------------------------
// out = LayerNorm(a + b) * w + bias ; b is f32 or bf16
// ---------------------------------------------------------------------------
template<bool BBF16>
__global__ __launch_bounds__(256) void ln_add(
    const float* __restrict__ a, const void* __restrict__ bptr,
    const float* __restrict__ w, const float* __restrict__ bias,
    float* __restrict__ out)
{
    const int row = blockIdx.x;
    const int tid = threadIdx.x;
    const size_t idx = (size_t)row * 256 + tid;
    const float bvv = BBF16 ? bu2f(((const ushort*)bptr)[idx])
                            : ((const float*)bptr)[idx];
    const float v = a[idx] + bvv;

    __shared__ float redA[4], redB[4];
    float s = v;
    #pragma unroll
    for (int o = 32; o; o >>= 1) s += __shfl_xor(s, o);
    if ((tid & 63) == 0) redA[tid >> 6] = s;
    __syncthreads();
    const float mu = (redA[0] + redA[1] + redA[2] + redA[3]) * (1.f / 256.f);
    const float dv = v - mu;
    float s2 = dv * dv;
    #pragma unroll
    for (int o = 32; o; o >>= 1) s2 += __shfl_xor(s2, o);
    if ((tid & 63) == 0) redB[tid >> 6] = s2;
    __syncthreads();
    const float var = (redB[0] + redB[1] + redB[2] + redB[3]) * (1.f / 256.f);
    out[idx] = dv * rsqrtf(var + 1e-5f) * w[tid] + bias[tid];
}

// ---------------------------------------------------------------------------
extern "C" void kernel_launch(void* const* d_in, const int* in_sizes, int n_in,
                              void* d_out, int out_size, void* d_ws, size_t ws_size,
                              hipStream_t stream)
{
    const float* src     = (const float*)d_in[0];
    const float* pos     = (const float*)d_in[1];
    const float* vratio  = (const float*)d_in[5];
    const float* refw    = (const float*)d_in[6];
    const float* value_w = (const float*)d_in[7];
    const float* value_b = (const float*)d_in[8];
    const float* out_w   = (const float*)d_in[9];
    const float* out_b   = (const float*)d_in[10];
    const float* box_w   = (const float*)d_in[11];
    const float* box_b   = (const float*)d_in[12];
    const float* attn_w  = (const float*)d_in[13];
    const float* attn_b  = (const float*)d_in[14];
    const float* lin1_w  = (const float*)d_in[15];
    const float* lin1_b  = (const float*)d_in[16];
    const float* lin2_w  = (const float*)d_in[17];
    const float* lin2_b  = (const float*)d_in[18];
    const float* n1w     = (const float*)d_in[19];
    const float* n1b     = (const float*)d_in[20];
    const float* n2w     = (const float*)d_in[21];
    const float* n2b     = (const float*)d_in[22];

    // workspace layout (byte offsets); peak 82,104,320 B
    char* wsb = (char*)d_ws;
    ushort* Wb    = (ushort*)wsb;                    // 720896 bf16 weights
    float*  qcb   = (float*)(wsb + 1441792);         // 256 f32 cat bias
    ushort* valb  = (ushort*)(wsb + 1442816);        // value bf16
    ushort* qoutb = (ushort*)(wsb + 12965888);       // off+logits bf16
    uint4*  prepb = (uint4*)(wsb + 24488960);        // 2.88M x 16B
    ushort* attb  = (ushort*)(wsb + 70581248);       // attn out bf16
    float*  src2  = (float*)(wsb + 24488960);        // reuse prep
    float*  xb    = (float*)(wsb + 47535104);        // reuse prep tail
    ushort* hb    = (ushort*)(wsb + 1442816);        // reuse val/qout/src2
    ushort* yb    = (ushort*)(wsb + 70581248);       // reuse attn out

    const dim3 blk(256);

    wconv<<<dim3(2817), blk, 0, stream>>>(
        value_w, box_w, attn_w, out_w, lin1_w, lin2_w, box_b, attn_b, Wb, qcb);

    // value = src @ value_w^T + b   -> bf16
    mfma_gemm<0, false, true><<<dim3(176, 2), blk, 0, stream>>>(
        src, nullptr, Wb, value_b, valb, TOKENS, 256, 256);
    // qout = (src+pos) @ [box_w;attn_w]^T + [box_b;attn_b] -> bf16
    mfma_gemm<1, false, true><<<dim3(176, 2), blk, 0, stream>>>(
        src, pos, Wb + 65536, qcb, qoutb, TOKENS, 256, 256);
    // per-(token,head) sampling prep
    box_prep<<<dim3((TOKENS * 8 + 255) / 256), blk, 0, stream>>>(
        qoutb, refw, vratio, prepb);
    // gather
    box_sample2<<<dim3(TOKENS / 2), blk, 0, stream>>>(valb, prepb, attb);
    // src2 = attnout @ out_w^T + b  -> f32
    mfma_gemm<2, false, false><<<dim3(176, 2), blk, 0, stream>>>(
        attb, nullptr, Wb + 131072, out_b, src2, TOKENS, 256, 256);
    // x = LN1(src + src2)
    ln_add<false><<<dim3(TOKENS), blk, 0, stream>>>(src, src2, n1w, n1b, xb);
    // h = relu(x @ lin1_w^T + b) -> bf16
    mfma_gemm<0, true, true><<<dim3(176, 8), blk, 0, stream>>>(
        xb, nullptr, Wb + 196608, lin1_b, hb, TOKENS, 1024, 256);
    // y = h @ lin2_w^T + b -> bf16
    mfma_gemm<2, false, true><<<dim3(176, 2), blk, 0, stream>>>(
        hb, nullptr, Wb + 458752, lin2_b, yb, TOKENS, 256, 1024);
    // out = LN2(x + y)
    ln_add<true><<<dim3(TOKENS), blk, 0, stream>>>(xb, yb, n2w, n2b, (float*)d_out);
}

// Round 3
// 269.706 us; speedup vs baseline: 2.9607x; 1.0910x over previous
//
#include <hip/hip_runtime.h>
#include <hip/hip_bf16.h>

#define TOKENS 22506
#define SLEN   11253

typedef __bf16 bf16x8 __attribute__((ext_vector_type(8)));
typedef float  f32x4  __attribute__((ext_vector_type(4)));

__device__ __forceinline__ ushort f2bu(float f) {
    __hip_bfloat16 h = __float2bfloat16(f);   // RNE
    return *reinterpret_cast<ushort*>(&h);
}
__device__ __forceinline__ float bu2f(ushort u) {
    return __uint_as_float((uint)u << 16);
}
__device__ __forceinline__ void gl16(const ushort* g, ushort* l) {
    __builtin_amdgcn_global_load_lds(
        (__attribute__((address_space(1))) void*)(g),
        (__attribute__((address_space(3))) void*)(l), 16, 0, 0);
}

// ---------------------------------------------------------------------------
// m97-structure MFMA GEMM: C[M,N] = A[M,K](bf16) @ W[N,K](bf16)^T + bias[N]
// 128x128 tile, BK=32, 256 thr = 4 waves (2x2), 4x4 frags of 16x16x32 bf16.
// All staging via global_load_lds width-16 (linear LDS [128][32], lane i of
// wave w writes LDS bytes w*1024 + i*16 — matches HW wave-uniform-base rule).
// ---------------------------------------------------------------------------
template<bool RELU, bool OUTBF16>
__global__ __launch_bounds__(256) void gemm_bf16(
    const ushort* __restrict__ A, const ushort* __restrict__ W,
    const float* __restrict__ bias, void* __restrict__ Cptr,
    int M, int N, int K)
{
    __shared__ ushort As[128 * 32];
    __shared__ ushort Bs[128 * 32];
    const int tid  = threadIdx.x;
    const int lane = tid & 63;
    const int wid  = tid >> 6;
    const int wr = wid >> 1, wc = wid & 1;
    const int m0 = blockIdx.x * 128, n0 = blockIdx.y * 128;
    const int lrow = lane & 15, lhi = lane >> 4;

    const int srow = tid >> 2;          // 0..63
    const int scol = (tid & 3) << 3;    // 0,8,16,24 (bf16 units; 16B chunk)

    const ushort* ga0 = A + (size_t)min(m0 + srow,      M - 1) * K + scol;
    const ushort* ga1 = A + (size_t)min(m0 + srow + 64, M - 1) * K + scol;
    const ushort* gb0 = W + (size_t)(n0 + srow)      * K + scol;
    const ushort* gb1 = W + (size_t)(n0 + srow + 64) * K + scol;
    ushort* la0 = &As[(srow     ) * 32 + scol];
    ushort* la1 = &As[(srow + 64) * 32 + scol];
    ushort* lb0 = &Bs[(srow     ) * 32 + scol];
    ushort* lb1 = &Bs[(srow + 64) * 32 + scol];

    f32x4 acc[4][4] = {};

    for (int k0 = 0; k0 < K; k0 += 32) {
        gl16(ga0 + k0, la0);
        gl16(ga1 + k0, la1);
        gl16(gb0 + k0, lb0);
        gl16(gb1 + k0, lb1);
        __syncthreads();                 // drains vmcnt, LDS visible

        bf16x8 afr[4], bfr[4];
        #pragma unroll
        for (int m = 0; m < 4; ++m)
            afr[m] = *reinterpret_cast<const bf16x8*>(
                &As[(wr * 64 + m * 16 + lrow) * 32 + lhi * 8]);
        #pragma unroll
        for (int n = 0; n < 4; ++n)
            bfr[n] = *reinterpret_cast<const bf16x8*>(
                &Bs[(wc * 64 + n * 16 + lrow) * 32 + lhi * 8]);
        #pragma unroll
        for (int m = 0; m < 4; ++m)
            #pragma unroll
            for (int n = 0; n < 4; ++n)
                acc[m][n] = __builtin_amdgcn_mfma_f32_16x16x32_bf16(
                    afr[m], bfr[n], acc[m][n], 0, 0, 0);
        __syncthreads();                 // before next stage overwrites
    }

    #pragma unroll
    for (int m = 0; m < 4; ++m) {
        #pragma unroll
        for (int n = 0; n < 4; ++n) {
            const int gcol = n0 + wc * 64 + n * 16 + lrow;
            const float bv = bias[gcol];
            #pragma unroll
            for (int r = 0; r < 4; ++r) {
                const int grow = m0 + wr * 64 + m * 16 + lhi * 4 + r;
                if (grow < M) {
                    float v = acc[m][n][r] + bv;
                    if (RELU) v = fmaxf(v, 0.f);
                    if (OUTBF16)
                        ((ushort*)Cptr)[(size_t)grow * N + gcol] = f2bu(v);
                    else
                        ((float*)Cptr)[(size_t)grow * N + gcol] = v;
                }
            }
        }
    }
}

// ---------------------------------------------------------------------------
// Input conversion: srcb = bf16(src), qb = bf16(src+pos). 4 elems/thread.
// ---------------------------------------------------------------------------
__global__ __launch_bounds__(256) void conv_inputs(
    const float4* __restrict__ src, const float4* __restrict__ pos,
    ushort4* __restrict__ srcb, ushort4* __restrict__ qb, int n4)
{
    const int i = blockIdx.x * 256 + threadIdx.x;
    if (i >= n4) return;
    const float4 s = src[i], p = pos[i];
    ushort4 us, uq;
    us.x = f2bu(s.x); us.y = f2bu(s.y); us.z = f2bu(s.z); us.w = f2bu(s.w);
    uq.x = f2bu(s.x + p.x); uq.y = f2bu(s.y + p.y);
    uq.z = f2bu(s.z + p.z); uq.w = f2bu(s.w + p.w);
    srcb[i] = us; qb[i] = uq;
}

// ---------------------------------------------------------------------------
// Weight conversion f32 -> bf16 packed + concatenated box/attn bias.
//   [0,65536) value_w | [65536,131072) box_w+attn_w | [131072,196608) out_w
//   [196608,458752) lin1_w | [458752,720896) lin2_w
// ---------------------------------------------------------------------------
__global__ __launch_bounds__(256) void wconv(
    const float* __restrict__ vw, const float* __restrict__ bw,
    const float* __restrict__ aw, const float* __restrict__ ow,
    const float* __restrict__ l1, const float* __restrict__ l2,
    const float* __restrict__ bb, const float* __restrict__ ab,
    ushort* __restrict__ dstW, float* __restrict__ dstQB)
{
    const int i = blockIdx.x * 256 + threadIdx.x;
    if (i < 720896) {
        float v;
        if      (i <  65536) v = vw[i];
        else if (i <  98304) v = bw[i -  65536];
        else if (i < 131072) v = aw[i -  98304];
        else if (i < 196608) v = ow[i - 131072];
        else if (i < 458752) v = l1[i - 196608];
        else                 v = l2[i - 458752];
        dstW[i] = f2bu(v);
    } else if (i < 721152) {
        const int j = i - 720896;
        dstQB[j] = (j < 128) ? bb[j] : ab[j - 128];
    }
}

// ---------------------------------------------------------------------------
// Box prep (one token-chunk): thread = (token, head). Softmax + box/bilinear
// math once; emit per point: 4x u16 value-row idx + 4x bf16 premult weights.
// ---------------------------------------------------------------------------
__global__ __launch_bounds__(256) void box_prep(
    const ushort* __restrict__ qout,   // chunk base: (t,256) off|logits
    const float* __restrict__ refw,    // chunk base: (t,4)
    const float* __restrict__ vr,      // this batch: (4,2)
    uint4* __restrict__ prep, int ntok)
{
    const int gid = blockIdx.x * 256 + threadIdx.x;
    if (gid >= ntok * 8) return;
    const int t = gid >> 3, h = gid & 7;
    const ushort* qr = qout + (size_t)t * 256;

    float pr[16];
    float mx = -1e30f;
    #pragma unroll
    for (int i = 0; i < 16; ++i) { pr[i] = bu2f(qr[128 + h * 16 + i]); mx = fmaxf(mx, pr[i]); }
    float ss = 0.f;
    #pragma unroll
    for (int i = 0; i < 16; ++i) { pr[i] = __expf(pr[i] - mx); ss += pr[i]; }
    const float inv = 1.f / ss;

    const float rcx = refw[t * 4 + 0], rcy = refw[t * 4 + 1];
    const float rww = refw[t * 4 + 2], rwh = refw[t * 4 + 3];

    const int LH[4]  = {92, 46, 23, 12};
    const int LS0[4] = {0, 8464, 10580, 11109};
    uint4* op = prep + (size_t)gid * 16;

    #pragma unroll
    for (int lvl = 0; lvl < 4; ++lvl) {
        const int Ww = LH[lvl], Hh = LH[lvl], s0 = LS0[lvl];
        const float vrx = vr[lvl * 2 + 0];
        const float vry = vr[lvl * 2 + 1];
        const float o0 = bu2f(qr[h * 16 + lvl * 4 + 0]) * 0.125f;
        const float o1 = bu2f(qr[h * 16 + lvl * 4 + 1]) * 0.125f;
        const float o2 = bu2f(qr[h * 16 + lvl * 4 + 2]) * 0.125f;
        const float o3 = bu2f(qr[h * 16 + lvl * 4 + 3]) * 0.125f;
        const float bx = rcx + o0 * rww;
        const float by = rcy + o1 * rwh;
        const float bwd = fmaxf(rww + o2 * rww, 0.f);
        const float bhd = fmaxf(rwh + o3 * rwh, 0.f);

        #pragma unroll
        for (int p = 0; p < 4; ++p) {
            const float jx = (p & 1) ? 0.25f : -0.25f;
            const float iy = (p & 2) ? 0.25f : -0.25f;
            const float px = (bx + jx * bwd) * vrx * (float)Ww - 0.5f;
            const float py = (by + iy * bhd) * vry * (float)Hh - 0.5f;
            const float x0f = floorf(px), y0f = floorf(py);
            const int x0 = (int)x0f, y0 = (int)y0f;
            const float wx = px - x0f, wy = py - y0f;
            const float aw = pr[lvl * 4 + p] * inv;

            const bool vx0 = (x0 >= 0)     && (x0 < Ww);
            const bool vx1 = (x0 + 1 >= 0) && (x0 + 1 < Ww);
            const bool vy0 = (y0 >= 0)     && (y0 < Hh);
            const bool vy1 = (y0 + 1 >= 0) && (y0 + 1 < Hh);
            const int cx0 = min(max(x0, 0), Ww - 1);
            const int cx1 = min(max(x0 + 1, 0), Ww - 1);
            const int cy0 = min(max(y0, 0), Hh - 1);
            const int cy1 = min(max(y0 + 1, 0), Hh - 1);

            const float w00 = (vx0 && vy0) ? aw * (1.f - wx) * (1.f - wy) : 0.f;
            const float w01 = (vx1 && vy0) ? aw * wx         * (1.f - wy) : 0.f;
            const float w10 = (vx0 && vy1) ? aw * (1.f - wx) * wy         : 0.f;
            const float w11 = (vx1 && vy1) ? aw * wx         * wy         : 0.f;

            uint4 q;
            q.x = (uint)(s0 + cy0 * Ww + cx0) | ((uint)(s0 + cy0 * Ww + cx1) << 16);
            q.y = (uint)(s0 + cy1 * Ww + cx0) | ((uint)(s0 + cy1 * Ww + cx1) << 16);
            q.z = (uint)f2bu(w00) | ((uint)f2bu(w01) << 16);
            q.w = (uint)f2bu(w10) | ((uint)f2bu(w11) << 16);
            op[lvl * 4 + p] = q;
        }
    }
}

// ---------------------------------------------------------------------------
// Box sample (one token-chunk): pure gather. Block = 2 tokens.
// ---------------------------------------------------------------------------
__global__ __launch_bounds__(256) void box_sample2(
    const ushort* __restrict__ val,    // this batch: (SLEN,256)
    const uint4* __restrict__ prep, ushort* __restrict__ attnout, int ntok)
{
    __shared__ uint4 pd[256];
    const int tid = threadIdx.x;
    const int t0 = blockIdx.x * 2;
    const int pidx = min(t0 * 128 + tid, ntok * 128 - 1);
    pd[tid] = prep[pidx];
    __syncthreads();

    const int tl = tid >> 7, h = (tid >> 4) & 7, dl = tid & 15;
    const int t = t0 + tl;
    if (t >= ntok) return;
    const ushort* vb = val + h * 32 + dl * 2;
    const uint4* pp = &pd[(tl << 7) + (h << 4)];

    float a0 = 0.f, a1 = 0.f;
    #pragma unroll
    for (int p = 0; p < 16; ++p) {
        const uint4 q = pp[p];
        const int i0 = (int)(q.x & 0xFFFFu);
        const int i1 = (int)(q.x >> 16);
        const int i2 = (int)(q.y & 0xFFFFu);
        const int i3 = (int)(q.y >> 16);
        const float w0 = __uint_as_float(q.z << 16);
        const float w1 = __uint_as_float(q.z & 0xFFFF0000u);
        const float w2 = __uint_as_float(q.w << 16);
        const float w3 = __uint_as_float(q.w & 0xFFFF0000u);
        const uint v0 = *reinterpret_cast<const uint*>(vb + (size_t)i0 * 256);
        const uint v1 = *reinterpret_cast<const uint*>(vb + (size_t)i1 * 256);
        const uint v2 = *reinterpret_cast<const uint*>(vb + (size_t)i2 * 256);
        const uint v3 = *reinterpret_cast<const uint*>(vb + (size_t)i3 * 256);
        a0 = fmaf(w0, __uint_as_float(v0 << 16), a0);
        a1 = fmaf(w0, __uint_as_float(v0 & 0xFFFF0000u), a1);
        a0 = fmaf(w1, __uint_as_float(v1 << 16), a0);
        a1 = fmaf(w1, __uint_as_float(v1 & 0xFFFF0000u), a1);
        a0 = fmaf(w2, __uint_as_float(v2 << 16), a0);
        a1 = fmaf(w2, __uint_as_float(v2 & 0xFFFF0000u), a1);
        a0 = fmaf(w3, __uint_as_float(v3 << 16), a0);
        a1 = fmaf(w3, __uint_as_float(v3 & 0xFFFF0000u), a1);
    }
    const uint o = (uint)f2bu(a0) | ((uint)f2bu(a1) << 16);
    *reinterpret_cast<uint*>(attnout + (size_t)t * 256 + h * 32 + dl * 2) = o;
}

// ---------------------------------------------------------------------------
// out = LayerNorm(a + b) * w + bias ; optional extra bf16 output copy
// ---------------------------------------------------------------------------
template<bool BBF16, bool WBF16>
__global__ __launch_bounds__(256) void ln_add(
    const float* __restrict__ a, const void* __restrict__ bptr,
    const float* __restrict__ w, const float* __restrict__ bias,
    float* __restrict__ out, ushort* __restrict__ outb)
{
    const int row = blockIdx.x;
    const int tid = threadIdx.x;
    const size_t idx = (size_t)row * 256 + tid;
    const float bvv = BBF16 ? bu2f(((const ushort*)bptr)[idx])
                            : ((const float*)bptr)[idx];
    const float v = a[idx] + bvv;

    __shared__ float redA[4], redB[4];
    float s = v;
    #pragma unroll
    for (int o = 32; o; o >>= 1) s += __shfl_xor(s, o);
    if ((tid & 63) == 0) redA[tid >> 6] = s;
    __syncthreads();
    const float mu = (redA[0] + redA[1] + redA[2] + redA[3]) * (1.f / 256.f);
    const float dv = v - mu;
    float s2 = dv * dv;
    #pragma unroll
    for (int o = 32; o; o >>= 1) s2 += __shfl_xor(s2, o);
    if ((tid & 63) == 0) redB[tid >> 6] = s2;
    __syncthreads();
    const float var = (redB[0] + redB[1] + redB[2] + redB[3]) * (1.f / 256.f);
    const float r = dv * rsqrtf(var + 1e-5f) * w[tid] + bias[tid];
    out[idx] = r;
    if (WBF16) outb[idx] = f2bu(r);
}

// ---------------------------------------------------------------------------
extern "C" void kernel_launch(void* const* d_in, const int* in_sizes, int n_in,
                              void* d_out, int out_size, void* d_ws, size_t ws_size,
                              hipStream_t stream)
{
    const float* src     = (const float*)d_in[0];
    const float* pos     = (const float*)d_in[1];
    const float* vratio  = (const float*)d_in[5];
    const float* refw    = (const float*)d_in[6];
    const float* value_w = (const float*)d_in[7];
    const float* value_b = (const float*)d_in[8];
    const float* out_w   = (const float*)d_in[9];
    const float* out_b   = (const float*)d_in[10];
    const float* box_w   = (const float*)d_in[11];
    const float* box_b   = (const float*)d_in[12];
    const float* attn_w  = (const float*)d_in[13];
    const float* attn_b  = (const float*)d_in[14];
    const float* lin1_w  = (const float*)d_in[15];
    const float* lin1_b  = (const float*)d_in[16];
    const float* lin2_w  = (const float*)d_in[17];
    const float* lin2_b  = (const float*)d_in[18];
    const float* n1w     = (const float*)d_in[19];
    const float* n1b     = (const float*)d_in[20];
    const float* n2w     = (const float*)d_in[21];
    const float* n2b     = (const float*)d_in[22];

    // workspace (peak 82,104,320 B, same as proven round-2 footprint)
    char* wsb = (char*)d_ws;
    ushort* Wb    = (ushort*)wsb;                    // 1,441,792 B weights
    float*  qcb   = (float*)(wsb + 1441792);         // 1 KB cat bias
    ushort* srcb  = (ushort*)(wsb + 1442816);        // bf16 src
    ushort* qb    = (ushort*)(wsb + 12965888);       // bf16 src+pos
    ushort* valb  = (ushort*)(wsb + 24488960);       // value bf16
    ushort* qoutb = (ushort*)(wsb + 36012032);       // off+logits bf16
    uint4*  prepb = (uint4*)(wsb + 47535104);        // 23 MB (per chunk)
    ushort* attb  = (ushort*)(wsb + 70581248);       // attn out bf16
    float*  src2  = (float*)(wsb + 1442816);         // reuse srcb+qb
    float*  xb    = (float*)(wsb + 36012032);        // reuse qoutb+prep head
    ushort* xbb   = (ushort*)(wsb + 24488960);       // reuse valb
    ushort* hb    = (ushort*)(wsb + 59058176);       // reuse prep tail+attb
    ushort* yb    = (ushort*)(wsb + 1442816);        // reuse src2

    const dim3 blk(256);

    wconv<<<dim3(2817), blk, 0, stream>>>(
        value_w, box_w, attn_w, out_w, lin1_w, lin2_w, box_b, attn_b, Wb, qcb);
    conv_inputs<<<dim3((TOKENS * 64 + 255) / 256), blk, 0, stream>>>(
        (const float4*)src, (const float4*)pos, (ushort4*)srcb, (ushort4*)qb,
        TOKENS * 64);

    // value = src @ value_w^T + b -> bf16
    gemm_bf16<false, true><<<dim3(176, 2), blk, 0, stream>>>(
        srcb, Wb, value_b, valb, TOKENS, 256, 256);
    // qout = q @ [box_w;attn_w]^T + [box_b;attn_b] -> bf16
    gemm_bf16<false, true><<<dim3(176, 2), blk, 0, stream>>>(
        qb, Wb + 65536, qcb, qoutb, TOKENS, 256, 256);

    // sampling, 2 token-chunks (prep buffer reused)
    for (int c = 0; c < 2; ++c) {
        const size_t t0 = (size_t)c * SLEN;
        box_prep<<<dim3((SLEN * 8 + 255) / 256), blk, 0, stream>>>(
            qoutb + t0 * 256, refw + t0 * 4, vratio + c * 8, prepb, SLEN);
        box_sample2<<<dim3((SLEN + 1) / 2), blk, 0, stream>>>(
            valb + t0 * 256, prepb, attb + t0 * 256, SLEN);
    }

    // src2 = attnout @ out_w^T + b -> f32
    gemm_bf16<false, false><<<dim3(176, 2), blk, 0, stream>>>(
        attb, Wb + 131072, out_b, src2, TOKENS, 256, 256);
    // x = LN1(src + src2) -> f32 + bf16
    ln_add<false, true><<<dim3(TOKENS), blk, 0, stream>>>(
        src, src2, n1w, n1b, xb, xbb);
    // FFN, 2 row-chunks (hidden buffer reused)
    for (int c = 0; c < 2; ++c) {
        const size_t r0 = (size_t)c * SLEN;
        gemm_bf16<true, true><<<dim3(88, 8), blk, 0, stream>>>(
            xbb + r0 * 256, Wb + 196608, lin1_b, hb, SLEN, 1024, 256);
        gemm_bf16<false, true><<<dim3(88, 2), blk, 0, stream>>>(
            hb, Wb + 458752, lin2_b, yb + r0 * 256, SLEN, 256, 1024);
    }
    // out = LN2(x + y)
    ln_add<true, false><<<dim3(TOKENS), blk, 0, stream>>>(
        xb, yb, n2w, n2b, (float*)d_out, nullptr);
}

// Round 4
// 218.599 us; speedup vs baseline: 3.6529x; 1.2338x over previous
//
#include <hip/hip_runtime.h>
#include <hip/hip_bf16.h>

#define TOKENS 22506
#define SLEN   11253

typedef __bf16 bf16x8 __attribute__((ext_vector_type(8)));
typedef float  f32x4  __attribute__((ext_vector_type(4)));

__device__ __forceinline__ ushort f2bu(float f) {
    __hip_bfloat16 h = __float2bfloat16(f);   // RNE
    return *reinterpret_cast<ushort*>(&h);
}
__device__ __forceinline__ float bu2f(ushort u) {
    return __uint_as_float((uint)u << 16);
}
__device__ __forceinline__ void gl16(const ushort* g, ushort* l) {
    __builtin_amdgcn_global_load_lds(
        (__attribute__((address_space(1))) void*)(g),
        (__attribute__((address_space(3))) void*)(l), 16, 0, 0);
}

// ---------------------------------------------------------------------------
// m97-structure MFMA GEMM + double-buffered LDS (2-phase pipeline).
// C[M,N] = A[M,K](bf16) @ W[N,K](bf16)^T + bias[N]
// 128x128 tile, BK=32, 256 thr = 4 waves (2x2), 4x4 frags of 16x16x32 bf16.
// Staging via global_load_lds width-16 into linear LDS [128][32] (lane i of
// wave w writes bytes w*1024 + i*16 — matches wave-uniform-base rule).
// Per iter: 1 barrier; stage(next) issued before ds_read+MFMA(cur) so HBM/L2
// latency overlaps compute. blockIdx.z selects source set (merged launches).
// ---------------------------------------------------------------------------
template<bool RELU, bool OUTBF16>
__global__ __launch_bounds__(256) void gemm_bf16(
    const ushort* __restrict__ A0, const ushort* __restrict__ W0,
    const float* __restrict__ b0, void* __restrict__ C0,
    const ushort* __restrict__ A1, const ushort* __restrict__ W1,
    const float* __restrict__ b1, void* __restrict__ C1,
    int M, int N, int K)
{
    const bool zz = blockIdx.z != 0;
    const ushort* A   = zz ? A1 : A0;
    const ushort* W   = zz ? W1 : W0;
    const float* bias = zz ? b1 : b0;
    void* Cptr        = zz ? C1 : C0;

    __shared__ ushort As[2][128 * 32];
    __shared__ ushort Bs[2][128 * 32];
    const int tid  = threadIdx.x;
    const int lane = tid & 63;
    const int wid  = tid >> 6;
    const int wr = wid >> 1, wc = wid & 1;
    const int m0 = blockIdx.x * 128, n0 = blockIdx.y * 128;
    const int lrow = lane & 15, lhi = lane >> 4;

    const int srow = tid >> 2;          // 0..63
    const int scol = (tid & 3) << 3;    // 0,8,16,24 (bf16 units; 16B chunk)
    const int lo   = srow * 32 + scol;

    const ushort* ga0 = A + (size_t)min(m0 + srow,      M - 1) * K + scol;
    const ushort* ga1 = A + (size_t)min(m0 + srow + 64, M - 1) * K + scol;
    const ushort* gb0 = W + (size_t)(n0 + srow)      * K + scol;
    const ushort* gb1 = W + (size_t)(n0 + srow + 64) * K + scol;

    f32x4 acc[4][4] = {};
    const int NT = K >> 5;

    // prologue: stage tile 0 into buffer 0
    gl16(ga0, &As[0][lo]);
    gl16(ga1, &As[0][lo + 64 * 32]);
    gl16(gb0, &Bs[0][lo]);
    gl16(gb1, &Bs[0][lo + 64 * 32]);

    int cur = 0;
    for (int t = 0; t < NT; ++t) {
        __syncthreads();   // drains vmcnt: buf[cur] ready; prev reads of buf[cur^1] done
        if (t + 1 < NT) {
            const int k0 = (t + 1) << 5;
            const int nb = cur ^ 1;
            gl16(ga0 + k0, &As[nb][lo]);
            gl16(ga1 + k0, &As[nb][lo + 64 * 32]);
            gl16(gb0 + k0, &Bs[nb][lo]);
            gl16(gb1 + k0, &Bs[nb][lo + 64 * 32]);
        }
        bf16x8 afr[4], bfr[4];
        #pragma unroll
        for (int m = 0; m < 4; ++m)
            afr[m] = *reinterpret_cast<const bf16x8*>(
                &As[cur][(wr * 64 + m * 16 + lrow) * 32 + lhi * 8]);
        #pragma unroll
        for (int n = 0; n < 4; ++n)
            bfr[n] = *reinterpret_cast<const bf16x8*>(
                &Bs[cur][(wc * 64 + n * 16 + lrow) * 32 + lhi * 8]);
        #pragma unroll
        for (int m = 0; m < 4; ++m)
            #pragma unroll
            for (int n = 0; n < 4; ++n)
                acc[m][n] = __builtin_amdgcn_mfma_f32_16x16x32_bf16(
                    afr[m], bfr[n], acc[m][n], 0, 0, 0);
        cur ^= 1;
    }

    #pragma unroll
    for (int m = 0; m < 4; ++m) {
        #pragma unroll
        for (int n = 0; n < 4; ++n) {
            const int gcol = n0 + wc * 64 + n * 16 + lrow;
            const float bv = bias[gcol];
            #pragma unroll
            for (int r = 0; r < 4; ++r) {
                const int grow = m0 + wr * 64 + m * 16 + lhi * 4 + r;
                if (grow < M) {
                    float v = acc[m][n][r] + bv;
                    if (RELU) v = fmaxf(v, 0.f);
                    if (OUTBF16)
                        ((ushort*)Cptr)[(size_t)grow * N + gcol] = f2bu(v);
                    else
                        ((float*)Cptr)[(size_t)grow * N + gcol] = v;
                }
            }
        }
    }
}

// ---------------------------------------------------------------------------
// Input conversion: srcb = bf16(src), qb = bf16(src+pos). 4 elems/thread.
// ---------------------------------------------------------------------------
__global__ __launch_bounds__(256) void conv_inputs(
    const float4* __restrict__ src, const float4* __restrict__ pos,
    ushort4* __restrict__ srcb, ushort4* __restrict__ qb, int n4)
{
    const int i = blockIdx.x * 256 + threadIdx.x;
    if (i >= n4) return;
    const float4 s = src[i], p = pos[i];
    ushort4 us, uq;
    us.x = f2bu(s.x); us.y = f2bu(s.y); us.z = f2bu(s.z); us.w = f2bu(s.w);
    uq.x = f2bu(s.x + p.x); uq.y = f2bu(s.y + p.y);
    uq.z = f2bu(s.z + p.z); uq.w = f2bu(s.w + p.w);
    srcb[i] = us; qb[i] = uq;
}

// ---------------------------------------------------------------------------
// Weight conversion f32 -> bf16 packed + concatenated box/attn bias.
//   [0,65536) value_w | [65536,131072) box_w+attn_w | [131072,196608) out_w
//   [196608,458752) lin1_w | [458752,720896) lin2_w
// ---------------------------------------------------------------------------
__global__ __launch_bounds__(256) void wconv(
    const float* __restrict__ vw, const float* __restrict__ bw,
    const float* __restrict__ aw, const float* __restrict__ ow,
    const float* __restrict__ l1, const float* __restrict__ l2,
    const float* __restrict__ bb, const float* __restrict__ ab,
    ushort* __restrict__ dstW, float* __restrict__ dstQB)
{
    const int i = blockIdx.x * 256 + threadIdx.x;
    if (i < 720896) {
        float v;
        if      (i <  65536) v = vw[i];
        else if (i <  98304) v = bw[i -  65536];
        else if (i < 131072) v = aw[i -  98304];
        else if (i < 196608) v = ow[i - 131072];
        else if (i < 458752) v = l1[i - 196608];
        else                 v = l2[i - 458752];
        dstW[i] = f2bu(v);
    } else if (i < 721152) {
        const int j = i - 720896;
        dstQB[j] = (j < 128) ? bb[j] : ab[j - 128];
    }
}

// ---------------------------------------------------------------------------
// Box prep: thread = (token, head). Softmax + box/bilinear math once; emit
// per point: 4x u16 value-row idx + 4x bf16 softmax-premultiplied weights.
// ---------------------------------------------------------------------------
__global__ __launch_bounds__(256) void box_prep(
    const ushort* __restrict__ qout,   // (t,256): off | logits
    const float* __restrict__ refw,    // (t,4)
    const float* __restrict__ vratio,  // (B,4,2)
    uint4* __restrict__ prep)
{
    const int gid = blockIdx.x * 256 + threadIdx.x;
    if (gid >= TOKENS * 8) return;
    const int t = gid >> 3, h = gid & 7;
    const int b = (t >= SLEN) ? 1 : 0;
    const ushort* qr = qout + (size_t)t * 256;
    const float* vr = vratio + b * 8;

    float pr[16];
    float mx = -1e30f;
    #pragma unroll
    for (int i = 0; i < 16; ++i) { pr[i] = bu2f(qr[128 + h * 16 + i]); mx = fmaxf(mx, pr[i]); }
    float ss = 0.f;
    #pragma unroll
    for (int i = 0; i < 16; ++i) { pr[i] = __expf(pr[i] - mx); ss += pr[i]; }
    const float inv = 1.f / ss;

    const float rcx = refw[t * 4 + 0], rcy = refw[t * 4 + 1];
    const float rww = refw[t * 4 + 2], rwh = refw[t * 4 + 3];

    const int LH[4]  = {92, 46, 23, 12};
    const int LS0[4] = {0, 8464, 10580, 11109};
    uint4* op = prep + (size_t)gid * 16;

    #pragma unroll
    for (int lvl = 0; lvl < 4; ++lvl) {
        const int Ww = LH[lvl], Hh = LH[lvl], s0 = LS0[lvl];
        const float vrx = vr[lvl * 2 + 0];
        const float vry = vr[lvl * 2 + 1];
        const float o0 = bu2f(qr[h * 16 + lvl * 4 + 0]) * 0.125f;
        const float o1 = bu2f(qr[h * 16 + lvl * 4 + 1]) * 0.125f;
        const float o2 = bu2f(qr[h * 16 + lvl * 4 + 2]) * 0.125f;
        const float o3 = bu2f(qr[h * 16 + lvl * 4 + 3]) * 0.125f;
        const float bx = rcx + o0 * rww;
        const float by = rcy + o1 * rwh;
        const float bwd = fmaxf(rww + o2 * rww, 0.f);
        const float bhd = fmaxf(rwh + o3 * rwh, 0.f);

        #pragma unroll
        for (int p = 0; p < 4; ++p) {
            const float jx = (p & 1) ? 0.25f : -0.25f;
            const float iy = (p & 2) ? 0.25f : -0.25f;
            const float px = (bx + jx * bwd) * vrx * (float)Ww - 0.5f;
            const float py = (by + iy * bhd) * vry * (float)Hh - 0.5f;
            const float x0f = floorf(px), y0f = floorf(py);
            const int x0 = (int)x0f, y0 = (int)y0f;
            const float wx = px - x0f, wy = py - y0f;
            const float aw = pr[lvl * 4 + p] * inv;

            const bool vx0 = (x0 >= 0)     && (x0 < Ww);
            const bool vx1 = (x0 + 1 >= 0) && (x0 + 1 < Ww);
            const bool vy0 = (y0 >= 0)     && (y0 < Hh);
            const bool vy1 = (y0 + 1 >= 0) && (y0 + 1 < Hh);
            const int cx0 = min(max(x0, 0), Ww - 1);
            const int cx1 = min(max(x0 + 1, 0), Ww - 1);
            const int cy0 = min(max(y0, 0), Hh - 1);
            const int cy1 = min(max(y0 + 1, 0), Hh - 1);

            const float w00 = (vx0 && vy0) ? aw * (1.f - wx) * (1.f - wy) : 0.f;
            const float w01 = (vx1 && vy0) ? aw * wx         * (1.f - wy) : 0.f;
            const float w10 = (vx0 && vy1) ? aw * (1.f - wx) * wy         : 0.f;
            const float w11 = (vx1 && vy1) ? aw * wx         * wy         : 0.f;

            uint4 q;
            q.x = (uint)(s0 + cy0 * Ww + cx0) | ((uint)(s0 + cy0 * Ww + cx1) << 16);
            q.y = (uint)(s0 + cy1 * Ww + cx0) | ((uint)(s0 + cy1 * Ww + cx1) << 16);
            q.z = (uint)f2bu(w00) | ((uint)f2bu(w01) << 16);
            q.w = (uint)f2bu(w10) | ((uint)f2bu(w11) << 16);
            op[lvl * 4 + p] = q;
        }
    }
}

// ---------------------------------------------------------------------------
// Box sample: pure gather. Block = 2 tokens; thread = (token, head, dim-pair).
// ---------------------------------------------------------------------------
__global__ __launch_bounds__(256) void box_sample2(
    const ushort* __restrict__ val, const uint4* __restrict__ prep,
    ushort* __restrict__ attnout)
{
    __shared__ uint4 pd[256];
    const int tid = threadIdx.x;
    const int t0 = blockIdx.x * 2;
    pd[tid] = prep[(size_t)t0 * 128 + tid];
    __syncthreads();

    const int tl = tid >> 7, h = (tid >> 4) & 7, dl = tid & 15;
    const int t = t0 + tl;
    const ushort* vb = val + ((t >= SLEN) ? (size_t)SLEN * 256 : 0) + h * 32 + dl * 2;
    const uint4* pp = &pd[(tl << 7) + (h << 4)];

    float a0 = 0.f, a1 = 0.f;
    #pragma unroll
    for (int p = 0; p < 16; ++p) {
        const uint4 q = pp[p];
        const int i0 = (int)(q.x & 0xFFFFu);
        const int i1 = (int)(q.x >> 16);
        const int i2 = (int)(q.y & 0xFFFFu);
        const int i3 = (int)(q.y >> 16);
        const float w0 = __uint_as_float(q.z << 16);
        const float w1 = __uint_as_float(q.z & 0xFFFF0000u);
        const float w2 = __uint_as_float(q.w << 16);
        const float w3 = __uint_as_float(q.w & 0xFFFF0000u);
        const uint v0 = *reinterpret_cast<const uint*>(vb + (size_t)i0 * 256);
        const uint v1 = *reinterpret_cast<const uint*>(vb + (size_t)i1 * 256);
        const uint v2 = *reinterpret_cast<const uint*>(vb + (size_t)i2 * 256);
        const uint v3 = *reinterpret_cast<const uint*>(vb + (size_t)i3 * 256);
        a0 = fmaf(w0, __uint_as_float(v0 << 16), a0);
        a1 = fmaf(w0, __uint_as_float(v0 & 0xFFFF0000u), a1);
        a0 = fmaf(w1, __uint_as_float(v1 << 16), a0);
        a1 = fmaf(w1, __uint_as_float(v1 & 0xFFFF0000u), a1);
        a0 = fmaf(w2, __uint_as_float(v2 << 16), a0);
        a1 = fmaf(w2, __uint_as_float(v2 & 0xFFFF0000u), a1);
        a0 = fmaf(w3, __uint_as_float(v3 << 16), a0);
        a1 = fmaf(w3, __uint_as_float(v3 & 0xFFFF0000u), a1);
    }
    const uint o = (uint)f2bu(a0) | ((uint)f2bu(a1) << 16);
    *reinterpret_cast<uint*>(attnout + (size_t)t * 256 + h * 32 + dl * 2) = o;
}

// ---------------------------------------------------------------------------
// LayerNorm(a + b): wave per row, thread handles 4 cols (float4), pure
// shuffle reduction. 4 rows/block.
// ---------------------------------------------------------------------------
template<bool BBF16, bool WBF16>
__global__ __launch_bounds__(256) void ln_add(
    const float* __restrict__ a, const void* __restrict__ bptr,
    const float* __restrict__ w, const float* __restrict__ bias,
    float* __restrict__ out, ushort* __restrict__ outb, int nrows)
{
    const int lane = threadIdx.x & 63, wv = threadIdx.x >> 6;
    const int row = blockIdx.x * 4 + wv;
    if (row >= nrows) return;
    const size_t base = (size_t)row * 256 + lane * 4;

    const float4 av = *reinterpret_cast<const float4*>(a + base);
    float4 bv;
    if (BBF16) {
        const ushort4 u = *reinterpret_cast<const ushort4*>((const ushort*)bptr + base);
        bv = make_float4(bu2f(u.x), bu2f(u.y), bu2f(u.z), bu2f(u.w));
    } else {
        bv = *reinterpret_cast<const float4*>((const float*)bptr + base);
    }
    const float v0 = av.x + bv.x, v1 = av.y + bv.y;
    const float v2 = av.z + bv.z, v3 = av.w + bv.w;

    float s = v0 + v1 + v2 + v3;
    #pragma unroll
    for (int o = 32; o; o >>= 1) s += __shfl_xor(s, o);
    const float mu = s * (1.f / 256.f);
    const float d0 = v0 - mu, d1 = v1 - mu, d2 = v2 - mu, d3 = v3 - mu;
    float s2 = d0 * d0 + d1 * d1 + d2 * d2 + d3 * d3;
    #pragma unroll
    for (int o = 32; o; o >>= 1) s2 += __shfl_xor(s2, o);
    const float rs = rsqrtf(s2 * (1.f / 256.f) + 1e-5f);

    const float4 w4 = *reinterpret_cast<const float4*>(w + lane * 4);
    const float4 g4 = *reinterpret_cast<const float4*>(bias + lane * 4);
    float4 o4;
    o4.x = d0 * rs * w4.x + g4.x;
    o4.y = d1 * rs * w4.y + g4.y;
    o4.z = d2 * rs * w4.z + g4.z;
    o4.w = d3 * rs * w4.w + g4.w;
    *reinterpret_cast<float4*>(out + base) = o4;
    if (WBF16) {
        ushort4 u;
        u.x = f2bu(o4.x); u.y = f2bu(o4.y); u.z = f2bu(o4.z); u.w = f2bu(o4.w);
        *reinterpret_cast<ushort4*>(outb + base) = u;
    }
}

// ---------------------------------------------------------------------------
extern "C" void kernel_launch(void* const* d_in, const int* in_sizes, int n_in,
                              void* d_out, int out_size, void* d_ws, size_t ws_size,
                              hipStream_t stream)
{
    const float* src     = (const float*)d_in[0];
    const float* pos     = (const float*)d_in[1];
    const float* vratio  = (const float*)d_in[5];
    const float* refw    = (const float*)d_in[6];
    const float* value_w = (const float*)d_in[7];
    const float* value_b = (const float*)d_in[8];
    const float* out_w   = (const float*)d_in[9];
    const float* out_b   = (const float*)d_in[10];
    const float* box_w   = (const float*)d_in[11];
    const float* box_b   = (const float*)d_in[12];
    const float* attn_w  = (const float*)d_in[13];
    const float* attn_b  = (const float*)d_in[14];
    const float* lin1_b  = (const float*)d_in[16];
    const float* lin1_w  = (const float*)d_in[15];
    const float* lin2_w  = (const float*)d_in[17];
    const float* lin2_b  = (const float*)d_in[18];
    const float* n1w     = (const float*)d_in[19];
    const float* n1b     = (const float*)d_in[20];
    const float* n2w     = (const float*)d_in[21];
    const float* n2b     = (const float*)d_in[22];

    // flat workspace layout (ws = 256 MiB; peak used = 220,381,184 B)
    char* wsb = (char*)d_ws;
    ushort* Wb    = (ushort*)(wsb);                  // 1,441,792 B
    float*  qcb   = (float*)(wsb + 1441792);         // 1 KB
    ushort* srcb  = (ushort*)(wsb + 1442816);        // 11.5 MB bf16 src
    ushort* qb    = (ushort*)(wsb + 12965888);       // 11.5 MB bf16 src+pos
    ushort* valb  = (ushort*)(wsb + 24488960);       // 11.5 MB value
    ushort* qoutb = (ushort*)(wsb + 36012032);       // 11.5 MB off+logits
    uint4*  prepb = (uint4*)(wsb + 47535104);        // 46.1 MB prep
    ushort* attb  = (ushort*)(wsb + 93627392);       // 11.5 MB attn out
    float*  src2  = (float*)(wsb + 105150464);       // 23.0 MB f32
    float*  xb    = (float*)(wsb + 128196608);       // 23.0 MB f32
    ushort* xbb   = (ushort*)(wsb + 151242752);      // 11.5 MB bf16 x
    ushort* hb    = (ushort*)(wsb + 162765824);      // 46.1 MB hidden
    ushort* yb    = (ushort*)(wsb + 208858112);      // 11.5 MB y

    const dim3 blk(256);

    wconv<<<dim3(2817), blk, 0, stream>>>(
        value_w, box_w, attn_w, out_w, lin1_w, lin2_w, box_b, attn_b, Wb, qcb);
    conv_inputs<<<dim3((TOKENS * 64 + 255) / 256), blk, 0, stream>>>(
        (const float4*)src, (const float4*)pos, (ushort4*)srcb, (ushort4*)qb,
        TOKENS * 64);

    // merged: z=0 value = src @ value_w^T ; z=1 qout = q @ [box;attn]^T
    gemm_bf16<false, true><<<dim3(176, 2, 2), blk, 0, stream>>>(
        srcb, Wb, value_b, valb,
        qb, Wb + 65536, qcb, qoutb, TOKENS, 256, 256);

    box_prep<<<dim3((TOKENS * 8 + 255) / 256), blk, 0, stream>>>(
        qoutb, refw, vratio, prepb);
    box_sample2<<<dim3(TOKENS / 2), blk, 0, stream>>>(valb, prepb, attb);

    // src2 = attnout @ out_w^T + b -> f32
    gemm_bf16<false, false><<<dim3(176, 2, 1), blk, 0, stream>>>(
        attb, Wb + 131072, out_b, src2,
        attb, Wb + 131072, out_b, src2, TOKENS, 256, 256);
    // x = LN1(src + src2) -> f32 + bf16
    ln_add<false, true><<<dim3((TOKENS + 3) / 4), blk, 0, stream>>>(
        src, src2, n1w, n1b, xb, xbb, TOKENS);
    // h = relu(x @ lin1_w^T + b) -> bf16
    gemm_bf16<true, true><<<dim3(176, 8, 1), blk, 0, stream>>>(
        xbb, Wb + 196608, lin1_b, hb,
        xbb, Wb + 196608, lin1_b, hb, TOKENS, 1024, 256);
    // y = h @ lin2_w^T + b -> bf16
    gemm_bf16<false, true><<<dim3(176, 2, 1), blk, 0, stream>>>(
        hb, Wb + 458752, lin2_b, yb,
        hb, Wb + 458752, lin2_b, yb, TOKENS, 256, 1024);
    // out = LN2(x + y)
    ln_add<true, false><<<dim3((TOKENS + 3) / 4), blk, 0, stream>>>(
        xb, yb, n2w, n2b, (float*)d_out, nullptr, TOKENS);
}

// Round 6
// 179.869 us; speedup vs baseline: 4.4394x; 1.2153x over previous
//
#include <hip/hip_runtime.h>
#include <hip/hip_bf16.h>

#define TOKENS 22506
#define SLEN   11253

typedef __bf16 bf16x8 __attribute__((ext_vector_type(8)));
typedef float  f32x4  __attribute__((ext_vector_type(4)));

#if defined(__has_builtin)
#if __has_builtin(__builtin_amdgcn_raw_buffer_load_b32) && __has_builtin(__builtin_amdgcn_make_buffer_rsrc)
#define HAS_BUFLOAD 1
#endif
#endif

__device__ __forceinline__ ushort f2bu(float f) {
    __hip_bfloat16 h = __float2bfloat16(f);   // RNE
    return *reinterpret_cast<ushort*>(&h);
}
__device__ __forceinline__ float bu2f(ushort u) {
    return __uint_as_float((uint)u << 16);
}
__device__ __forceinline__ void gl16(const ushort* g, ushort* l) {
    __builtin_amdgcn_global_load_lds(
        (__attribute__((address_space(1))) void*)(g),
        (__attribute__((address_space(3))) void*)(l), 16, 0, 0);
}

// ---------------------------------------------------------------------------
// m97-structure MFMA GEMM + double-buffered LDS (2-phase pipeline).
// C[M,N] = A[M,K](bf16) @ W[N,K](bf16)^T + bias[N], bf16 out.
// 128x128 tile, BK=32, 256 thr = 4 waves (2x2), 4x4 frags of 16x16x32 bf16.
// Staging via global_load_lds width-16 into linear LDS [128][32].
// blockIdx.z selects source set (merged launches).
// ---------------------------------------------------------------------------
template<bool RELU>
__global__ __launch_bounds__(256) void gemm_bf16(
    const ushort* __restrict__ A0, const ushort* __restrict__ W0,
    const float* __restrict__ b0, ushort* __restrict__ C0,
    const ushort* __restrict__ A1, const ushort* __restrict__ W1,
    const float* __restrict__ b1, ushort* __restrict__ C1,
    int M, int N, int K)
{
    const bool zz = blockIdx.z != 0;
    const ushort* A   = zz ? A1 : A0;
    const ushort* W   = zz ? W1 : W0;
    const float* bias = zz ? b1 : b0;
    ushort* Cptr      = zz ? C1 : C0;

    __shared__ ushort As[2][128 * 32];
    __shared__ ushort Bs[2][128 * 32];
    const int tid  = threadIdx.x;
    const int lane = tid & 63;
    const int wid  = tid >> 6;
    const int wr = wid >> 1, wc = wid & 1;
    const int m0 = blockIdx.x * 128, n0 = blockIdx.y * 128;
    const int lrow = lane & 15, lhi = lane >> 4;

    const int srow = tid >> 2;          // 0..63
    const int scol = (tid & 3) << 3;    // 0,8,16,24 (bf16 units; 16B chunk)
    const int lo   = srow * 32 + scol;

    const ushort* ga0 = A + (size_t)min(m0 + srow,      M - 1) * K + scol;
    const ushort* ga1 = A + (size_t)min(m0 + srow + 64, M - 1) * K + scol;
    const ushort* gb0 = W + (size_t)(n0 + srow)      * K + scol;
    const ushort* gb1 = W + (size_t)(n0 + srow + 64) * K + scol;

    f32x4 acc[4][4] = {};
    const int NT = K >> 5;

    gl16(ga0, &As[0][lo]);
    gl16(ga1, &As[0][lo + 64 * 32]);
    gl16(gb0, &Bs[0][lo]);
    gl16(gb1, &Bs[0][lo + 64 * 32]);

    int cur = 0;
    for (int t = 0; t < NT; ++t) {
        __syncthreads();   // buf[cur] ready; prev reads of buf[cur^1] done
        if (t + 1 < NT) {
            const int k0 = (t + 1) << 5;
            const int nb = cur ^ 1;
            gl16(ga0 + k0, &As[nb][lo]);
            gl16(ga1 + k0, &As[nb][lo + 64 * 32]);
            gl16(gb0 + k0, &Bs[nb][lo]);
            gl16(gb1 + k0, &Bs[nb][lo + 64 * 32]);
        }
        bf16x8 afr[4], bfr[4];
        #pragma unroll
        for (int m = 0; m < 4; ++m)
            afr[m] = *reinterpret_cast<const bf16x8*>(
                &As[cur][(wr * 64 + m * 16 + lrow) * 32 + lhi * 8]);
        #pragma unroll
        for (int n = 0; n < 4; ++n)
            bfr[n] = *reinterpret_cast<const bf16x8*>(
                &Bs[cur][(wc * 64 + n * 16 + lrow) * 32 + lhi * 8]);
        #pragma unroll
        for (int m = 0; m < 4; ++m)
            #pragma unroll
            for (int n = 0; n < 4; ++n)
                acc[m][n] = __builtin_amdgcn_mfma_f32_16x16x32_bf16(
                    afr[m], bfr[n], acc[m][n], 0, 0, 0);
        cur ^= 1;
    }

    #pragma unroll
    for (int m = 0; m < 4; ++m) {
        #pragma unroll
        for (int n = 0; n < 4; ++n) {
            const int gcol = n0 + wc * 64 + n * 16 + lrow;
            const float bv = bias[gcol];
            #pragma unroll
            for (int r = 0; r < 4; ++r) {
                const int grow = m0 + wr * 64 + m * 16 + lhi * 4 + r;
                if (grow < M) {
                    float v = acc[m][n][r] + bv;
                    if (RELU) v = fmaxf(v, 0.f);
                    Cptr[(size_t)grow * N + gcol] = f2bu(v);
                }
            }
        }
    }
}

// ---------------------------------------------------------------------------
// Input conversion: srcb = bf16(src), qb = bf16(src+pos). 4 elems/thread.
// ---------------------------------------------------------------------------
__global__ __launch_bounds__(256) void conv_inputs(
    const float4* __restrict__ src, const float4* __restrict__ pos,
    ushort4* __restrict__ srcb, ushort4* __restrict__ qb, int n4)
{
    const int i = blockIdx.x * 256 + threadIdx.x;
    if (i >= n4) return;
    const float4 s = src[i], p = pos[i];
    ushort4 us, uq;
    us.x = f2bu(s.x); us.y = f2bu(s.y); us.z = f2bu(s.z); us.w = f2bu(s.w);
    uq.x = f2bu(s.x + p.x); uq.y = f2bu(s.y + p.y);
    uq.z = f2bu(s.z + p.z); uq.w = f2bu(s.w + p.w);
    srcb[i] = us; qb[i] = uq;
}

// ---------------------------------------------------------------------------
// Weight conversion f32 -> bf16 packed + concatenated box/attn bias.
//   [0,65536) value_w | [65536,131072) box_w+attn_w | [131072,196608) out_w
//   [196608,458752) lin1_w | [458752,720896) lin2_w
// ---------------------------------------------------------------------------
__global__ __launch_bounds__(256) void wconv(
    const float* __restrict__ vw, const float* __restrict__ bw,
    const float* __restrict__ aw, const float* __restrict__ ow,
    const float* __restrict__ l1, const float* __restrict__ l2,
    const float* __restrict__ bb, const float* __restrict__ ab,
    ushort* __restrict__ dstW, float* __restrict__ dstQB)
{
    const int i = blockIdx.x * 256 + threadIdx.x;
    if (i < 720896) {
        float v;
        if      (i <  65536) v = vw[i];
        else if (i <  98304) v = bw[i -  65536];
        else if (i < 131072) v = aw[i -  98304];
        else if (i < 196608) v = ow[i - 131072];
        else if (i < 458752) v = l1[i - 196608];
        else                 v = l2[i - 458752];
        dstW[i] = f2bu(v);
    } else if (i < 721152) {
        const int j = i - 720896;
        dstQB[j] = (j < 128) ? bb[j] : ab[j - 128];
    }
}

// ---------------------------------------------------------------------------
// Fused box prep + sample. Block = 2 tokens.
// Phase 1: thread = (unit, point), unit = token*8+head (16 units x 16 pts).
//   16-lane shfl softmax; box/bilinear math once per point; emit to LDS:
//   {4x u32 byte-offset (row*512 + h*64), 4x f32 premult weights}.
//   Unit stride 544 B -> phase-2 ds_read_b128 conflict-free across units.
// Phase 2: thread = (unit, dim-pair). Per point: 2 ds_read (broadcast) +
//   4 buffer_load (32-bit voffset, zero addr VALU) + 8 unpack + 8 fma.
// ---------------------------------------------------------------------------
__global__ __launch_bounds__(256) void box_fused(
    const ushort* __restrict__ val,    // (B*SLEN, 256) bf16
    const ushort* __restrict__ qout,   // (t,256): off[128] | logits[128] bf16
    const float* __restrict__ refw,    // (t,4)
    const float* __restrict__ vratio,  // (B,4,2)
    ushort* __restrict__ attnout)      // (t,256) bf16
{
    __shared__ uint4 pd[16 * 34];      // 8704 B
    const int tid = threadIdx.x;
    const int t0 = blockIdx.x * 2;

    // ---------------- phase 1 ----------------
    {
        const int u = tid >> 4, p = tid & 15;
        const int t = t0 + (u >> 3), h = u & 7;
        const int b = (t >= SLEN) ? 1 : 0;
        const int lvl = p >> 2, k = p & 3;
        const ushort* qr = qout + (size_t)t * 256;

        const uint2 ou = *reinterpret_cast<const uint2*>(qr + h * 16 + lvl * 4);
        const float o0 = __uint_as_float(ou.x << 16) * 0.125f;
        const float o1 = __uint_as_float(ou.x & 0xFFFF0000u) * 0.125f;
        const float o2 = __uint_as_float(ou.y << 16) * 0.125f;
        const float o3 = __uint_as_float(ou.y & 0xFFFF0000u) * 0.125f;
        const float lg = bu2f(qr[128 + h * 16 + p]);

        float mx = lg;
        #pragma unroll
        for (int o = 1; o < 16; o <<= 1) mx = fmaxf(mx, __shfl_xor(mx, o));
        const float e = __expf(lg - mx);
        float ss = e;
        #pragma unroll
        for (int o = 1; o < 16; o <<= 1) ss += __shfl_xor(ss, o);
        const float wp = e / ss;

        const float4 rw = *reinterpret_cast<const float4*>(refw + (size_t)t * 4);
        const int Ww = (lvl == 0) ? 92 : (lvl == 1) ? 46 : (lvl == 2) ? 23 : 12;
        const int s0 = (lvl == 0) ? 0 : (lvl == 1) ? 8464 : (lvl == 2) ? 10580 : 11109;
        const float vrx = vratio[(b * 4 + lvl) * 2 + 0];
        const float vry = vratio[(b * 4 + lvl) * 2 + 1];

        const float bx  = rw.x + o0 * rw.z;
        const float by  = rw.y + o1 * rw.w;
        const float bwd = fmaxf(rw.z + o2 * rw.z, 0.f);
        const float bhd = fmaxf(rw.w + o3 * rw.w, 0.f);
        const float jx = (k & 1) ? 0.25f : -0.25f;
        const float iy = (k & 2) ? 0.25f : -0.25f;
        const float px = (bx + jx * bwd) * vrx * (float)Ww - 0.5f;
        const float py = (by + iy * bhd) * vry * (float)Ww - 0.5f;
        const float x0f = floorf(px), y0f = floorf(py);
        const int x0 = (int)x0f, y0 = (int)y0f;
        const float wx = px - x0f, wy = py - y0f;

        const bool vx0 = (x0 >= 0) && (x0 < Ww);
        const bool vx1 = (x0 + 1 >= 0) && (x0 + 1 < Ww);
        const bool vy0 = (y0 >= 0) && (y0 < Ww);
        const bool vy1 = (y0 + 1 >= 0) && (y0 + 1 < Ww);
        const int cx0 = min(max(x0, 0), Ww - 1);
        const int cx1 = min(max(x0 + 1, 0), Ww - 1);
        const int cy0 = min(max(y0, 0), Ww - 1);
        const int cy1 = min(max(y0 + 1, 0), Ww - 1);

        float4 w4;
        w4.x = (vx0 && vy0) ? wp * (1.f - wx) * (1.f - wy) : 0.f;
        w4.y = (vx1 && vy0) ? wp * wx         * (1.f - wy) : 0.f;
        w4.z = (vx0 && vy1) ? wp * (1.f - wx) * wy         : 0.f;
        w4.w = (vx1 && vy1) ? wp * wx         * wy         : 0.f;

        const uint hb_ = (uint)h * 64u;
        uint4 off4;
        off4.x = (uint)(s0 + cy0 * Ww + cx0) * 512u + hb_;
        off4.y = (uint)(s0 + cy0 * Ww + cx1) * 512u + hb_;
        off4.z = (uint)(s0 + cy1 * Ww + cx0) * 512u + hb_;
        off4.w = (uint)(s0 + cy1 * Ww + cx1) * 512u + hb_;

        pd[u * 34 + p * 2] = off4;
        *reinterpret_cast<float4*>(&pd[u * 34 + p * 2 + 1]) = w4;
    }
    __syncthreads();

    // ---------------- phase 2 ----------------
    const int u = tid >> 4, dl = tid & 15;
    const int t = t0 + (u >> 3), h = u & 7;
    const uint boff = (uint)dl * 4u + ((t >= SLEN) ? (uint)SLEN * 512u : 0u);

#if HAS_BUFLOAD
    const auto rsrc = __builtin_amdgcn_make_buffer_rsrc(
        (void*)val, /*stride*/ (short)0, /*num_records*/ -1,
        /*flags*/ 0x00020000);
#endif

    const uint4* pu = &pd[u * 34];
    float a0 = 0.f, a1 = 0.f;
    #pragma unroll 4
    for (int p = 0; p < 16; ++p) {
        const uint4 off4 = pu[p * 2];
        const float4 w4 = *reinterpret_cast<const float4*>(&pu[p * 2 + 1]);
#if HAS_BUFLOAD
        const uint v0 = __builtin_amdgcn_raw_buffer_load_b32(rsrc, (int)(off4.x + boff), 0, 0);
        const uint v1 = __builtin_amdgcn_raw_buffer_load_b32(rsrc, (int)(off4.y + boff), 0, 0);
        const uint v2 = __builtin_amdgcn_raw_buffer_load_b32(rsrc, (int)(off4.z + boff), 0, 0);
        const uint v3 = __builtin_amdgcn_raw_buffer_load_b32(rsrc, (int)(off4.w + boff), 0, 0);
#else
        const char* vb = (const char*)val;
        const uint v0 = *(const uint*)(vb + off4.x + boff);
        const uint v1 = *(const uint*)(vb + off4.y + boff);
        const uint v2 = *(const uint*)(vb + off4.z + boff);
        const uint v3 = *(const uint*)(vb + off4.w + boff);
#endif
        a0 = fmaf(w4.x, __uint_as_float(v0 << 16), a0);
        a1 = fmaf(w4.x, __uint_as_float(v0 & 0xFFFF0000u), a1);
        a0 = fmaf(w4.y, __uint_as_float(v1 << 16), a0);
        a1 = fmaf(w4.y, __uint_as_float(v1 & 0xFFFF0000u), a1);
        a0 = fmaf(w4.z, __uint_as_float(v2 << 16), a0);
        a1 = fmaf(w4.z, __uint_as_float(v2 & 0xFFFF0000u), a1);
        a0 = fmaf(w4.w, __uint_as_float(v3 << 16), a0);
        a1 = fmaf(w4.w, __uint_as_float(v3 & 0xFFFF0000u), a1);
    }
    const uint o = (uint)f2bu(a0) | ((uint)f2bu(a1) << 16);
    reinterpret_cast<uint*>(attnout)[(size_t)t * 128 + h * 16 + dl] = o;
}

// ---------------------------------------------------------------------------
// LayerNorm(a + b): wave per row, thread handles 4 cols, shuffle reduction,
// 4 rows/block. b always bf16. AF32: a f32 vs bf16. OUTF32: f32 vs bf16 out.
// ---------------------------------------------------------------------------
template<bool AF32, bool OUTF32>
__global__ __launch_bounds__(256) void ln_add2(
    const void* __restrict__ aptr, const ushort* __restrict__ bptr,
    const float* __restrict__ w, const float* __restrict__ bias,
    void* __restrict__ outp, int nrows)
{
    const int lane = threadIdx.x & 63, wv = threadIdx.x >> 6;
    const int row = blockIdx.x * 4 + wv;
    if (row >= nrows) return;
    const size_t base = (size_t)row * 256 + lane * 4;

    float4 av;
    if (AF32) {
        av = *reinterpret_cast<const float4*>((const float*)aptr + base);
    } else {
        const ushort4 u = *reinterpret_cast<const ushort4*>((const ushort*)aptr + base);
        av = make_float4(bu2f(u.x), bu2f(u.y), bu2f(u.z), bu2f(u.w));
    }
    const ushort4 ub = *reinterpret_cast<const ushort4*>(bptr + base);
    const float v0 = av.x + bu2f(ub.x), v1 = av.y + bu2f(ub.y);
    const float v2 = av.z + bu2f(ub.z), v3 = av.w + bu2f(ub.w);

    float s = v0 + v1 + v2 + v3;
    #pragma unroll
    for (int o = 32; o; o >>= 1) s += __shfl_xor(s, o);
    const float mu = s * (1.f / 256.f);
    const float d0 = v0 - mu, d1 = v1 - mu, d2 = v2 - mu, d3 = v3 - mu;
    float s2 = d0 * d0 + d1 * d1 + d2 * d2 + d3 * d3;
    #pragma unroll
    for (int o = 32; o; o >>= 1) s2 += __shfl_xor(s2, o);
    const float rs = rsqrtf(s2 * (1.f / 256.f) + 1e-5f);

    const float4 w4 = *reinterpret_cast<const float4*>(w + lane * 4);
    const float4 g4 = *reinterpret_cast<const float4*>(bias + lane * 4);
    const float r0 = d0 * rs * w4.x + g4.x;
    const float r1 = d1 * rs * w4.y + g4.y;
    const float r2 = d2 * rs * w4.z + g4.z;
    const float r3 = d3 * rs * w4.w + g4.w;
    if (OUTF32) {
        *reinterpret_cast<float4*>((float*)outp + base) = make_float4(r0, r1, r2, r3);
    } else {
        ushort4 u;
        u.x = f2bu(r0); u.y = f2bu(r1); u.z = f2bu(r2); u.w = f2bu(r3);
        *reinterpret_cast<ushort4*>((ushort*)outp + base) = u;
    }
}

// ---------------------------------------------------------------------------
extern "C" void kernel_launch(void* const* d_in, const int* in_sizes, int n_in,
                              void* d_out, int out_size, void* d_ws, size_t ws_size,
                              hipStream_t stream)
{
    const float* src     = (const float*)d_in[0];
    const float* pos     = (const float*)d_in[1];
    const float* vratio  = (const float*)d_in[5];
    const float* refw    = (const float*)d_in[6];
    const float* value_w = (const float*)d_in[7];
    const float* value_b = (const float*)d_in[8];
    const float* out_w   = (const float*)d_in[9];
    const float* out_b   = (const float*)d_in[10];
    const float* box_w   = (const float*)d_in[11];
    const float* box_b   = (const float*)d_in[12];
    const float* attn_w  = (const float*)d_in[13];
    const float* attn_b  = (const float*)d_in[14];
    const float* lin1_w  = (const float*)d_in[15];
    const float* lin1_b  = (const float*)d_in[16];
    const float* lin2_w  = (const float*)d_in[17];
    const float* lin2_b  = (const float*)d_in[18];
    const float* n1w     = (const float*)d_in[19];
    const float* n1b     = (const float*)d_in[20];
    const float* n2w     = (const float*)d_in[21];
    const float* n2b     = (const float*)d_in[22];

    // flat workspace layout (~140 MB of 256 MiB)
    char* wsb = (char*)d_ws;
    ushort* Wb    = (ushort*)(wsb);                  // 1,441,792 B
    float*  qcb   = (float*)(wsb + 1441792);         // 1 KB
    ushort* srcb  = (ushort*)(wsb + 1442816);        // 11.5 MB bf16 src
    ushort* qb    = (ushort*)(wsb + 12965888);       // 11.5 MB bf16 src+pos
    ushort* valb  = (ushort*)(wsb + 24488960);       // 11.5 MB value
    ushort* qoutb = (ushort*)(wsb + 36012032);       // 11.5 MB off+logits
    ushort* attb  = (ushort*)(wsb + 47535104);       // 11.5 MB attn out
    ushort* src2b = (ushort*)(wsb + 59058176);       // 11.5 MB src2 bf16
    ushort* xbb   = (ushort*)(wsb + 70581248);       // 11.5 MB x bf16
    ushort* hb    = (ushort*)(wsb + 82104320);       // 46.1 MB hidden
    ushort* yb    = (ushort*)(wsb + 128196608);      // 11.5 MB y bf16

    const dim3 blk(256);

    wconv<<<dim3(2817), blk, 0, stream>>>(
        value_w, box_w, attn_w, out_w, lin1_w, lin2_w, box_b, attn_b, Wb, qcb);
    conv_inputs<<<dim3((TOKENS * 64 + 255) / 256), blk, 0, stream>>>(
        (const float4*)src, (const float4*)pos, (ushort4*)srcb, (ushort4*)qb,
        TOKENS * 64);

    // merged: z=0 value = src @ value_w^T ; z=1 qout = q @ [box;attn]^T
    gemm_bf16<false><<<dim3(176, 2, 2), blk, 0, stream>>>(
        srcb, Wb, value_b, valb,
        qb, Wb + 65536, qcb, qoutb, TOKENS, 256, 256);

    // fused prep + gather
    box_fused<<<dim3(SLEN), blk, 0, stream>>>(valb, qoutb, refw, vratio, attb);

    // src2 = attnout @ out_w^T + b -> bf16
    gemm_bf16<false><<<dim3(176, 2, 1), blk, 0, stream>>>(
        attb, Wb + 131072, out_b, src2b,
        attb, Wb + 131072, out_b, src2b, TOKENS, 256, 256);
    // x = LN1(src + src2) -> bf16
    ln_add2<true, false><<<dim3((TOKENS + 3) / 4), blk, 0, stream>>>(
        src, src2b, n1w, n1b, xbb, TOKENS);
    // h = relu(x @ lin1_w^T + b) -> bf16
    gemm_bf16<true><<<dim3(176, 8, 1), blk, 0, stream>>>(
        xbb, Wb + 196608, lin1_b, hb,
        xbb, Wb + 196608, lin1_b, hb, TOKENS, 1024, 256);
    // y = h @ lin2_w^T + b -> bf16
    gemm_bf16<false><<<dim3(176, 2, 1), blk, 0, stream>>>(
        hb, Wb + 458752, lin2_b, yb,
        hb, Wb + 458752, lin2_b, yb, TOKENS, 256, 1024);
    // out = LN2(x + y) -> f32
    ln_add2<false, true><<<dim3((TOKENS + 3) / 4), blk, 0, stream>>>(
        xbb, yb, n2w, n2b, (float*)d_out, TOKENS);
}

// Round 8
// 167.209 us; speedup vs baseline: 4.7755x; 1.0757x over previous
//
#include <hip/hip_runtime.h>
#include <hip/hip_bf16.h>

#define TOKENS 22506
#define SLEN   11253

typedef __bf16 bf16x8 __attribute__((ext_vector_type(8)));
typedef float  f32x4  __attribute__((ext_vector_type(4)));
typedef float  f32x2  __attribute__((ext_vector_type(2)));
typedef uint   u32x4  __attribute__((ext_vector_type(4)));

__device__ __forceinline__ ushort f2bu(float f) {
    __hip_bfloat16 h = __float2bfloat16(f);   // RNE
    return *reinterpret_cast<ushort*>(&h);
}
__device__ __forceinline__ float bu2f(ushort u) {
    return __uint_as_float((uint)u << 16);
}
__device__ __forceinline__ void gl16(const ushort* g, ushort* l) {
    __builtin_amdgcn_global_load_lds(
        (__attribute__((address_space(1))) void*)(g),
        (__attribute__((address_space(3))) void*)(l), 16, 0, 0);
}

// ---------------------------------------------------------------------------
// 64x128-tile MFMA GEMM (high-TLP variant for N=256 GEMMs).
// C = A(bf16) @ W(bf16)^T + bias, bf16 out. BK=32, 256 thr = 4 waves (2x2),
// each wave 32x64 (acc[2][4]). global_load_lds staging, double-buffered.
// Epilogue: acc -> LDS bf16 (padded rows) -> coalesced dwordx4 stores.
// blockIdx.z selects source set.
// ---------------------------------------------------------------------------
template<bool RELU>
__global__ __launch_bounds__(256) void gemm_small(
    const ushort* __restrict__ A0, const ushort* __restrict__ W0,
    const float* __restrict__ b0, ushort* __restrict__ C0,
    const ushort* __restrict__ A1, const ushort* __restrict__ W1,
    const float* __restrict__ b1, ushort* __restrict__ C1,
    int M, int N, int K)
{
    const bool zz = blockIdx.z != 0;
    const ushort* A   = zz ? A1 : A0;
    const ushort* W   = zz ? W1 : W0;
    const float* bias = zz ? b1 : b0;
    ushort* Cptr      = zz ? C1 : C0;

    __shared__ ushort smem[12288];           // 24 KB
    // staging: As[buf] = smem + buf*2048 (64x32), Bs[buf] = smem+4096+buf*4096
    const int tid  = threadIdx.x;
    const int lane = tid & 63;
    const int wid  = tid >> 6;
    const int wr = wid >> 1, wc = wid & 1;
    const int m0 = blockIdx.x * 64, n0 = blockIdx.y * 128;
    const int lrow = lane & 15, lhi = lane >> 4;

    const int arow = tid >> 2;               // 0..63
    const int scol = (tid & 3) << 3;
    const ushort* ga  = A + (size_t)min(m0 + arow, M - 1) * K + scol;
    const ushort* gb0 = W + (size_t)(n0 + arow)      * K + scol;
    const ushort* gb1 = W + (size_t)(n0 + arow + 64) * K + scol;

    f32x4 acc[2][4] = {};
    const int NT = K >> 5;

    gl16(ga,  &smem[tid * 8]);
    gl16(gb0, &smem[4096 + tid * 8]);
    gl16(gb1, &smem[4096 + tid * 8 + 2048]);

    int cur = 0;
    for (int t = 0; t < NT; ++t) {
        __syncthreads();
        if (t + 1 < NT) {
            const int k0 = (t + 1) << 5;
            const int nb = cur ^ 1;
            gl16(ga  + k0, &smem[nb * 2048 + tid * 8]);
            gl16(gb0 + k0, &smem[4096 + nb * 4096 + tid * 8]);
            gl16(gb1 + k0, &smem[4096 + nb * 4096 + tid * 8 + 2048]);
        }
        bf16x8 afr[2], bfr[4];
        #pragma unroll
        for (int m = 0; m < 2; ++m)
            afr[m] = *reinterpret_cast<const bf16x8*>(
                &smem[cur * 2048 + (wr * 32 + m * 16 + lrow) * 32 + lhi * 8]);
        #pragma unroll
        for (int n = 0; n < 4; ++n)
            bfr[n] = *reinterpret_cast<const bf16x8*>(
                &smem[4096 + cur * 4096 + (wc * 64 + n * 16 + lrow) * 32 + lhi * 8]);
        #pragma unroll
        for (int m = 0; m < 2; ++m)
            #pragma unroll
            for (int n = 0; n < 4; ++n)
                acc[m][n] = __builtin_amdgcn_mfma_f32_16x16x32_bf16(
                    afr[m], bfr[n], acc[m][n], 0, 0, 0);
        cur ^= 1;
    }

    // epilogue: regs -> LDS (padded 136-elem rows) -> coalesced stores
    __syncthreads();
    #pragma unroll
    for (int m = 0; m < 2; ++m) {
        #pragma unroll
        for (int n = 0; n < 4; ++n) {
            const int col = wc * 64 + n * 16 + lrow;
            const float bv = bias[n0 + col];
            #pragma unroll
            for (int r = 0; r < 4; ++r) {
                const int row = wr * 32 + m * 16 + lhi * 4 + r;
                float v = acc[m][n][r] + bv;
                if (RELU) v = fmaxf(v, 0.f);
                smem[row * 136 + col] = f2bu(v);
            }
        }
    }
    __syncthreads();
    #pragma unroll
    for (int i = 0; i < 4; ++i) {
        const int e = tid + i * 256;
        const int row = e >> 4, ch = e & 15;
        if (m0 + row < M) {
            const u32x4 v = *reinterpret_cast<const u32x4*>(&smem[row * 136 + ch * 8]);
            *reinterpret_cast<u32x4*>(Cptr + (size_t)(m0 + row) * N + n0 + ch * 8) = v;
        }
    }
}

// ---------------------------------------------------------------------------
// 128x128-tile MFMA GEMM (lin1). Same structure; NTSTORE = nontemporal C.
// ---------------------------------------------------------------------------
template<bool RELU, bool NTSTORE>
__global__ __launch_bounds__(256) void gemm128(
    const ushort* __restrict__ A, const ushort* __restrict__ W,
    const float* __restrict__ bias, ushort* __restrict__ Cptr,
    int M, int N, int K)
{
    __shared__ ushort smem[17408];           // 34,816 B
    // staging: As[buf] = smem + buf*4096, Bs[buf] = smem + 8192 + buf*4096
    const int tid  = threadIdx.x;
    const int lane = tid & 63;
    const int wid  = tid >> 6;
    const int wr = wid >> 1, wc = wid & 1;
    const int m0 = blockIdx.x * 128, n0 = blockIdx.y * 128;
    const int lrow = lane & 15, lhi = lane >> 4;

    const int arow = tid >> 2;
    const int scol = (tid & 3) << 3;
    const ushort* ga0 = A + (size_t)min(m0 + arow,      M - 1) * K + scol;
    const ushort* ga1 = A + (size_t)min(m0 + arow + 64, M - 1) * K + scol;
    const ushort* gb0 = W + (size_t)(n0 + arow)      * K + scol;
    const ushort* gb1 = W + (size_t)(n0 + arow + 64) * K + scol;

    f32x4 acc[4][4] = {};
    const int NT = K >> 5;

    gl16(ga0, &smem[tid * 8]);
    gl16(ga1, &smem[tid * 8 + 2048]);
    gl16(gb0, &smem[8192 + tid * 8]);
    gl16(gb1, &smem[8192 + tid * 8 + 2048]);

    int cur = 0;
    for (int t = 0; t < NT; ++t) {
        __syncthreads();
        if (t + 1 < NT) {
            const int k0 = (t + 1) << 5;
            const int nb = cur ^ 1;
            gl16(ga0 + k0, &smem[nb * 4096 + tid * 8]);
            gl16(ga1 + k0, &smem[nb * 4096 + tid * 8 + 2048]);
            gl16(gb0 + k0, &smem[8192 + nb * 4096 + tid * 8]);
            gl16(gb1 + k0, &smem[8192 + nb * 4096 + tid * 8 + 2048]);
        }
        bf16x8 afr[4], bfr[4];
        #pragma unroll
        for (int m = 0; m < 4; ++m)
            afr[m] = *reinterpret_cast<const bf16x8*>(
                &smem[cur * 4096 + (wr * 64 + m * 16 + lrow) * 32 + lhi * 8]);
        #pragma unroll
        for (int n = 0; n < 4; ++n)
            bfr[n] = *reinterpret_cast<const bf16x8*>(
                &smem[8192 + cur * 4096 + (wc * 64 + n * 16 + lrow) * 32 + lhi * 8]);
        #pragma unroll
        for (int m = 0; m < 4; ++m)
            #pragma unroll
            for (int n = 0; n < 4; ++n)
                acc[m][n] = __builtin_amdgcn_mfma_f32_16x16x32_bf16(
                    afr[m], bfr[n], acc[m][n], 0, 0, 0);
        cur ^= 1;
    }

    __syncthreads();
    #pragma unroll
    for (int m = 0; m < 4; ++m) {
        #pragma unroll
        for (int n = 0; n < 4; ++n) {
            const int col = wc * 64 + n * 16 + lrow;
            const float bv = bias[n0 + col];
            #pragma unroll
            for (int r = 0; r < 4; ++r) {
                const int row = wr * 64 + m * 16 + lhi * 4 + r;
                float v = acc[m][n][r] + bv;
                if (RELU) v = fmaxf(v, 0.f);
                smem[row * 136 + col] = f2bu(v);
            }
        }
    }
    __syncthreads();
    #pragma unroll
    for (int i = 0; i < 8; ++i) {
        const int e = tid + i * 256;
        const int row = e >> 4, ch = e & 15;
        if (m0 + row < M) {
            const u32x4 v = *reinterpret_cast<const u32x4*>(&smem[row * 136 + ch * 8]);
            u32x4* dst = reinterpret_cast<u32x4*>(Cptr + (size_t)(m0 + row) * N + n0 + ch * 8);
            if (NTSTORE) __builtin_nontemporal_store(v, dst);
            else *dst = v;
        }
    }
}

// ---------------------------------------------------------------------------
// Merged one-time prep: weight f32->bf16 pack + cat bias  AND  input cvt.
//   blocks [0,2817): weights; [2817, 8444): srcb/qb conversion.
// ---------------------------------------------------------------------------
__global__ __launch_bounds__(256) void prep_all(
    const float* __restrict__ vw, const float* __restrict__ bw,
    const float* __restrict__ aw, const float* __restrict__ ow,
    const float* __restrict__ l1, const float* __restrict__ l2,
    const float* __restrict__ bb, const float* __restrict__ ab,
    ushort* __restrict__ dstW, float* __restrict__ dstQB,
    const float4* __restrict__ src, const float4* __restrict__ pos,
    ushort4* __restrict__ srcb, ushort4* __restrict__ qb)
{
    const int blk = blockIdx.x;
    if (blk < 2817) {
        const int i = blk * 256 + threadIdx.x;
        if (i < 720896) {
            float v;
            if      (i <  65536) v = vw[i];
            else if (i <  98304) v = bw[i -  65536];
            else if (i < 131072) v = aw[i -  98304];
            else if (i < 196608) v = ow[i - 131072];
            else if (i < 458752) v = l1[i - 196608];
            else                 v = l2[i - 458752];
            dstW[i] = f2bu(v);
        } else if (i < 721152) {
            const int j = i - 720896;
            dstQB[j] = (j < 128) ? bb[j] : ab[j - 128];
        }
    } else {
        const int i = (blk - 2817) * 256 + threadIdx.x;
        if (i >= TOKENS * 64) return;
        const float4 s = src[i], p = pos[i];
        ushort4 us, uq;
        us.x = f2bu(s.x); us.y = f2bu(s.y); us.z = f2bu(s.z); us.w = f2bu(s.w);
        uq.x = f2bu(s.x + p.x); uq.y = f2bu(s.y + p.y);
        uq.z = f2bu(s.z + p.z); uq.w = f2bu(s.w + p.w);
        srcb[i] = us; qb[i] = uq;
    }
}

// ---------------------------------------------------------------------------
// Fused box prep + sample v2. Block = 4 tokens (32 units of (token,head)).
// Phase 1: thread = (unit, 2 points). 8-lane shfl softmax; box/bilinear math
//   once per point; emit {4x u32 byte-offset, 4x f32 premult weight} to LDS
//   (unit stride 33*16B -> phase-2 reads conflict-free).
// Phase 2: thread = (unit, 4-dim slot). Per corner: 1 global dwordx2 +
//   4 unpack + 2 packed-f32 fma.
// ---------------------------------------------------------------------------
__global__ __launch_bounds__(256) void box_fused(
    const ushort* __restrict__ val,    // (B*SLEN, 256) bf16
    const ushort* __restrict__ qout,   // (t,256): off[128] | logits[128] bf16
    const float* __restrict__ refw,    // (t,4)
    const float* __restrict__ vratio,  // (B,4,2)
    ushort* __restrict__ attnout)      // (t,256) bf16
{
    __shared__ uint4 pd[32 * 33];      // 16,896 B
    const int tid = threadIdx.x;
    const int t0 = blockIdx.x * 4;

    // ---------------- phase 1 ----------------
    {
        const int u = tid >> 3, pp = tid & 7;
        const int t = min(t0 + (u >> 3), TOKENS - 1);
        const int h = u & 7;
        const int b = (t >= SLEN) ? 1 : 0;
        const ushort* qr = qout + (size_t)t * 256;

        const float l0 = bu2f(qr[128 + h * 16 + pp]);
        const float l1 = bu2f(qr[128 + h * 16 + pp + 8]);
        float mx = fmaxf(l0, l1);
        #pragma unroll
        for (int o = 1; o < 8; o <<= 1) mx = fmaxf(mx, __shfl_xor(mx, o));
        const float e0 = __expf(l0 - mx), e1 = __expf(l1 - mx);
        float ss = e0 + e1;
        #pragma unroll
        for (int o = 1; o < 8; o <<= 1) ss += __shfl_xor(ss, o);
        const float inv = 1.f / ss;

        const float4 rw = *reinterpret_cast<const float4*>(refw + (size_t)t * 4);

        #pragma unroll
        for (int j = 0; j < 2; ++j) {
            const int p = pp + j * 8;
            const int lvl = p >> 2, k = p & 3;
            const float wp = (j ? e1 : e0) * inv;

            const uint2 ou = *reinterpret_cast<const uint2*>(qr + h * 16 + lvl * 4);
            const float o0 = __uint_as_float(ou.x << 16) * 0.125f;
            const float o1 = __uint_as_float(ou.x & 0xFFFF0000u) * 0.125f;
            const float o2 = __uint_as_float(ou.y << 16) * 0.125f;
            const float o3 = __uint_as_float(ou.y & 0xFFFF0000u) * 0.125f;

            const int Ww = (lvl == 0) ? 92 : (lvl == 1) ? 46 : (lvl == 2) ? 23 : 12;
            const int s0 = (lvl == 0) ? 0 : (lvl == 1) ? 8464 : (lvl == 2) ? 10580 : 11109;
            const float vrx = vratio[(b * 4 + lvl) * 2 + 0];
            const float vry = vratio[(b * 4 + lvl) * 2 + 1];

            const float bx  = rw.x + o0 * rw.z;
            const float by  = rw.y + o1 * rw.w;
            const float bwd = fmaxf(rw.z + o2 * rw.z, 0.f);
            const float bhd = fmaxf(rw.w + o3 * rw.w, 0.f);
            const float jx = (k & 1) ? 0.25f : -0.25f;
            const float iy = (k & 2) ? 0.25f : -0.25f;
            const float px = (bx + jx * bwd) * vrx * (float)Ww - 0.5f;
            const float py = (by + iy * bhd) * vry * (float)Ww - 0.5f;
            const float x0f = floorf(px), y0f = floorf(py);
            const int x0 = (int)x0f, y0 = (int)y0f;
            const float wx = px - x0f, wy = py - y0f;

            const bool vx0 = (x0 >= 0) && (x0 < Ww);
            const bool vx1 = (x0 + 1 >= 0) && (x0 + 1 < Ww);
            const bool vy0 = (y0 >= 0) && (y0 < Ww);
            const bool vy1 = (y0 + 1 >= 0) && (y0 + 1 < Ww);
            const int cx0 = min(max(x0, 0), Ww - 1);
            const int cx1 = min(max(x0 + 1, 0), Ww - 1);
            const int cy0 = min(max(y0, 0), Ww - 1);
            const int cy1 = min(max(y0 + 1, 0), Ww - 1);

            float4 w4;
            w4.x = (vx0 && vy0) ? wp * (1.f - wx) * (1.f - wy) : 0.f;
            w4.y = (vx1 && vy0) ? wp * wx         * (1.f - wy) : 0.f;
            w4.z = (vx0 && vy1) ? wp * (1.f - wx) * wy         : 0.f;
            w4.w = (vx1 && vy1) ? wp * wx         * wy         : 0.f;

            const uint hb_ = (uint)h * 64u;
            uint4 off4;
            off4.x = (uint)(s0 + cy0 * Ww + cx0) * 512u + hb_;
            off4.y = (uint)(s0 + cy0 * Ww + cx1) * 512u + hb_;
            off4.z = (uint)(s0 + cy1 * Ww + cx0) * 512u + hb_;
            off4.w = (uint)(s0 + cy1 * Ww + cx1) * 512u + hb_;

            pd[u * 33 + p * 2]     = off4;
            *reinterpret_cast<float4*>(&pd[u * 33 + p * 2 + 1]) = w4;
        }
    }
    __syncthreads();

    // ---------------- phase 2 ----------------
    const int u = tid >> 3, dl = tid & 7;
    const int traw = t0 + (u >> 3);
    const int t = min(traw, TOKENS - 1);
    const int h = u & 7;
    // base covers batch + dim-slot; per-corner offset adds row*512 + h*64
    const char* vb = (const char*)val + (size_t)((t >= SLEN) ? SLEN * 512u : 0u)
                     + (uint)dl * 8u;

    const uint4* pu = &pd[u * 33];
    f32x2 a01 = {0.f, 0.f}, a23 = {0.f, 0.f};
    #pragma unroll 4
    for (int p = 0; p < 16; ++p) {
        const uint4 off4 = pu[p * 2];
        const float4 w4 = *reinterpret_cast<const float4*>(&pu[p * 2 + 1]);
        #pragma unroll
        for (int c = 0; c < 4; ++c) {
            const uint off = (c == 0) ? off4.x : (c == 1) ? off4.y
                           : (c == 2) ? off4.z : off4.w;
            const float w  = (c == 0) ? w4.x : (c == 1) ? w4.y
                           : (c == 2) ? w4.z : w4.w;
            const uint2 vv = *reinterpret_cast<const uint2*>(vb + off);
            f32x2 va, vc;
            va.x = __uint_as_float(vv.x << 16);
            va.y = __uint_as_float(vv.x & 0xFFFF0000u);
            vc.x = __uint_as_float(vv.y << 16);
            vc.y = __uint_as_float(vv.y & 0xFFFF0000u);
            f32x2 wv; wv.x = w; wv.y = w;
            a01 += wv * va;
            a23 += wv * vc;
        }
    }
    if (traw < TOKENS) {
        uint2 o;
        o.x = (uint)f2bu(a01.x) | ((uint)f2bu(a01.y) << 16);
        o.y = (uint)f2bu(a23.x) | ((uint)f2bu(a23.y) << 16);
        *reinterpret_cast<uint2*>(attnout + (size_t)t * 256 + h * 32 + dl * 4) = o;
    }
}

// ---------------------------------------------------------------------------
// LayerNorm(a + b): wave per row, thread handles 4 cols, shuffle reduction,
// 4 rows/block. b always bf16. AF32: a f32 vs bf16. OUTF32: f32 vs bf16 out.
// ---------------------------------------------------------------------------
template<bool AF32, bool OUTF32>
__global__ __launch_bounds__(256) void ln_add2(
    const void* __restrict__ aptr, const ushort* __restrict__ bptr,
    const float* __restrict__ w, const float* __restrict__ bias,
    void* __restrict__ outp, int nrows)
{
    const int lane = threadIdx.x & 63, wv = threadIdx.x >> 6;
    const int row = blockIdx.x * 4 + wv;
    if (row >= nrows) return;
    const size_t base = (size_t)row * 256 + lane * 4;

    float4 av;
    if (AF32) {
        av = *reinterpret_cast<const float4*>((const float*)aptr + base);
    } else {
        const ushort4 u = *reinterpret_cast<const ushort4*>((const ushort*)aptr + base);
        av = make_float4(bu2f(u.x), bu2f(u.y), bu2f(u.z), bu2f(u.w));
    }
    const ushort4 ub = *reinterpret_cast<const ushort4*>(bptr + base);
    const float v0 = av.x + bu2f(ub.x), v1 = av.y + bu2f(ub.y);
    const float v2 = av.z + bu2f(ub.z), v3 = av.w + bu2f(ub.w);

    float s = v0 + v1 + v2 + v3;
    #pragma unroll
    for (int o = 32; o; o >>= 1) s += __shfl_xor(s, o);
    const float mu = s * (1.f / 256.f);
    const float d0 = v0 - mu, d1 = v1 - mu, d2 = v2 - mu, d3 = v3 - mu;
    float s2 = d0 * d0 + d1 * d1 + d2 * d2 + d3 * d3;
    #pragma unroll
    for (int o = 32; o; o >>= 1) s2 += __shfl_xor(s2, o);
    const float rs = rsqrtf(s2 * (1.f / 256.f) + 1e-5f);

    const float4 w4 = *reinterpret_cast<const float4*>(w + lane * 4);
    const float4 g4 = *reinterpret_cast<const float4*>(bias + lane * 4);
    const float r0 = d0 * rs * w4.x + g4.x;
    const float r1 = d1 * rs * w4.y + g4.y;
    const float r2 = d2 * rs * w4.z + g4.z;
    const float r3 = d3 * rs * w4.w + g4.w;
    if (OUTF32) {
        *reinterpret_cast<float4*>((float*)outp + base) = make_float4(r0, r1, r2, r3);
    } else {
        ushort4 u;
        u.x = f2bu(r0); u.y = f2bu(r1); u.z = f2bu(r2); u.w = f2bu(r3);
        *reinterpret_cast<ushort4*>((ushort*)outp + base) = u;
    }
}

// ---------------------------------------------------------------------------
extern "C" void kernel_launch(void* const* d_in, const int* in_sizes, int n_in,
                              void* d_out, int out_size, void* d_ws, size_t ws_size,
                              hipStream_t stream)
{
    const float* src     = (const float*)d_in[0];
    const float* pos     = (const float*)d_in[1];
    const float* vratio  = (const float*)d_in[5];
    const float* refw    = (const float*)d_in[6];
    const float* value_w = (const float*)d_in[7];
    const float* value_b = (const float*)d_in[8];
    const float* out_w   = (const float*)d_in[9];
    const float* out_b   = (const float*)d_in[10];
    const float* box_w   = (const float*)d_in[11];
    const float* box_b   = (const float*)d_in[12];
    const float* attn_w  = (const float*)d_in[13];
    const float* attn_b  = (const float*)d_in[14];
    const float* lin1_w  = (const float*)d_in[15];
    const float* lin1_b  = (const float*)d_in[16];
    const float* lin2_w  = (const float*)d_in[17];
    const float* lin2_b  = (const float*)d_in[18];
    const float* n1w     = (const float*)d_in[19];
    const float* n1b     = (const float*)d_in[20];
    const float* n2w     = (const float*)d_in[21];
    const float* n2b     = (const float*)d_in[22];

    // flat workspace layout (~140 MB of 256 MiB)
    char* wsb = (char*)d_ws;
    ushort* Wb    = (ushort*)(wsb);                  // 1,441,792 B
    float*  qcb   = (float*)(wsb + 1441792);         // 1 KB
    ushort* srcb  = (ushort*)(wsb + 1442816);        // 11.5 MB bf16 src
    ushort* qb    = (ushort*)(wsb + 12965888);       // 11.5 MB bf16 src+pos
    ushort* valb  = (ushort*)(wsb + 24488960);       // 11.5 MB value
    ushort* qoutb = (ushort*)(wsb + 36012032);       // 11.5 MB off+logits
    ushort* attb  = (ushort*)(wsb + 47535104);       // 11.5 MB attn out
    ushort* src2b = (ushort*)(wsb + 59058176);       // 11.5 MB src2 bf16
    ushort* xbb   = (ushort*)(wsb + 70581248);       // 11.5 MB x bf16
    ushort* hb    = (ushort*)(wsb + 82104320);       // 46.1 MB hidden
    ushort* yb    = (ushort*)(wsb + 128196608);      // 11.5 MB y bf16

    const dim3 blk(256);

    // one-time prep (weights + input cvt) in a single launch
    prep_all<<<dim3(8444), blk, 0, stream>>>(
        value_w, box_w, attn_w, out_w, lin1_w, lin2_w, box_b, attn_b, Wb, qcb,
        (const float4*)src, (const float4*)pos, (ushort4*)srcb, (ushort4*)qb);

    // merged: z=0 value = src @ value_w^T ; z=1 qout = q @ [box;attn]^T
    gemm_small<false><<<dim3(352, 2, 2), blk, 0, stream>>>(
        srcb, Wb, value_b, valb,
        qb, Wb + 65536, qcb, qoutb, TOKENS, 256, 256);

    // fused prep + gather (4 tokens/block)
    box_fused<<<dim3((TOKENS + 3) / 4), blk, 0, stream>>>(
        valb, qoutb, refw, vratio, attb);

    // src2 = attnout @ out_w^T + b -> bf16
    gemm_small<false><<<dim3(352, 2, 1), blk, 0, stream>>>(
        attb, Wb + 131072, out_b, src2b,
        attb, Wb + 131072, out_b, src2b, TOKENS, 256, 256);
    // x = LN1(src + src2) -> bf16
    ln_add2<true, false><<<dim3((TOKENS + 3) / 4), blk, 0, stream>>>(
        src, src2b, n1w, n1b, xbb, TOKENS);
    // h = relu(x @ lin1_w^T + b) -> bf16 (nontemporal C stores)
    gemm128<true, true><<<dim3(176, 8), blk, 0, stream>>>(
        xbb, Wb + 196608, lin1_b, hb, TOKENS, 1024, 256);
    // y = h @ lin2_w^T + b -> bf16
    gemm_small<false><<<dim3(352, 2, 1), blk, 0, stream>>>(
        hb, Wb + 458752, lin2_b, yb,
        hb, Wb + 458752, lin2_b, yb, TOKENS, 256, 1024);
    // out = LN2(x + y) -> f32
    ln_add2<false, true><<<dim3((TOKENS + 3) / 4), blk, 0, stream>>>(
        xbb, yb, n2w, n2b, (float*)d_out, TOKENS);
}

// Round 9
// 153.262 us; speedup vs baseline: 5.2101x; 1.0910x over previous
//
#include <hip/hip_runtime.h>
#include <hip/hip_bf16.h>

#define TOKENS 22506
#define SLEN   11253

typedef __bf16 bf16x8 __attribute__((ext_vector_type(8)));
typedef float  f32x4  __attribute__((ext_vector_type(4)));
typedef float  f32x2  __attribute__((ext_vector_type(2)));
typedef uint   u32x4  __attribute__((ext_vector_type(4)));

__device__ __forceinline__ ushort f2bu(float f) {
    __hip_bfloat16 h = __float2bfloat16(f);   // RNE
    return *reinterpret_cast<ushort*>(&h);
}
__device__ __forceinline__ float bu2f(ushort u) {
    return __uint_as_float((uint)u << 16);
}
__device__ __forceinline__ void gl16(const ushort* g, ushort* l) {
    __builtin_amdgcn_global_load_lds(
        (__attribute__((address_space(1))) void*)(g),
        (__attribute__((address_space(3))) void*)(l), 16, 0, 0);
}

// ---------------------------------------------------------------------------
// 64x128-tile MFMA GEMM (high-TLP variant for N=256 GEMMs).
// C = A(bf16) @ W(bf16)^T + bias, bf16 out. BK=32, 256 thr = 4 waves (2x2),
// each wave 32x64 (acc[2][4]). global_load_lds staging, double-buffered.
// Epilogue: acc -> LDS bf16 (padded rows) -> coalesced dwordx4 stores.
// blockIdx.z selects source set.
// ---------------------------------------------------------------------------
template<bool RELU>
__global__ __launch_bounds__(256) void gemm_small(
    const ushort* __restrict__ A0, const ushort* __restrict__ W0,
    const float* __restrict__ b0, ushort* __restrict__ C0,
    const ushort* __restrict__ A1, const ushort* __restrict__ W1,
    const float* __restrict__ b1, ushort* __restrict__ C1,
    int M, int N, int K)
{
    const bool zz = blockIdx.z != 0;
    const ushort* A   = zz ? A1 : A0;
    const ushort* W   = zz ? W1 : W0;
    const float* bias = zz ? b1 : b0;
    ushort* Cptr      = zz ? C1 : C0;

    __shared__ ushort smem[12288];           // 24 KB
    const int tid  = threadIdx.x;
    const int lane = tid & 63;
    const int wid  = tid >> 6;
    const int wr = wid >> 1, wc = wid & 1;
    const int m0 = blockIdx.x * 64, n0 = blockIdx.y * 128;
    const int lrow = lane & 15, lhi = lane >> 4;

    const int arow = tid >> 2;               // 0..63
    const int scol = (tid & 3) << 3;
    const ushort* ga  = A + (size_t)min(m0 + arow, M - 1) * K + scol;
    const ushort* gb0 = W + (size_t)(n0 + arow)      * K + scol;
    const ushort* gb1 = W + (size_t)(n0 + arow + 64) * K + scol;

    f32x4 acc[2][4] = {};
    const int NT = K >> 5;

    gl16(ga,  &smem[tid * 8]);
    gl16(gb0, &smem[4096 + tid * 8]);
    gl16(gb1, &smem[4096 + tid * 8 + 2048]);

    int cur = 0;
    for (int t = 0; t < NT; ++t) {
        __syncthreads();
        if (t + 1 < NT) {
            const int k0 = (t + 1) << 5;
            const int nb = cur ^ 1;
            gl16(ga  + k0, &smem[nb * 2048 + tid * 8]);
            gl16(gb0 + k0, &smem[4096 + nb * 4096 + tid * 8]);
            gl16(gb1 + k0, &smem[4096 + nb * 4096 + tid * 8 + 2048]);
        }
        bf16x8 afr[2], bfr[4];
        #pragma unroll
        for (int m = 0; m < 2; ++m)
            afr[m] = *reinterpret_cast<const bf16x8*>(
                &smem[cur * 2048 + (wr * 32 + m * 16 + lrow) * 32 + lhi * 8]);
        #pragma unroll
        for (int n = 0; n < 4; ++n)
            bfr[n] = *reinterpret_cast<const bf16x8*>(
                &smem[4096 + cur * 4096 + (wc * 64 + n * 16 + lrow) * 32 + lhi * 8]);
        #pragma unroll
        for (int m = 0; m < 2; ++m)
            #pragma unroll
            for (int n = 0; n < 4; ++n)
                acc[m][n] = __builtin_amdgcn_mfma_f32_16x16x32_bf16(
                    afr[m], bfr[n], acc[m][n], 0, 0, 0);
        cur ^= 1;
    }

    // epilogue: regs -> LDS (padded 136-elem rows) -> coalesced stores
    __syncthreads();
    #pragma unroll
    for (int m = 0; m < 2; ++m) {
        #pragma unroll
        for (int n = 0; n < 4; ++n) {
            const int col = wc * 64 + n * 16 + lrow;
            const float bv = bias[n0 + col];
            #pragma unroll
            for (int r = 0; r < 4; ++r) {
                const int row = wr * 32 + m * 16 + lhi * 4 + r;
                float v = acc[m][n][r] + bv;
                if (RELU) v = fmaxf(v, 0.f);
                smem[row * 136 + col] = f2bu(v);
            }
        }
    }
    __syncthreads();
    #pragma unroll
    for (int i = 0; i < 4; ++i) {
        const int e = tid + i * 256;
        const int row = e >> 4, ch = e & 15;
        if (m0 + row < M) {
            const u32x4 v = *reinterpret_cast<const u32x4*>(&smem[row * 136 + ch * 8]);
            *reinterpret_cast<u32x4*>(Cptr + (size_t)(m0 + row) * N + n0 + ch * 8) = v;
        }
    }
}

// ---------------------------------------------------------------------------
// 128x128-tile MFMA GEMM (lin1). Same structure; NTSTORE = nontemporal C.
// ---------------------------------------------------------------------------
template<bool RELU, bool NTSTORE>
__global__ __launch_bounds__(256) void gemm128(
    const ushort* __restrict__ A, const ushort* __restrict__ W,
    const float* __restrict__ bias, ushort* __restrict__ Cptr,
    int M, int N, int K)
{
    __shared__ ushort smem[17408];           // 34,816 B
    const int tid  = threadIdx.x;
    const int lane = tid & 63;
    const int wid  = tid >> 6;
    const int wr = wid >> 1, wc = wid & 1;
    const int m0 = blockIdx.x * 128, n0 = blockIdx.y * 128;
    const int lrow = lane & 15, lhi = lane >> 4;

    const int arow = tid >> 2;
    const int scol = (tid & 3) << 3;
    const ushort* ga0 = A + (size_t)min(m0 + arow,      M - 1) * K + scol;
    const ushort* ga1 = A + (size_t)min(m0 + arow + 64, M - 1) * K + scol;
    const ushort* gb0 = W + (size_t)(n0 + arow)      * K + scol;
    const ushort* gb1 = W + (size_t)(n0 + arow + 64) * K + scol;

    f32x4 acc[4][4] = {};
    const int NT = K >> 5;

    gl16(ga0, &smem[tid * 8]);
    gl16(ga1, &smem[tid * 8 + 2048]);
    gl16(gb0, &smem[8192 + tid * 8]);
    gl16(gb1, &smem[8192 + tid * 8 + 2048]);

    int cur = 0;
    for (int t = 0; t < NT; ++t) {
        __syncthreads();
        if (t + 1 < NT) {
            const int k0 = (t + 1) << 5;
            const int nb = cur ^ 1;
            gl16(ga0 + k0, &smem[nb * 4096 + tid * 8]);
            gl16(ga1 + k0, &smem[nb * 4096 + tid * 8 + 2048]);
            gl16(gb0 + k0, &smem[8192 + nb * 4096 + tid * 8]);
            gl16(gb1 + k0, &smem[8192 + nb * 4096 + tid * 8 + 2048]);
        }
        bf16x8 afr[4], bfr[4];
        #pragma unroll
        for (int m = 0; m < 4; ++m)
            afr[m] = *reinterpret_cast<const bf16x8*>(
                &smem[cur * 4096 + (wr * 64 + m * 16 + lrow) * 32 + lhi * 8]);
        #pragma unroll
        for (int n = 0; n < 4; ++n)
            bfr[n] = *reinterpret_cast<const bf16x8*>(
                &smem[8192 + cur * 4096 + (wc * 64 + n * 16 + lrow) * 32 + lhi * 8]);
        #pragma unroll
        for (int m = 0; m < 4; ++m)
            #pragma unroll
            for (int n = 0; n < 4; ++n)
                acc[m][n] = __builtin_amdgcn_mfma_f32_16x16x32_bf16(
                    afr[m], bfr[n], acc[m][n], 0, 0, 0);
        cur ^= 1;
    }

    __syncthreads();
    #pragma unroll
    for (int m = 0; m < 4; ++m) {
        #pragma unroll
        for (int n = 0; n < 4; ++n) {
            const int col = wc * 64 + n * 16 + lrow;
            const float bv = bias[n0 + col];
            #pragma unroll
            for (int r = 0; r < 4; ++r) {
                const int row = wr * 64 + m * 16 + lhi * 4 + r;
                float v = acc[m][n][r] + bv;
                if (RELU) v = fmaxf(v, 0.f);
                smem[row * 136 + col] = f2bu(v);
            }
        }
    }
    __syncthreads();
    #pragma unroll
    for (int i = 0; i < 8; ++i) {
        const int e = tid + i * 256;
        const int row = e >> 4, ch = e & 15;
        if (m0 + row < M) {
            const u32x4 v = *reinterpret_cast<const u32x4*>(&smem[row * 136 + ch * 8]);
            u32x4* dst = reinterpret_cast<u32x4*>(Cptr + (size_t)(m0 + row) * N + n0 + ch * 8);
            if (NTSTORE) __builtin_nontemporal_store(v, dst);
            else *dst = v;
        }
    }
}

// ---------------------------------------------------------------------------
// Merged one-time prep: weight f32->bf16 pack + cat bias  AND  input cvt.
// ---------------------------------------------------------------------------
__global__ __launch_bounds__(256) void prep_all(
    const float* __restrict__ vw, const float* __restrict__ bw,
    const float* __restrict__ aw, const float* __restrict__ ow,
    const float* __restrict__ l1, const float* __restrict__ l2,
    const float* __restrict__ bb, const float* __restrict__ ab,
    ushort* __restrict__ dstW, float* __restrict__ dstQB,
    const float4* __restrict__ src, const float4* __restrict__ pos,
    ushort4* __restrict__ srcb, ushort4* __restrict__ qb)
{
    const int blk = blockIdx.x;
    if (blk < 2817) {
        const int i = blk * 256 + threadIdx.x;
        if (i < 720896) {
            float v;
            if      (i <  65536) v = vw[i];
            else if (i <  98304) v = bw[i -  65536];
            else if (i < 131072) v = aw[i -  98304];
            else if (i < 196608) v = ow[i - 131072];
            else if (i < 458752) v = l1[i - 196608];
            else                 v = l2[i - 458752];
            dstW[i] = f2bu(v);
        } else if (i < 721152) {
            const int j = i - 720896;
            dstQB[j] = (j < 128) ? bb[j] : ab[j - 128];
        }
    } else {
        const int i = (blk - 2817) * 256 + threadIdx.x;
        if (i >= TOKENS * 64) return;
        const float4 s = src[i], p = pos[i];
        ushort4 us, uq;
        us.x = f2bu(s.x); us.y = f2bu(s.y); us.z = f2bu(s.z); us.w = f2bu(s.w);
        uq.x = f2bu(s.x + p.x); uq.y = f2bu(s.y + p.y);
        uq.z = f2bu(s.z + p.z); uq.w = f2bu(s.w + p.w);
        srcb[i] = us; qb[i] = uq;
    }
}

// ---------------------------------------------------------------------------
// Fused box prep + sample v3. Block = 4 tokens (32 units of (token,head)).
// Phase 1: unchanged from v2 (thread = (unit, 2 points), 8-lane softmax).
// Phase 2: thread = (unit, 4-dim slot); points processed in GROUPS OF 4 with
//   all 16 corner uint2 loads batched into registers before consumption
//   (fully unrolled, compile-time indices) -> 16 loads in flight per group,
//   4 stall points per thread instead of 64 (fixes v2's MLP=1 latency bind).
// ---------------------------------------------------------------------------
__global__ __launch_bounds__(256) void box_fused(
    const ushort* __restrict__ val,    // (B*SLEN, 256) bf16
    const ushort* __restrict__ qout,   // (t,256): off[128] | logits[128] bf16
    const float* __restrict__ refw,    // (t,4)
    const float* __restrict__ vratio,  // (B,4,2)
    ushort* __restrict__ attnout)      // (t,256) bf16
{
    __shared__ uint4 pd[32 * 33];      // 16,896 B
    const int tid = threadIdx.x;
    const int t0 = blockIdx.x * 4;

    // ---------------- phase 1 ----------------
    {
        const int u = tid >> 3, pp = tid & 7;
        const int t = min(t0 + (u >> 3), TOKENS - 1);
        const int h = u & 7;
        const int b = (t >= SLEN) ? 1 : 0;
        const ushort* qr = qout + (size_t)t * 256;

        const float l0 = bu2f(qr[128 + h * 16 + pp]);
        const float l1 = bu2f(qr[128 + h * 16 + pp + 8]);
        float mx = fmaxf(l0, l1);
        #pragma unroll
        for (int o = 1; o < 8; o <<= 1) mx = fmaxf(mx, __shfl_xor(mx, o));
        const float e0 = __expf(l0 - mx), e1 = __expf(l1 - mx);
        float ss = e0 + e1;
        #pragma unroll
        for (int o = 1; o < 8; o <<= 1) ss += __shfl_xor(ss, o);
        const float inv = 1.f / ss;

        const float4 rw = *reinterpret_cast<const float4*>(refw + (size_t)t * 4);

        #pragma unroll
        for (int j = 0; j < 2; ++j) {
            const int p = pp + j * 8;
            const int lvl = p >> 2, k = p & 3;
            const float wp = (j ? e1 : e0) * inv;

            const uint2 ou = *reinterpret_cast<const uint2*>(qr + h * 16 + lvl * 4);
            const float o0 = __uint_as_float(ou.x << 16) * 0.125f;
            const float o1 = __uint_as_float(ou.x & 0xFFFF0000u) * 0.125f;
            const float o2 = __uint_as_float(ou.y << 16) * 0.125f;
            const float o3 = __uint_as_float(ou.y & 0xFFFF0000u) * 0.125f;

            const int Ww = (lvl == 0) ? 92 : (lvl == 1) ? 46 : (lvl == 2) ? 23 : 12;
            const int s0 = (lvl == 0) ? 0 : (lvl == 1) ? 8464 : (lvl == 2) ? 10580 : 11109;
            const float vrx = vratio[(b * 4 + lvl) * 2 + 0];
            const float vry = vratio[(b * 4 + lvl) * 2 + 1];

            const float bx  = rw.x + o0 * rw.z;
            const float by  = rw.y + o1 * rw.w;
            const float bwd = fmaxf(rw.z + o2 * rw.z, 0.f);
            const float bhd = fmaxf(rw.w + o3 * rw.w, 0.f);
            const float jx = (k & 1) ? 0.25f : -0.25f;
            const float iy = (k & 2) ? 0.25f : -0.25f;
            const float px = (bx + jx * bwd) * vrx * (float)Ww - 0.5f;
            const float py = (by + iy * bhd) * vry * (float)Ww - 0.5f;
            const float x0f = floorf(px), y0f = floorf(py);
            const int x0 = (int)x0f, y0 = (int)y0f;
            const float wx = px - x0f, wy = py - y0f;

            const bool vx0 = (x0 >= 0) && (x0 < Ww);
            const bool vx1 = (x0 + 1 >= 0) && (x0 + 1 < Ww);
            const bool vy0 = (y0 >= 0) && (y0 < Ww);
            const bool vy1 = (y0 + 1 >= 0) && (y0 + 1 < Ww);
            const int cx0 = min(max(x0, 0), Ww - 1);
            const int cx1 = min(max(x0 + 1, 0), Ww - 1);
            const int cy0 = min(max(y0, 0), Ww - 1);
            const int cy1 = min(max(y0 + 1, 0), Ww - 1);

            float4 w4;
            w4.x = (vx0 && vy0) ? wp * (1.f - wx) * (1.f - wy) : 0.f;
            w4.y = (vx1 && vy0) ? wp * wx         * (1.f - wy) : 0.f;
            w4.z = (vx0 && vy1) ? wp * (1.f - wx) * wy         : 0.f;
            w4.w = (vx1 && vy1) ? wp * wx         * wy         : 0.f;

            const uint hb_ = (uint)h * 64u;
            uint4 off4;
            off4.x = (uint)(s0 + cy0 * Ww + cx0) * 512u + hb_;
            off4.y = (uint)(s0 + cy0 * Ww + cx1) * 512u + hb_;
            off4.z = (uint)(s0 + cy1 * Ww + cx0) * 512u + hb_;
            off4.w = (uint)(s0 + cy1 * Ww + cx1) * 512u + hb_;

            pd[u * 33 + p * 2]     = off4;
            *reinterpret_cast<float4*>(&pd[u * 33 + p * 2 + 1]) = w4;
        }
    }
    __syncthreads();

    // ---------------- phase 2 (grouped, MLP=16) ----------------
    const int u = tid >> 3, dl = tid & 7;
    const int traw = t0 + (u >> 3);
    const int t = min(traw, TOKENS - 1);
    const int h = u & 7;
    const char* vb = (const char*)val + (size_t)((t >= SLEN) ? SLEN * 512u : 0u)
                     + (uint)dl * 8u;

    const uint4* pu = &pd[u * 33];
    f32x2 a01 = {0.f, 0.f}, a23 = {0.f, 0.f};

    #pragma unroll
    for (int g = 0; g < 4; ++g) {
        // read the 4 points' metadata (broadcast ds_reads)
        uint4  off4[4];
        float4 ww[4];
        #pragma unroll
        for (int q = 0; q < 4; ++q) {
            off4[q] = pu[(g * 4 + q) * 2];
            ww[q]   = *reinterpret_cast<const float4*>(&pu[(g * 4 + q) * 2 + 1]);
        }
        // issue all 16 corner loads (independent -> stay in flight together)
        uint2 vv[16];
        #pragma unroll
        for (int q = 0; q < 4; ++q) {
            vv[q * 4 + 0] = *reinterpret_cast<const uint2*>(vb + off4[q].x);
            vv[q * 4 + 1] = *reinterpret_cast<const uint2*>(vb + off4[q].y);
            vv[q * 4 + 2] = *reinterpret_cast<const uint2*>(vb + off4[q].z);
            vv[q * 4 + 3] = *reinterpret_cast<const uint2*>(vb + off4[q].w);
        }
        // consume
        #pragma unroll
        for (int q = 0; q < 4; ++q) {
            #pragma unroll
            for (int c = 0; c < 4; ++c) {
                const float w = (c == 0) ? ww[q].x : (c == 1) ? ww[q].y
                              : (c == 2) ? ww[q].z : ww[q].w;
                const uint2 v2 = vv[q * 4 + c];
                f32x2 va, vc;
                va.x = __uint_as_float(v2.x << 16);
                va.y = __uint_as_float(v2.x & 0xFFFF0000u);
                vc.x = __uint_as_float(v2.y << 16);
                vc.y = __uint_as_float(v2.y & 0xFFFF0000u);
                f32x2 wv; wv.x = w; wv.y = w;
                a01 += wv * va;
                a23 += wv * vc;
            }
        }
    }
    if (traw < TOKENS) {
        uint2 o;
        o.x = (uint)f2bu(a01.x) | ((uint)f2bu(a01.y) << 16);
        o.y = (uint)f2bu(a23.x) | ((uint)f2bu(a23.y) << 16);
        *reinterpret_cast<uint2*>(attnout + (size_t)t * 256 + h * 32 + dl * 4) = o;
    }
}

// ---------------------------------------------------------------------------
// LayerNorm(a + b): wave per row, thread handles 4 cols, shuffle reduction,
// 4 rows/block. b always bf16. AF32: a f32 vs bf16. OUTF32: f32 vs bf16 out.
// ---------------------------------------------------------------------------
template<bool AF32, bool OUTF32>
__global__ __launch_bounds__(256) void ln_add2(
    const void* __restrict__ aptr, const ushort* __restrict__ bptr,
    const float* __restrict__ w, const float* __restrict__ bias,
    void* __restrict__ outp, int nrows)
{
    const int lane = threadIdx.x & 63, wv = threadIdx.x >> 6;
    const int row = blockIdx.x * 4 + wv;
    if (row >= nrows) return;
    const size_t base = (size_t)row * 256 + lane * 4;

    float4 av;
    if (AF32) {
        av = *reinterpret_cast<const float4*>((const float*)aptr + base);
    } else {
        const ushort4 u = *reinterpret_cast<const ushort4*>((const ushort*)aptr + base);
        av = make_float4(bu2f(u.x), bu2f(u.y), bu2f(u.z), bu2f(u.w));
    }
    const ushort4 ub = *reinterpret_cast<const ushort4*>(bptr + base);
    const float v0 = av.x + bu2f(ub.x), v1 = av.y + bu2f(ub.y);
    const float v2 = av.z + bu2f(ub.z), v3 = av.w + bu2f(ub.w);

    float s = v0 + v1 + v2 + v3;
    #pragma unroll
    for (int o = 32; o; o >>= 1) s += __shfl_xor(s, o);
    const float mu = s * (1.f / 256.f);
    const float d0 = v0 - mu, d1 = v1 - mu, d2 = v2 - mu, d3 = v3 - mu;
    float s2 = d0 * d0 + d1 * d1 + d2 * d2 + d3 * d3;
    #pragma unroll
    for (int o = 32; o; o >>= 1) s2 += __shfl_xor(s2, o);
    const float rs = rsqrtf(s2 * (1.f / 256.f) + 1e-5f);

    const float4 w4 = *reinterpret_cast<const float4*>(w + lane * 4);
    const float4 g4 = *reinterpret_cast<const float4*>(bias + lane * 4);
    const float r0 = d0 * rs * w4.x + g4.x;
    const float r1 = d1 * rs * w4.y + g4.y;
    const float r2 = d2 * rs * w4.z + g4.z;
    const float r3 = d3 * rs * w4.w + g4.w;
    if (OUTF32) {
        *reinterpret_cast<float4*>((float*)outp + base) = make_float4(r0, r1, r2, r3);
    } else {
        ushort4 u;
        u.x = f2bu(r0); u.y = f2bu(r1); u.z = f2bu(r2); u.w = f2bu(r3);
        *reinterpret_cast<ushort4*>((ushort*)outp + base) = u;
    }
}

// ---------------------------------------------------------------------------
extern "C" void kernel_launch(void* const* d_in, const int* in_sizes, int n_in,
                              void* d_out, int out_size, void* d_ws, size_t ws_size,
                              hipStream_t stream)
{
    const float* src     = (const float*)d_in[0];
    const float* pos     = (const float*)d_in[1];
    const float* vratio  = (const float*)d_in[5];
    const float* refw    = (const float*)d_in[6];
    const float* value_w = (const float*)d_in[7];
    const float* value_b = (const float*)d_in[8];
    const float* out_w   = (const float*)d_in[9];
    const float* out_b   = (const float*)d_in[10];
    const float* box_w   = (const float*)d_in[11];
    const float* box_b   = (const float*)d_in[12];
    const float* attn_w  = (const float*)d_in[13];
    const float* attn_b  = (const float*)d_in[14];
    const float* lin1_w  = (const float*)d_in[15];
    const float* lin1_b  = (const float*)d_in[16];
    const float* lin2_w  = (const float*)d_in[17];
    const float* lin2_b  = (const float*)d_in[18];
    const float* n1w     = (const float*)d_in[19];
    const float* n1b     = (const float*)d_in[20];
    const float* n2w     = (const float*)d_in[21];
    const float* n2b     = (const float*)d_in[22];

    // flat workspace layout (~140 MB of 256 MiB)
    char* wsb = (char*)d_ws;
    ushort* Wb    = (ushort*)(wsb);                  // 1,441,792 B
    float*  qcb   = (float*)(wsb + 1441792);         // 1 KB
    ushort* srcb  = (ushort*)(wsb + 1442816);        // 11.5 MB bf16 src
    ushort* qb    = (ushort*)(wsb + 12965888);       // 11.5 MB bf16 src+pos
    ushort* valb  = (ushort*)(wsb + 24488960);       // 11.5 MB value
    ushort* qoutb = (ushort*)(wsb + 36012032);       // 11.5 MB off+logits
    ushort* attb  = (ushort*)(wsb + 47535104);       // 11.5 MB attn out
    ushort* src2b = (ushort*)(wsb + 59058176);       // 11.5 MB src2 bf16
    ushort* xbb   = (ushort*)(wsb + 70581248);       // 11.5 MB x bf16
    ushort* hb    = (ushort*)(wsb + 82104320);       // 46.1 MB hidden
    ushort* yb    = (ushort*)(wsb + 128196608);      // 11.5 MB y bf16

    const dim3 blk(256);

    // one-time prep (weights + input cvt) in a single launch
    prep_all<<<dim3(8444), blk, 0, stream>>>(
        value_w, box_w, attn_w, out_w, lin1_w, lin2_w, box_b, attn_b, Wb, qcb,
        (const float4*)src, (const float4*)pos, (ushort4*)srcb, (ushort4*)qb);

    // merged: z=0 value = src @ value_w^T ; z=1 qout = q @ [box;attn]^T
    gemm_small<false><<<dim3(352, 2, 2), blk, 0, stream>>>(
        srcb, Wb, value_b, valb,
        qb, Wb + 65536, qcb, qoutb, TOKENS, 256, 256);

    // fused prep + gather (4 tokens/block)
    box_fused<<<dim3((TOKENS + 3) / 4), blk, 0, stream>>>(
        valb, qoutb, refw, vratio, attb);

    // src2 = attnout @ out_w^T + b -> bf16
    gemm_small<false><<<dim3(352, 2, 1), blk, 0, stream>>>(
        attb, Wb + 131072, out_b, src2b,
        attb, Wb + 131072, out_b, src2b, TOKENS, 256, 256);
    // x = LN1(src + src2) -> bf16
    ln_add2<true, false><<<dim3((TOKENS + 3) / 4), blk, 0, stream>>>(
        src, src2b, n1w, n1b, xbb, TOKENS);
    // h = relu(x @ lin1_w^T + b) -> bf16 (nontemporal C stores)
    gemm128<true, true><<<dim3(176, 8), blk, 0, stream>>>(
        xbb, Wb + 196608, lin1_b, hb, TOKENS, 1024, 256);
    // y = h @ lin2_w^T + b -> bf16
    gemm_small<false><<<dim3(352, 2, 1), blk, 0, stream>>>(
        hb, Wb + 458752, lin2_b, yb,
        hb, Wb + 458752, lin2_b, yb, TOKENS, 256, 1024);
    // out = LN2(x + y) -> f32
    ln_add2<false, true><<<dim3((TOKENS + 3) / 4), blk, 0, stream>>>(
        xbb, yb, n2w, n2b, (float*)d_out, TOKENS);
}

// Round 10
// 148.456 us; speedup vs baseline: 5.3788x; 1.0324x over previous
//
#include <hip/hip_runtime.h>
#include <hip/hip_bf16.h>

#define TOKENS 22506
#define SLEN   11253

typedef __bf16 bf16x8 __attribute__((ext_vector_type(8)));
typedef float  f32x4  __attribute__((ext_vector_type(4)));
typedef float  f32x2  __attribute__((ext_vector_type(2)));
typedef uint   u32x4  __attribute__((ext_vector_type(4)));

__device__ __forceinline__ ushort f2bu(float f) {
    __hip_bfloat16 h = __float2bfloat16(f);   // RNE
    return *reinterpret_cast<ushort*>(&h);
}
__device__ __forceinline__ float bu2f(ushort u) {
    return __uint_as_float((uint)u << 16);
}
__device__ __forceinline__ void gl16(const ushort* g, ushort* l) {
    __builtin_amdgcn_global_load_lds(
        (__attribute__((address_space(1))) void*)(g),
        (__attribute__((address_space(3))) void*)(l), 16, 0, 0);
}

// ---------------------------------------------------------------------------
// 64x128-tile MFMA GEMM (high-TLP variant).
// C = A(bf16) @ W(bf16)^T + bias, bf16 out. BK=32, 256 thr = 4 waves (2x2),
// each wave 32x64 (acc[2][4]). global_load_lds staging, double-buffered.
// Epilogue: acc -> LDS bf16 (padded rows) -> coalesced dwordx4 stores.
// blockIdx.z selects source set. NTSTORE: nontemporal C (streaming outputs).
// ---------------------------------------------------------------------------
template<bool RELU, bool NTSTORE>
__global__ __launch_bounds__(256) void gemm_small(
    const ushort* __restrict__ A0, const ushort* __restrict__ W0,
    const float* __restrict__ b0, ushort* __restrict__ C0,
    const ushort* __restrict__ A1, const ushort* __restrict__ W1,
    const float* __restrict__ b1, ushort* __restrict__ C1,
    int M, int N, int K)
{
    const bool zz = blockIdx.z != 0;
    const ushort* A   = zz ? A1 : A0;
    const ushort* W   = zz ? W1 : W0;
    const float* bias = zz ? b1 : b0;
    ushort* Cptr      = zz ? C1 : C0;

    __shared__ ushort smem[12288];           // 24 KB
    const int tid  = threadIdx.x;
    const int lane = tid & 63;
    const int wid  = tid >> 6;
    const int wr = wid >> 1, wc = wid & 1;
    const int m0 = blockIdx.x * 64, n0 = blockIdx.y * 128;
    const int lrow = lane & 15, lhi = lane >> 4;

    const int arow = tid >> 2;               // 0..63
    const int scol = (tid & 3) << 3;
    const ushort* ga  = A + (size_t)min(m0 + arow, M - 1) * K + scol;
    const ushort* gb0 = W + (size_t)(n0 + arow)      * K + scol;
    const ushort* gb1 = W + (size_t)(n0 + arow + 64) * K + scol;

    f32x4 acc[2][4] = {};
    const int NT = K >> 5;

    gl16(ga,  &smem[tid * 8]);
    gl16(gb0, &smem[4096 + tid * 8]);
    gl16(gb1, &smem[4096 + tid * 8 + 2048]);

    int cur = 0;
    for (int t = 0; t < NT; ++t) {
        __syncthreads();
        if (t + 1 < NT) {
            const int k0 = (t + 1) << 5;
            const int nb = cur ^ 1;
            gl16(ga  + k0, &smem[nb * 2048 + tid * 8]);
            gl16(gb0 + k0, &smem[4096 + nb * 4096 + tid * 8]);
            gl16(gb1 + k0, &smem[4096 + nb * 4096 + tid * 8 + 2048]);
        }
        bf16x8 afr[2], bfr[4];
        #pragma unroll
        for (int m = 0; m < 2; ++m)
            afr[m] = *reinterpret_cast<const bf16x8*>(
                &smem[cur * 2048 + (wr * 32 + m * 16 + lrow) * 32 + lhi * 8]);
        #pragma unroll
        for (int n = 0; n < 4; ++n)
            bfr[n] = *reinterpret_cast<const bf16x8*>(
                &smem[4096 + cur * 4096 + (wc * 64 + n * 16 + lrow) * 32 + lhi * 8]);
        #pragma unroll
        for (int m = 0; m < 2; ++m)
            #pragma unroll
            for (int n = 0; n < 4; ++n)
                acc[m][n] = __builtin_amdgcn_mfma_f32_16x16x32_bf16(
                    afr[m], bfr[n], acc[m][n], 0, 0, 0);
        cur ^= 1;
    }

    // epilogue: regs -> LDS (padded 136-elem rows) -> coalesced stores
    __syncthreads();
    #pragma unroll
    for (int m = 0; m < 2; ++m) {
        #pragma unroll
        for (int n = 0; n < 4; ++n) {
            const int col = wc * 64 + n * 16 + lrow;
            const float bv = bias[n0 + col];
            #pragma unroll
            for (int r = 0; r < 4; ++r) {
                const int row = wr * 32 + m * 16 + lhi * 4 + r;
                float v = acc[m][n][r] + bv;
                if (RELU) v = fmaxf(v, 0.f);
                smem[row * 136 + col] = f2bu(v);
            }
        }
    }
    __syncthreads();
    #pragma unroll
    for (int i = 0; i < 4; ++i) {
        const int e = tid + i * 256;
        const int row = e >> 4, ch = e & 15;
        if (m0 + row < M) {
            const u32x4 v = *reinterpret_cast<const u32x4*>(&smem[row * 136 + ch * 8]);
            u32x4* dst = reinterpret_cast<u32x4*>(Cptr + (size_t)(m0 + row) * N + n0 + ch * 8);
            if (NTSTORE) __builtin_nontemporal_store(v, dst);
            else *dst = v;
        }
    }
}

// ---------------------------------------------------------------------------
// Merged one-time prep: weight f32->bf16 pack + cat bias  AND  input cvt.
// ---------------------------------------------------------------------------
__global__ __launch_bounds__(256) void prep_all(
    const float* __restrict__ vw, const float* __restrict__ bw,
    const float* __restrict__ aw, const float* __restrict__ ow,
    const float* __restrict__ l1, const float* __restrict__ l2,
    const float* __restrict__ bb, const float* __restrict__ ab,
    ushort* __restrict__ dstW, float* __restrict__ dstQB,
    const float4* __restrict__ src, const float4* __restrict__ pos,
    ushort4* __restrict__ srcb, ushort4* __restrict__ qb)
{
    const int blk = blockIdx.x;
    if (blk < 2817) {
        const int i = blk * 256 + threadIdx.x;
        if (i < 720896) {
            float v;
            if      (i <  65536) v = vw[i];
            else if (i <  98304) v = bw[i -  65536];
            else if (i < 131072) v = aw[i -  98304];
            else if (i < 196608) v = ow[i - 131072];
            else if (i < 458752) v = l1[i - 196608];
            else                 v = l2[i - 458752];
            dstW[i] = f2bu(v);
        } else if (i < 721152) {
            const int j = i - 720896;
            dstQB[j] = (j < 128) ? bb[j] : ab[j - 128];
        }
    } else {
        const int i = (blk - 2817) * 256 + threadIdx.x;
        if (i >= TOKENS * 64) return;
        const float4 s = src[i], p = pos[i];
        ushort4 us, uq;
        us.x = f2bu(s.x); us.y = f2bu(s.y); us.z = f2bu(s.z); us.w = f2bu(s.w);
        uq.x = f2bu(s.x + p.x); uq.y = f2bu(s.y + p.y);
        uq.z = f2bu(s.z + p.z); uq.w = f2bu(s.w + p.w);
        srcb[i] = us; qb[i] = uq;
    }
}

// ---------------------------------------------------------------------------
// Fused box prep + sample v4. Block = 8 tokens (64 units of (token,head)).
// Phase 1: thread = (unit, level). Softmax over 16 via 4-lane shfl; box math
//   once per level; 4 points each; emit {4x u32 row-byte-offset, 4x f32
//   premult weight} per point to LDS (unit stride 33*16B, 2-way aliasing).
// Phase 2: thread = (unit, 16B-dim-slot): 4 lanes x dwordx4 = 64B row chunk
//   (1 KB/wave-instruction). Points in pairs: 8 dwordx4 gathers batched in
//   registers before consumption (MLP=8), 16 unpack + 8 pk-fma per load.
// ---------------------------------------------------------------------------
__global__ __launch_bounds__(256) void box_fused(
    const ushort* __restrict__ val,    // (B*SLEN, 256) bf16
    const ushort* __restrict__ qout,   // (t,256): off[128] | logits[128] bf16
    const float* __restrict__ refw,    // (t,4)
    const float* __restrict__ vratio,  // (B,4,2)
    ushort* __restrict__ attnout)      // (t,256) bf16
{
    __shared__ uint4 pd[64 * 33];      // 33,792 B
    const int tid = threadIdx.x;
    const int t0 = blockIdx.x * 8;

    // ---------------- phase 1 ----------------
    {
        const int u = tid >> 2, lvl = tid & 3;
        const int t = min(t0 + (u >> 3), TOKENS - 1);
        const int h = u & 7;
        const int b = (t >= SLEN) ? 1 : 0;
        const ushort* qr = qout + (size_t)t * 256;

        // this level's 4 logits
        const uint2 lu = *reinterpret_cast<const uint2*>(qr + 128 + h * 16 + lvl * 4);
        float e0 = __uint_as_float(lu.x << 16);
        float e1 = __uint_as_float(lu.x & 0xFFFF0000u);
        float e2 = __uint_as_float(lu.y << 16);
        float e3 = __uint_as_float(lu.y & 0xFFFF0000u);
        float mx = fmaxf(fmaxf(e0, e1), fmaxf(e2, e3));
        mx = fmaxf(mx, __shfl_xor(mx, 1));
        mx = fmaxf(mx, __shfl_xor(mx, 2));
        e0 = __expf(e0 - mx); e1 = __expf(e1 - mx);
        e2 = __expf(e2 - mx); e3 = __expf(e3 - mx);
        float ss = e0 + e1 + e2 + e3;
        ss += __shfl_xor(ss, 1);
        ss += __shfl_xor(ss, 2);
        const float inv = 1.f / ss;
        const float pe[4] = { e0 * inv, e1 * inv, e2 * inv, e3 * inv };

        // this level's 4 box offsets
        const uint2 ou = *reinterpret_cast<const uint2*>(qr + h * 16 + lvl * 4);
        const float o0 = __uint_as_float(ou.x << 16) * 0.125f;
        const float o1 = __uint_as_float(ou.x & 0xFFFF0000u) * 0.125f;
        const float o2 = __uint_as_float(ou.y << 16) * 0.125f;
        const float o3 = __uint_as_float(ou.y & 0xFFFF0000u) * 0.125f;

        const float4 rw = *reinterpret_cast<const float4*>(refw + (size_t)t * 4);
        const int Ww = (lvl == 0) ? 92 : (lvl == 1) ? 46 : (lvl == 2) ? 23 : 12;
        const int s0 = (lvl == 0) ? 0 : (lvl == 1) ? 8464 : (lvl == 2) ? 10580 : 11109;
        const float vrx = vratio[(b * 4 + lvl) * 2 + 0];
        const float vry = vratio[(b * 4 + lvl) * 2 + 1];

        const float bx  = rw.x + o0 * rw.z;
        const float by  = rw.y + o1 * rw.w;
        const float bwd = fmaxf(rw.z + o2 * rw.z, 0.f);
        const float bhd = fmaxf(rw.w + o3 * rw.w, 0.f);

        #pragma unroll
        for (int k = 0; k < 4; ++k) {
            const float jx = (k & 1) ? 0.25f : -0.25f;
            const float iy = (k & 2) ? 0.25f : -0.25f;
            const float px = (bx + jx * bwd) * vrx * (float)Ww - 0.5f;
            const float py = (by + iy * bhd) * vry * (float)Ww - 0.5f;
            const float x0f = floorf(px), y0f = floorf(py);
            const int x0 = (int)x0f, y0 = (int)y0f;
            const float wx = px - x0f, wy = py - y0f;
            const float wp = pe[k];

            const bool vx0 = (x0 >= 0) && (x0 < Ww);
            const bool vx1 = (x0 + 1 >= 0) && (x0 + 1 < Ww);
            const bool vy0 = (y0 >= 0) && (y0 < Ww);
            const bool vy1 = (y0 + 1 >= 0) && (y0 + 1 < Ww);
            const int cx0 = min(max(x0, 0), Ww - 1);
            const int cx1 = min(max(x0 + 1, 0), Ww - 1);
            const int cy0 = min(max(y0, 0), Ww - 1);
            const int cy1 = min(max(y0 + 1, 0), Ww - 1);

            float4 w4;
            w4.x = (vx0 && vy0) ? wp * (1.f - wx) * (1.f - wy) : 0.f;
            w4.y = (vx1 && vy0) ? wp * wx         * (1.f - wy) : 0.f;
            w4.z = (vx0 && vy1) ? wp * (1.f - wx) * wy         : 0.f;
            w4.w = (vx1 && vy1) ? wp * wx         * wy         : 0.f;

            uint4 off4;
            off4.x = (uint)(s0 + cy0 * Ww + cx0) * 512u;
            off4.y = (uint)(s0 + cy0 * Ww + cx1) * 512u;
            off4.z = (uint)(s0 + cy1 * Ww + cx0) * 512u;
            off4.w = (uint)(s0 + cy1 * Ww + cx1) * 512u;

            const int p = lvl * 4 + k;
            pd[u * 33 + p * 2] = off4;
            *reinterpret_cast<float4*>(&pd[u * 33 + p * 2 + 1]) = w4;
        }
    }
    __syncthreads();

    // ---------------- phase 2 (pairs of points, MLP=8, 16B gathers) --------
    const int u = tid >> 2, dl = tid & 3;
    const int traw = t0 + (u >> 3);
    const int t = min(traw, TOKENS - 1);
    const int h = u & 7;
    const uint boff = (uint)(((t >= SLEN) ? SLEN * 512u : 0u) + h * 64u + dl * 16u);
    const char* base = (const char*)val;

    const uint4* pu = &pd[u * 33];
    f32x2 a0 = {0.f, 0.f}, a1 = {0.f, 0.f}, a2 = {0.f, 0.f}, a3 = {0.f, 0.f};

    #pragma unroll
    for (int g = 0; g < 8; ++g) {
        const uint4  offA = pu[g * 4 + 0];
        const float4 wA   = *reinterpret_cast<const float4*>(&pu[g * 4 + 1]);
        const uint4  offB = pu[g * 4 + 2];
        const float4 wB   = *reinterpret_cast<const float4*>(&pu[g * 4 + 3]);

        // issue all 8 gathers (independent; stay in flight together)
        uint4 v0 = *reinterpret_cast<const uint4*>(base + (offA.x + boff));
        uint4 v1 = *reinterpret_cast<const uint4*>(base + (offA.y + boff));
        uint4 v2 = *reinterpret_cast<const uint4*>(base + (offA.z + boff));
        uint4 v3 = *reinterpret_cast<const uint4*>(base + (offA.w + boff));
        uint4 v4 = *reinterpret_cast<const uint4*>(base + (offB.x + boff));
        uint4 v5 = *reinterpret_cast<const uint4*>(base + (offB.y + boff));
        uint4 v6 = *reinterpret_cast<const uint4*>(base + (offB.z + boff));
        uint4 v7 = *reinterpret_cast<const uint4*>(base + (offB.w + boff));

        auto acc8 = [&](const uint4 v, const float w) {
            f32x2 wv; wv.x = w; wv.y = w;
            f32x2 tv;
            tv.x = __uint_as_float(v.x << 16);
            tv.y = __uint_as_float(v.x & 0xFFFF0000u);
            a0 += wv * tv;
            tv.x = __uint_as_float(v.y << 16);
            tv.y = __uint_as_float(v.y & 0xFFFF0000u);
            a1 += wv * tv;
            tv.x = __uint_as_float(v.z << 16);
            tv.y = __uint_as_float(v.z & 0xFFFF0000u);
            a2 += wv * tv;
            tv.x = __uint_as_float(v.w << 16);
            tv.y = __uint_as_float(v.w & 0xFFFF0000u);
            a3 += wv * tv;
        };
        acc8(v0, wA.x); acc8(v1, wA.y); acc8(v2, wA.z); acc8(v3, wA.w);
        acc8(v4, wB.x); acc8(v5, wB.y); acc8(v6, wB.z); acc8(v7, wB.w);
    }

    if (traw < TOKENS) {
        u32x4 o;
        o[0] = (uint)f2bu(a0.x) | ((uint)f2bu(a0.y) << 16);
        o[1] = (uint)f2bu(a1.x) | ((uint)f2bu(a1.y) << 16);
        o[2] = (uint)f2bu(a2.x) | ((uint)f2bu(a2.y) << 16);
        o[3] = (uint)f2bu(a3.x) | ((uint)f2bu(a3.y) << 16);
        *reinterpret_cast<u32x4*>(attnout + (size_t)t * 256 + h * 32 + dl * 8) = o;
    }
}

// ---------------------------------------------------------------------------
// LayerNorm(a + b): wave per row, thread handles 4 cols, shuffle reduction,
// 4 rows/block. b always bf16. AF32: a f32 vs bf16. OUTF32: f32 vs bf16 out.
// ---------------------------------------------------------------------------
template<bool AF32, bool OUTF32>
__global__ __launch_bounds__(256) void ln_add2(
    const void* __restrict__ aptr, const ushort* __restrict__ bptr,
    const float* __restrict__ w, const float* __restrict__ bias,
    void* __restrict__ outp, int nrows)
{
    const int lane = threadIdx.x & 63, wv = threadIdx.x >> 6;
    const int row = blockIdx.x * 4 + wv;
    if (row >= nrows) return;
    const size_t base = (size_t)row * 256 + lane * 4;

    float4 av;
    if (AF32) {
        av = *reinterpret_cast<const float4*>((const float*)aptr + base);
    } else {
        const ushort4 u = *reinterpret_cast<const ushort4*>((const ushort*)aptr + base);
        av = make_float4(bu2f(u.x), bu2f(u.y), bu2f(u.z), bu2f(u.w));
    }
    const ushort4 ub = *reinterpret_cast<const ushort4*>(bptr + base);
    const float v0 = av.x + bu2f(ub.x), v1 = av.y + bu2f(ub.y);
    const float v2 = av.z + bu2f(ub.z), v3 = av.w + bu2f(ub.w);

    float s = v0 + v1 + v2 + v3;
    #pragma unroll
    for (int o = 32; o; o >>= 1) s += __shfl_xor(s, o);
    const float mu = s * (1.f / 256.f);
    const float d0 = v0 - mu, d1 = v1 - mu, d2 = v2 - mu, d3 = v3 - mu;
    float s2 = d0 * d0 + d1 * d1 + d2 * d2 + d3 * d3;
    #pragma unroll
    for (int o = 32; o; o >>= 1) s2 += __shfl_xor(s2, o);
    const float rs = rsqrtf(s2 * (1.f / 256.f) + 1e-5f);

    const float4 w4 = *reinterpret_cast<const float4*>(w + lane * 4);
    const float4 g4 = *reinterpret_cast<const float4*>(bias + lane * 4);
    const float r0 = d0 * rs * w4.x + g4.x;
    const float r1 = d1 * rs * w4.y + g4.y;
    const float r2 = d2 * rs * w4.z + g4.z;
    const float r3 = d3 * rs * w4.w + g4.w;
    if (OUTF32) {
        *reinterpret_cast<float4*>((float*)outp + base) = make_float4(r0, r1, r2, r3);
    } else {
        ushort4 u;
        u.x = f2bu(r0); u.y = f2bu(r1); u.z = f2bu(r2); u.w = f2bu(r3);
        *reinterpret_cast<ushort4*>((ushort*)outp + base) = u;
    }
}

// ---------------------------------------------------------------------------
extern "C" void kernel_launch(void* const* d_in, const int* in_sizes, int n_in,
                              void* d_out, int out_size, void* d_ws, size_t ws_size,
                              hipStream_t stream)
{
    const float* src     = (const float*)d_in[0];
    const float* pos     = (const float*)d_in[1];
    const float* vratio  = (const float*)d_in[5];
    const float* refw    = (const float*)d_in[6];
    const float* value_w = (const float*)d_in[7];
    const float* value_b = (const float*)d_in[8];
    const float* out_w   = (const float*)d_in[9];
    const float* out_b   = (const float*)d_in[10];
    const float* box_w   = (const float*)d_in[11];
    const float* box_b   = (const float*)d_in[12];
    const float* attn_w  = (const float*)d_in[13];
    const float* attn_b  = (const float*)d_in[14];
    const float* lin1_w  = (const float*)d_in[15];
    const float* lin1_b  = (const float*)d_in[16];
    const float* lin2_w  = (const float*)d_in[17];
    const float* lin2_b  = (const float*)d_in[18];
    const float* n1w     = (const float*)d_in[19];
    const float* n1b     = (const float*)d_in[20];
    const float* n2w     = (const float*)d_in[21];
    const float* n2b     = (const float*)d_in[22];

    // flat workspace layout (~140 MB of 256 MiB)
    char* wsb = (char*)d_ws;
    ushort* Wb    = (ushort*)(wsb);                  // 1,441,792 B
    float*  qcb   = (float*)(wsb + 1441792);         // 1 KB
    ushort* srcb  = (ushort*)(wsb + 1442816);        // 11.5 MB bf16 src
    ushort* qb    = (ushort*)(wsb + 12965888);       // 11.5 MB bf16 src+pos
    ushort* valb  = (ushort*)(wsb + 24488960);       // 11.5 MB value
    ushort* qoutb = (ushort*)(wsb + 36012032);       // 11.5 MB off+logits
    ushort* attb  = (ushort*)(wsb + 47535104);       // 11.5 MB attn out
    ushort* src2b = (ushort*)(wsb + 59058176);       // 11.5 MB src2 bf16
    ushort* xbb   = (ushort*)(wsb + 70581248);       // 11.5 MB x bf16
    ushort* hb    = (ushort*)(wsb + 82104320);       // 46.1 MB hidden
    ushort* yb    = (ushort*)(wsb + 128196608);      // 11.5 MB y bf16

    const dim3 blk(256);

    // one-time prep (weights + input cvt) in a single launch
    prep_all<<<dim3(8444), blk, 0, stream>>>(
        value_w, box_w, attn_w, out_w, lin1_w, lin2_w, box_b, attn_b, Wb, qcb,
        (const float4*)src, (const float4*)pos, (ushort4*)srcb, (ushort4*)qb);

    // merged: z=0 value = src @ value_w^T ; z=1 qout = q @ [box;attn]^T
    gemm_small<false, false><<<dim3(352, 2, 2), blk, 0, stream>>>(
        srcb, Wb, value_b, valb,
        qb, Wb + 65536, qcb, qoutb, TOKENS, 256, 256);

    // fused prep + gather (8 tokens/block)
    box_fused<<<dim3((TOKENS + 7) / 8), blk, 0, stream>>>(
        valb, qoutb, refw, vratio, attb);

    // src2 = attnout @ out_w^T + b -> bf16
    gemm_small<false, false><<<dim3(352, 2, 1), blk, 0, stream>>>(
        attb, Wb + 131072, out_b, src2b,
        attb, Wb + 131072, out_b, src2b, TOKENS, 256, 256);
    // x = LN1(src + src2) -> bf16
    ln_add2<true, false><<<dim3((TOKENS + 3) / 4), blk, 0, stream>>>(
        src, src2b, n1w, n1b, xbb, TOKENS);
    // h = relu(x @ lin1_w^T + b) -> bf16 (64x128 tiles, NT C stores)
    gemm_small<true, true><<<dim3(352, 8, 1), blk, 0, stream>>>(
        xbb, Wb + 196608, lin1_b, hb,
        xbb, Wb + 196608, lin1_b, hb, TOKENS, 1024, 256);
    // y = h @ lin2_w^T + b -> bf16
    gemm_small<false, false><<<dim3(352, 2, 1), blk, 0, stream>>>(
        hb, Wb + 458752, lin2_b, yb,
        hb, Wb + 458752, lin2_b, yb, TOKENS, 256, 1024);
    // out = LN2(x + y) -> f32
    ln_add2<false, true><<<dim3((TOKENS + 3) / 4), blk, 0, stream>>>(
        xbb, yb, n2w, n2b, (float*)d_out, TOKENS);
}

// Round 11
// 146.258 us; speedup vs baseline: 5.4596x; 1.0150x over previous
//
#include <hip/hip_runtime.h>
#include <hip/hip_bf16.h>
#include <hip/hip_fp16.h>

#define TOKENS 22506
#define SLEN   11253

typedef __bf16 bf16x8 __attribute__((ext_vector_type(8)));
typedef float  f32x4  __attribute__((ext_vector_type(4)));
typedef float  f32x2  __attribute__((ext_vector_type(2)));
typedef uint   u32x4  __attribute__((ext_vector_type(4)));

__device__ __forceinline__ ushort f2bu(float f) {
    __hip_bfloat16 h = __float2bfloat16(f);   // RNE
    return *reinterpret_cast<ushort*>(&h);
}
__device__ __forceinline__ float bu2f(ushort u) {
    return __uint_as_float((uint)u << 16);
}
__device__ __forceinline__ uint pkf16(float a, float b) {
    __half2 h = __floats2half2_rn(a, b);
    return *reinterpret_cast<uint*>(&h);
}
__device__ __forceinline__ void gl16(const ushort* g, ushort* l) {
    __builtin_amdgcn_global_load_lds(
        (__attribute__((address_space(1))) void*)(g),
        (__attribute__((address_space(3))) void*)(l), 16, 0, 0);
}

// ---------------------------------------------------------------------------
// 64x128-tile MFMA GEMM (high-TLP variant).
// C = A(bf16) @ W(bf16)^T + bias, bf16 out. BK=32, 256 thr = 4 waves (2x2),
// each wave 32x64 (acc[2][4]). global_load_lds staging, double-buffered.
// Epilogue: acc -> LDS bf16 (padded rows) -> coalesced dwordx4 stores.
// blockIdx.z selects source set. NTSTORE: nontemporal C (streaming outputs).
// ---------------------------------------------------------------------------
template<bool RELU, bool NTSTORE>
__global__ __launch_bounds__(256) void gemm_small(
    const ushort* __restrict__ A0, const ushort* __restrict__ W0,
    const float* __restrict__ b0, ushort* __restrict__ C0,
    const ushort* __restrict__ A1, const ushort* __restrict__ W1,
    const float* __restrict__ b1, ushort* __restrict__ C1,
    int M, int N, int K)
{
    const bool zz = blockIdx.z != 0;
    const ushort* A   = zz ? A1 : A0;
    const ushort* W   = zz ? W1 : W0;
    const float* bias = zz ? b1 : b0;
    ushort* Cptr      = zz ? C1 : C0;

    __shared__ ushort smem[12288];           // 24 KB
    const int tid  = threadIdx.x;
    const int lane = tid & 63;
    const int wid  = tid >> 6;
    const int wr = wid >> 1, wc = wid & 1;
    const int m0 = blockIdx.x * 64, n0 = blockIdx.y * 128;
    const int lrow = lane & 15, lhi = lane >> 4;

    const int arow = tid >> 2;               // 0..63
    const int scol = (tid & 3) << 3;
    const ushort* ga  = A + (size_t)min(m0 + arow, M - 1) * K + scol;
    const ushort* gb0 = W + (size_t)(n0 + arow)      * K + scol;
    const ushort* gb1 = W + (size_t)(n0 + arow + 64) * K + scol;

    f32x4 acc[2][4] = {};
    const int NT = K >> 5;

    gl16(ga,  &smem[tid * 8]);
    gl16(gb0, &smem[4096 + tid * 8]);
    gl16(gb1, &smem[4096 + tid * 8 + 2048]);

    int cur = 0;
    for (int t = 0; t < NT; ++t) {
        __syncthreads();
        if (t + 1 < NT) {
            const int k0 = (t + 1) << 5;
            const int nb = cur ^ 1;
            gl16(ga  + k0, &smem[nb * 2048 + tid * 8]);
            gl16(gb0 + k0, &smem[4096 + nb * 4096 + tid * 8]);
            gl16(gb1 + k0, &smem[4096 + nb * 4096 + tid * 8 + 2048]);
        }
        bf16x8 afr[2], bfr[4];
        #pragma unroll
        for (int m = 0; m < 2; ++m)
            afr[m] = *reinterpret_cast<const bf16x8*>(
                &smem[cur * 2048 + (wr * 32 + m * 16 + lrow) * 32 + lhi * 8]);
        #pragma unroll
        for (int n = 0; n < 4; ++n)
            bfr[n] = *reinterpret_cast<const bf16x8*>(
                &smem[4096 + cur * 4096 + (wc * 64 + n * 16 + lrow) * 32 + lhi * 8]);
        #pragma unroll
        for (int m = 0; m < 2; ++m)
            #pragma unroll
            for (int n = 0; n < 4; ++n)
                acc[m][n] = __builtin_amdgcn_mfma_f32_16x16x32_bf16(
                    afr[m], bfr[n], acc[m][n], 0, 0, 0);
        cur ^= 1;
    }

    // epilogue: regs -> LDS (padded 136-elem rows) -> coalesced stores
    __syncthreads();
    #pragma unroll
    for (int m = 0; m < 2; ++m) {
        #pragma unroll
        for (int n = 0; n < 4; ++n) {
            const int col = wc * 64 + n * 16 + lrow;
            const float bv = bias[n0 + col];
            #pragma unroll
            for (int r = 0; r < 4; ++r) {
                const int row = wr * 32 + m * 16 + lhi * 4 + r;
                float v = acc[m][n][r] + bv;
                if (RELU) v = fmaxf(v, 0.f);
                smem[row * 136 + col] = f2bu(v);
            }
        }
    }
    __syncthreads();
    #pragma unroll
    for (int i = 0; i < 4; ++i) {
        const int e = tid + i * 256;
        const int row = e >> 4, ch = e & 15;
        if (m0 + row < M) {
            const u32x4 v = *reinterpret_cast<const u32x4*>(&smem[row * 136 + ch * 8]);
            u32x4* dst = reinterpret_cast<u32x4*>(Cptr + (size_t)(m0 + row) * N + n0 + ch * 8);
            if (NTSTORE) __builtin_nontemporal_store(v, dst);
            else *dst = v;
        }
    }
}

// ---------------------------------------------------------------------------
// Merged one-time prep: weight f32->bf16 pack + cat bias  AND  input cvt.
// ---------------------------------------------------------------------------
__global__ __launch_bounds__(256) void prep_all(
    const float* __restrict__ vw, const float* __restrict__ bw,
    const float* __restrict__ aw, const float* __restrict__ ow,
    const float* __restrict__ l1, const float* __restrict__ l2,
    const float* __restrict__ bb, const float* __restrict__ ab,
    ushort* __restrict__ dstW, float* __restrict__ dstQB,
    const float4* __restrict__ src, const float4* __restrict__ pos,
    ushort4* __restrict__ srcb, ushort4* __restrict__ qb)
{
    const int blk = blockIdx.x;
    if (blk < 2817) {
        const int i = blk * 256 + threadIdx.x;
        if (i < 720896) {
            float v;
            if      (i <  65536) v = vw[i];
            else if (i <  98304) v = bw[i -  65536];
            else if (i < 131072) v = aw[i -  98304];
            else if (i < 196608) v = ow[i - 131072];
            else if (i < 458752) v = l1[i - 196608];
            else                 v = l2[i - 458752];
            dstW[i] = f2bu(v);
        } else if (i < 721152) {
            const int j = i - 720896;
            dstQB[j] = (j < 128) ? bb[j] : ab[j - 128];
        }
    } else {
        const int i = (blk - 2817) * 256 + threadIdx.x;
        if (i >= TOKENS * 64) return;
        const float4 s = src[i], p = pos[i];
        ushort4 us, uq;
        us.x = f2bu(s.x); us.y = f2bu(s.y); us.z = f2bu(s.z); us.w = f2bu(s.w);
        uq.x = f2bu(s.x + p.x); uq.y = f2bu(s.y + p.y);
        uq.z = f2bu(s.z + p.z); uq.w = f2bu(s.w + p.w);
        srcb[i] = us; qb[i] = uq;
    }
}

// ---------------------------------------------------------------------------
// Fused box prep + sample v5. Block = 8 tokens (64 units of (token,head)).
// LDS split into offs (uint4, stride 17 -> 2-way aliasing, free) and wts
// (f16x4 as uint2, stride 17 -> conflict-free): 26,112 B total, ~6 blocks/CU
// (v4's 33.8KB pd halved occupancy to 27% -> latency-bound; this restores it).
// Phase 1: thread = (unit, level). 4-lane shfl softmax; box math once/level.
// Phase 2: thread = (unit, 16B-slot): dwordx4 gathers, pairs of points with
//   8 loads batched in registers (MLP=8).
// ---------------------------------------------------------------------------
__global__ __launch_bounds__(256) void box_fused(
    const ushort* __restrict__ val,    // (B*SLEN, 256) bf16
    const ushort* __restrict__ qout,   // (t,256): off[128] | logits[128] bf16
    const float* __restrict__ refw,    // (t,4)
    const float* __restrict__ vratio,  // (B,4,2)
    ushort* __restrict__ attnout)      // (t,256) bf16
{
    __shared__ uint4 offs[64 * 17];    // 17,408 B
    __shared__ uint2 wts[64 * 17];     //  8,704 B
    const int tid = threadIdx.x;
    const int t0 = blockIdx.x * 8;

    // ---------------- phase 1 ----------------
    {
        const int u = tid >> 2, lvl = tid & 3;
        const int t = min(t0 + (u >> 3), TOKENS - 1);
        const int h = u & 7;
        const int b = (t >= SLEN) ? 1 : 0;
        const ushort* qr = qout + (size_t)t * 256;

        // this level's 4 logits
        const uint2 lu = *reinterpret_cast<const uint2*>(qr + 128 + h * 16 + lvl * 4);
        float e0 = __uint_as_float(lu.x << 16);
        float e1 = __uint_as_float(lu.x & 0xFFFF0000u);
        float e2 = __uint_as_float(lu.y << 16);
        float e3 = __uint_as_float(lu.y & 0xFFFF0000u);
        float mx = fmaxf(fmaxf(e0, e1), fmaxf(e2, e3));
        mx = fmaxf(mx, __shfl_xor(mx, 1));
        mx = fmaxf(mx, __shfl_xor(mx, 2));
        e0 = __expf(e0 - mx); e1 = __expf(e1 - mx);
        e2 = __expf(e2 - mx); e3 = __expf(e3 - mx);
        float ss = e0 + e1 + e2 + e3;
        ss += __shfl_xor(ss, 1);
        ss += __shfl_xor(ss, 2);
        const float inv = 1.f / ss;
        const float pe[4] = { e0 * inv, e1 * inv, e2 * inv, e3 * inv };

        // this level's 4 box offsets
        const uint2 ou = *reinterpret_cast<const uint2*>(qr + h * 16 + lvl * 4);
        const float o0 = __uint_as_float(ou.x << 16) * 0.125f;
        const float o1 = __uint_as_float(ou.x & 0xFFFF0000u) * 0.125f;
        const float o2 = __uint_as_float(ou.y << 16) * 0.125f;
        const float o3 = __uint_as_float(ou.y & 0xFFFF0000u) * 0.125f;

        const float4 rw = *reinterpret_cast<const float4*>(refw + (size_t)t * 4);
        const int Ww = (lvl == 0) ? 92 : (lvl == 1) ? 46 : (lvl == 2) ? 23 : 12;
        const int s0 = (lvl == 0) ? 0 : (lvl == 1) ? 8464 : (lvl == 2) ? 10580 : 11109;
        const float vrx = vratio[(b * 4 + lvl) * 2 + 0];
        const float vry = vratio[(b * 4 + lvl) * 2 + 1];

        const float bx  = rw.x + o0 * rw.z;
        const float by  = rw.y + o1 * rw.w;
        const float bwd = fmaxf(rw.z + o2 * rw.z, 0.f);
        const float bhd = fmaxf(rw.w + o3 * rw.w, 0.f);

        #pragma unroll
        for (int k = 0; k < 4; ++k) {
            const float jx = (k & 1) ? 0.25f : -0.25f;
            const float iy = (k & 2) ? 0.25f : -0.25f;
            const float px = (bx + jx * bwd) * vrx * (float)Ww - 0.5f;
            const float py = (by + iy * bhd) * vry * (float)Ww - 0.5f;
            const float x0f = floorf(px), y0f = floorf(py);
            const int x0 = (int)x0f, y0 = (int)y0f;
            const float wx = px - x0f, wy = py - y0f;
            const float wp = pe[k];

            const bool vx0 = (x0 >= 0) && (x0 < Ww);
            const bool vx1 = (x0 + 1 >= 0) && (x0 + 1 < Ww);
            const bool vy0 = (y0 >= 0) && (y0 < Ww);
            const bool vy1 = (y0 + 1 >= 0) && (y0 + 1 < Ww);
            const int cx0 = min(max(x0, 0), Ww - 1);
            const int cx1 = min(max(x0 + 1, 0), Ww - 1);
            const int cy0 = min(max(y0, 0), Ww - 1);
            const int cy1 = min(max(y0 + 1, 0), Ww - 1);

            const float w00 = (vx0 && vy0) ? wp * (1.f - wx) * (1.f - wy) : 0.f;
            const float w01 = (vx1 && vy0) ? wp * wx         * (1.f - wy) : 0.f;
            const float w10 = (vx0 && vy1) ? wp * (1.f - wx) * wy         : 0.f;
            const float w11 = (vx1 && vy1) ? wp * wx         * wy         : 0.f;

            uint4 off4;
            off4.x = (uint)(s0 + cy0 * Ww + cx0) * 512u;
            off4.y = (uint)(s0 + cy0 * Ww + cx1) * 512u;
            off4.z = (uint)(s0 + cy1 * Ww + cx0) * 512u;
            off4.w = (uint)(s0 + cy1 * Ww + cx1) * 512u;

            const int p = lvl * 4 + k;
            offs[u * 17 + p] = off4;
            wts[u * 17 + p]  = make_uint2(pkf16(w00, w01), pkf16(w10, w11));
        }
    }
    __syncthreads();

    // ---------------- phase 2 (pairs of points, MLP=8, 16B gathers) --------
    const int u = tid >> 2, dl = tid & 3;
    const int traw = t0 + (u >> 3);
    const int t = min(traw, TOKENS - 1);
    const int h = u & 7;
    const uint boff = (uint)(((t >= SLEN) ? SLEN * 512u : 0u) + h * 64u + dl * 16u);
    const char* base = (const char*)val;

    const uint4* po = &offs[u * 17];
    const uint2* pw = &wts[u * 17];
    f32x2 a0 = {0.f, 0.f}, a1 = {0.f, 0.f}, a2 = {0.f, 0.f}, a3 = {0.f, 0.f};

    #pragma unroll
    for (int g = 0; g < 8; ++g) {
        const uint4 oA = po[g * 2 + 0];
        const uint4 oB = po[g * 2 + 1];
        const uint2 wA = pw[g * 2 + 0];
        const uint2 wB = pw[g * 2 + 1];

        // issue all 8 gathers (independent; stay in flight together)
        uint4 v0 = *reinterpret_cast<const uint4*>(base + (oA.x + boff));
        uint4 v1 = *reinterpret_cast<const uint4*>(base + (oA.y + boff));
        uint4 v2 = *reinterpret_cast<const uint4*>(base + (oA.z + boff));
        uint4 v3 = *reinterpret_cast<const uint4*>(base + (oA.w + boff));
        uint4 v4 = *reinterpret_cast<const uint4*>(base + (oB.x + boff));
        uint4 v5 = *reinterpret_cast<const uint4*>(base + (oB.y + boff));
        uint4 v6 = *reinterpret_cast<const uint4*>(base + (oB.w ^ oB.w ^ oB.z + boff));
        uint4 v7 = *reinterpret_cast<const uint4*>(base + (oB.w + boff));

        const float2 wAl = __half22float2(*reinterpret_cast<const __half2*>(&wA.x));
        const float2 wAh = __half22float2(*reinterpret_cast<const __half2*>(&wA.y));
        const float2 wBl = __half22float2(*reinterpret_cast<const __half2*>(&wB.x));
        const float2 wBh = __half22float2(*reinterpret_cast<const __half2*>(&wB.y));

        auto acc8 = [&](const uint4 v, const float w) {
            f32x2 wv; wv.x = w; wv.y = w;
            f32x2 tv;
            tv.x = __uint_as_float(v.x << 16);
            tv.y = __uint_as_float(v.x & 0xFFFF0000u);
            a0 += wv * tv;
            tv.x = __uint_as_float(v.y << 16);
            tv.y = __uint_as_float(v.y & 0xFFFF0000u);
            a1 += wv * tv;
            tv.x = __uint_as_float(v.z << 16);
            tv.y = __uint_as_float(v.z & 0xFFFF0000u);
            a2 += wv * tv;
            tv.x = __uint_as_float(v.w << 16);
            tv.y = __uint_as_float(v.w & 0xFFFF0000u);
            a3 += wv * tv;
        };
        acc8(v0, wAl.x); acc8(v1, wAl.y); acc8(v2, wAh.x); acc8(v3, wAh.y);
        acc8(v4, wBl.x); acc8(v5, wBl.y); acc8(v6, wBh.x); acc8(v7, wBh.y);
    }

    if (traw < TOKENS) {
        u32x4 o;
        o[0] = (uint)f2bu(a0.x) | ((uint)f2bu(a0.y) << 16);
        o[1] = (uint)f2bu(a1.x) | ((uint)f2bu(a1.y) << 16);
        o[2] = (uint)f2bu(a2.x) | ((uint)f2bu(a2.y) << 16);
        o[3] = (uint)f2bu(a3.x) | ((uint)f2bu(a3.y) << 16);
        *reinterpret_cast<u32x4*>(attnout + (size_t)t * 256 + h * 32 + dl * 8) = o;
    }
}

// ---------------------------------------------------------------------------
// LayerNorm(a + b): wave per row, thread handles 4 cols, shuffle reduction,
// 4 rows/block. b always bf16. AF32: a f32 vs bf16. OUTF32: f32 vs bf16 out.
// ---------------------------------------------------------------------------
template<bool AF32, bool OUTF32>
__global__ __launch_bounds__(256) void ln_add2(
    const void* __restrict__ aptr, const ushort* __restrict__ bptr,
    const float* __restrict__ w, const float* __restrict__ bias,
    void* __restrict__ outp, int nrows)
{
    const int lane = threadIdx.x & 63, wv = threadIdx.x >> 6;
    const int row = blockIdx.x * 4 + wv;
    if (row >= nrows) return;
    const size_t base = (size_t)row * 256 + lane * 4;

    float4 av;
    if (AF32) {
        av = *reinterpret_cast<const float4*>((const float*)aptr + base);
    } else {
        const ushort4 u = *reinterpret_cast<const ushort4*>((const ushort*)aptr + base);
        av = make_float4(bu2f(u.x), bu2f(u.y), bu2f(u.z), bu2f(u.w));
    }
    const ushort4 ub = *reinterpret_cast<const ushort4*>(bptr + base);
    const float v0 = av.x + bu2f(ub.x), v1 = av.y + bu2f(ub.y);
    const float v2 = av.z + bu2f(ub.z), v3 = av.w + bu2f(ub.w);

    float s = v0 + v1 + v2 + v3;
    #pragma unroll
    for (int o = 32; o; o >>= 1) s += __shfl_xor(s, o);
    const float mu = s * (1.f / 256.f);
    const float d0 = v0 - mu, d1 = v1 - mu, d2 = v2 - mu, d3 = v3 - mu;
    float s2 = d0 * d0 + d1 * d1 + d2 * d2 + d3 * d3;
    #pragma unroll
    for (int o = 32; o; o >>= 1) s2 += __shfl_xor(s2, o);
    const float rs = rsqrtf(s2 * (1.f / 256.f) + 1e-5f);

    const float4 w4 = *reinterpret_cast<const float4*>(w + lane * 4);
    const float4 g4 = *reinterpret_cast<const float4*>(bias + lane * 4);
    const float r0 = d0 * rs * w4.x + g4.x;
    const float r1 = d1 * rs * w4.y + g4.y;
    const float r2 = d2 * rs * w4.z + g4.z;
    const float r3 = d3 * rs * w4.w + g4.w;
    if (OUTF32) {
        *reinterpret_cast<float4*>((float*)outp + base) = make_float4(r0, r1, r2, r3);
    } else {
        ushort4 u;
        u.x = f2bu(r0); u.y = f2bu(r1); u.z = f2bu(r2); u.w = f2bu(r3);
        *reinterpret_cast<ushort4*>((ushort*)outp + base) = u;
    }
}

// ---------------------------------------------------------------------------
extern "C" void kernel_launch(void* const* d_in, const int* in_sizes, int n_in,
                              void* d_out, int out_size, void* d_ws, size_t ws_size,
                              hipStream_t stream)
{
    const float* src     = (const float*)d_in[0];
    const float* pos     = (const float*)d_in[1];
    const float* vratio  = (const float*)d_in[5];
    const float* refw    = (const float*)d_in[6];
    const float* value_w = (const float*)d_in[7];
    const float* value_b = (const float*)d_in[8];
    const float* out_w   = (const float*)d_in[9];
    const float* out_b   = (const float*)d_in[10];
    const float* box_w   = (const float*)d_in[11];
    const float* box_b   = (const float*)d_in[12];
    const float* attn_w  = (const float*)d_in[13];
    const float* attn_b  = (const float*)d_in[14];
    const float* lin1_w  = (const float*)d_in[15];
    const float* lin1_b  = (const float*)d_in[16];
    const float* lin2_w  = (const float*)d_in[17];
    const float* lin2_b  = (const float*)d_in[18];
    const float* n1w     = (const float*)d_in[19];
    const float* n1b     = (const float*)d_in[20];
    const float* n2w     = (const float*)d_in[21];
    const float* n2b     = (const float*)d_in[22];

    // flat workspace layout (~140 MB of 256 MiB)
    char* wsb = (char*)d_ws;
    ushort* Wb    = (ushort*)(wsb);                  // 1,441,792 B
    float*  qcb   = (float*)(wsb + 1441792);         // 1 KB
    ushort* srcb  = (ushort*)(wsb + 1442816);        // 11.5 MB bf16 src
    ushort* qb    = (ushort*)(wsb + 12965888);       // 11.5 MB bf16 src+pos
    ushort* valb  = (ushort*)(wsb + 24488960);       // 11.5 MB value
    ushort* qoutb = (ushort*)(wsb + 36012032);       // 11.5 MB off+logits
    ushort* attb  = (ushort*)(wsb + 47535104);       // 11.5 MB attn out
    ushort* src2b = (ushort*)(wsb + 59058176);       // 11.5 MB src2 bf16
    ushort* xbb   = (ushort*)(wsb + 70581248);       // 11.5 MB x bf16
    ushort* hb    = (ushort*)(wsb + 82104320);       // 46.1 MB hidden
    ushort* yb    = (ushort*)(wsb + 128196608);      // 11.5 MB y bf16

    const dim3 blk(256);

    // one-time prep (weights + input cvt) in a single launch
    prep_all<<<dim3(8444), blk, 0, stream>>>(
        value_w, box_w, attn_w, out_w, lin1_w, lin2_w, box_b, attn_b, Wb, qcb,
        (const float4*)src, (const float4*)pos, (ushort4*)srcb, (ushort4*)qb);

    // merged: z=0 value = src @ value_w^T ; z=1 qout = q @ [box;attn]^T
    gemm_small<false, false><<<dim3(352, 2, 2), blk, 0, stream>>>(
        srcb, Wb, value_b, valb,
        qb, Wb + 65536, qcb, qoutb, TOKENS, 256, 256);

    // fused prep + gather (8 tokens/block)
    box_fused<<<dim3((TOKENS + 7) / 8), blk, 0, stream>>>(
        valb, qoutb, refw, vratio, attb);

    // src2 = attnout @ out_w^T + b -> bf16
    gemm_small<false, false><<<dim3(352, 2, 1), blk, 0, stream>>>(
        attb, Wb + 131072, out_b, src2b,
        attb, Wb + 131072, out_b, src2b, TOKENS, 256, 256);
    // x = LN1(src + src2) -> bf16
    ln_add2<true, false><<<dim3((TOKENS + 3) / 4), blk, 0, stream>>>(
        src, src2b, n1w, n1b, xbb, TOKENS);
    // h = relu(x @ lin1_w^T + b) -> bf16 (64x128 tiles, NT C stores)
    gemm_small<true, true><<<dim3(352, 8, 1), blk, 0, stream>>>(
        xbb, Wb + 196608, lin1_b, hb,
        xbb, Wb + 196608, lin1_b, hb, TOKENS, 1024, 256);
    // y = h @ lin2_w^T + b -> bf16
    gemm_small<false, false><<<dim3(352, 2, 1), blk, 0, stream>>>(
        hb, Wb + 458752, lin2_b, yb,
        hb, Wb + 458752, lin2_b, yb, TOKENS, 256, 1024);
    // out = LN2(x + y) -> f32
    ln_add2<false, true><<<dim3((TOKENS + 3) / 4), blk, 0, stream>>>(
        xbb, yb, n2w, n2b, (float*)d_out, TOKENS);
}

// Round 13
// 134.932 us; speedup vs baseline: 5.9179x; 1.0839x over previous
//
#include <hip/hip_runtime.h>
#include <hip/hip_bf16.h>
#include <hip/hip_fp16.h>

#define TOKENS 22506
#define SLEN   11253

typedef __bf16 bf16x8 __attribute__((ext_vector_type(8)));
typedef float  f32x4  __attribute__((ext_vector_type(4)));
typedef float  f32x2  __attribute__((ext_vector_type(2)));
typedef uint   u32x4  __attribute__((ext_vector_type(4)));

#if defined(__has_builtin)
#if __has_builtin(__builtin_amdgcn_cvt_pk_f32_fp8) && __has_builtin(__builtin_amdgcn_cvt_pk_fp8_f32)
#define HAS_FP8CVT 1
#endif
#endif

__device__ __forceinline__ ushort f2bu(float f) {
    __hip_bfloat16 h = __float2bfloat16(f);   // RNE
    return *reinterpret_cast<ushort*>(&h);
}
__device__ __forceinline__ float bu2f(ushort u) {
    return __uint_as_float((uint)u << 16);
}
__device__ __forceinline__ uint pkf16(float a, float b) {
    __half2 h = __floats2half2_rn(a, b);
    return *reinterpret_cast<uint*>(&h);
}
__device__ __forceinline__ void gl16(const ushort* g, ushort* l) {
    __builtin_amdgcn_global_load_lds(
        (__attribute__((address_space(1))) void*)(g),
        (__attribute__((address_space(3))) void*)(l), 16, 0, 0);
}

#ifndef HAS_FP8CVT
// fallback software e4m3fn codec (compile-safety only)
__device__ __forceinline__ uint enc_fp8(float x) {
    if (!(fabsf(x) >= 0.f)) return 0;
    uint u = __float_as_uint(x);
    uint s = (u >> 24) & 0x80u;
    float ax = fabsf(x);
    if (ax >= 448.f) return s | 0x7Eu;
    if (ax < 0.0009765625f) return s;
    int e; frexpf(ax, &e);
    int ue = e - 1;
    if (ue < -6) {
        int m = (int)(ax * 512.f + 0.5f);
        if (m > 7) m = 7;
        return s | (uint)m;
    }
    float q = ax * exp2f((float)(3 - ue));
    int mi = (int)(q + 0.5f);
    if (mi >= 16) { mi >>= 1; ++ue; if (ue > 8) return s | 0x7Eu; }
    return s | ((uint)(ue + 7) << 3) | ((uint)mi & 7u);
}
__device__ __forceinline__ float dec_fp8(uint b) {
    const float sgn = (b & 0x80u) ? -1.f : 1.f;
    const uint e = (b >> 3) & 15u, m = b & 7u;
    if (e == 0) return sgn * (float)m * 0.001953125f;
    return sgn * (1.0f + (float)m * 0.125f) * exp2f((float)e - 7.f);
}
#endif

__device__ __forceinline__ uint fp8pack4(float f0, float f1, float f2, float f3) {
#ifdef HAS_FP8CVT
    int p = 0;
    p = __builtin_amdgcn_cvt_pk_fp8_f32(f0, f1, p, false);
    p = __builtin_amdgcn_cvt_pk_fp8_f32(f2, f3, p, true);
    return (uint)p;
#else
    return enc_fp8(f0) | (enc_fp8(f1) << 8) | (enc_fp8(f2) << 16) | (enc_fp8(f3) << 24);
#endif
}
template<bool HI>
__device__ __forceinline__ f32x2 fp8pair(uint w) {
#ifdef HAS_FP8CVT
    auto c = __builtin_amdgcn_cvt_pk_f32_fp8((int)w, HI);   // HI is a literal here
    f32x2 r; r.x = c[0]; r.y = c[1]; return r;
#else
    const uint sh = HI ? 16u : 0u;
    f32x2 r; r.x = dec_fp8((w >> sh) & 0xFFu); r.y = dec_fp8((w >> (sh + 8)) & 0xFFu);
    return r;
#endif
}

// ---------------------------------------------------------------------------
// 64x128-tile MFMA GEMM (high-TLP variant).
// C = A(bf16) @ W(bf16)^T + bias. BK=32, 256 thr = 4 waves (2x2), each wave
// 32x64 (acc[2][4]). global_load_lds staging, double-buffered. Epilogue:
// acc -> LDS bf16 -> coalesced stores. blockIdx.z selects source set.
// NTSTORE: nontemporal C. F8Z0: z==0 slice emits fp8-e4m3 C (value tensor).
// ---------------------------------------------------------------------------
template<bool RELU, bool NTSTORE, bool F8Z0>
__global__ __launch_bounds__(256) void gemm_small(
    const ushort* __restrict__ A0, const ushort* __restrict__ W0,
    const float* __restrict__ b0, void* __restrict__ C0,
    const ushort* __restrict__ A1, const ushort* __restrict__ W1,
    const float* __restrict__ b1, void* __restrict__ C1,
    int M, int N, int K)
{
    const bool zz = blockIdx.z != 0;
    const ushort* A   = zz ? A1 : A0;
    const ushort* W   = zz ? W1 : W0;
    const float* bias = zz ? b1 : b0;
    void* Cptr        = zz ? C1 : C0;

    __shared__ ushort smem[12288];           // 24 KB
    const int tid  = threadIdx.x;
    const int lane = tid & 63;
    const int wid  = tid >> 6;
    const int wr = wid >> 1, wc = wid & 1;
    const int m0 = blockIdx.x * 64, n0 = blockIdx.y * 128;
    const int lrow = lane & 15, lhi = lane >> 4;

    const int arow = tid >> 2;               // 0..63
    const int scol = (tid & 3) << 3;
    const ushort* ga  = A + (size_t)min(m0 + arow, M - 1) * K + scol;
    const ushort* gb0 = W + (size_t)(n0 + arow)      * K + scol;
    const ushort* gb1 = W + (size_t)(n0 + arow + 64) * K + scol;

    f32x4 acc[2][4] = {};
    const int NT = K >> 5;

    gl16(ga,  &smem[tid * 8]);
    gl16(gb0, &smem[4096 + tid * 8]);
    gl16(gb1, &smem[4096 + tid * 8 + 2048]);

    int cur = 0;
    for (int t = 0; t < NT; ++t) {
        __syncthreads();
        if (t + 1 < NT) {
            const int k0 = (t + 1) << 5;
            const int nb = cur ^ 1;
            gl16(ga  + k0, &smem[nb * 2048 + tid * 8]);
            gl16(gb0 + k0, &smem[4096 + nb * 4096 + tid * 8]);
            gl16(gb1 + k0, &smem[4096 + nb * 4096 + tid * 8 + 2048]);
        }
        bf16x8 afr[2], bfr[4];
        #pragma unroll
        for (int m = 0; m < 2; ++m)
            afr[m] = *reinterpret_cast<const bf16x8*>(
                &smem[cur * 2048 + (wr * 32 + m * 16 + lrow) * 32 + lhi * 8]);
        #pragma unroll
        for (int n = 0; n < 4; ++n)
            bfr[n] = *reinterpret_cast<const bf16x8*>(
                &smem[4096 + cur * 4096 + (wc * 64 + n * 16 + lrow) * 32 + lhi * 8]);
        #pragma unroll
        for (int m = 0; m < 2; ++m)
            #pragma unroll
            for (int n = 0; n < 4; ++n)
                acc[m][n] = __builtin_amdgcn_mfma_f32_16x16x32_bf16(
                    afr[m], bfr[n], acc[m][n], 0, 0, 0);
        cur ^= 1;
    }

    // epilogue: regs -> LDS (padded 136-elem rows) -> coalesced stores
    __syncthreads();
    #pragma unroll
    for (int m = 0; m < 2; ++m) {
        #pragma unroll
        for (int n = 0; n < 4; ++n) {
            const int col = wc * 64 + n * 16 + lrow;
            const float bv = bias[n0 + col];
            #pragma unroll
            for (int r = 0; r < 4; ++r) {
                const int row = wr * 32 + m * 16 + lhi * 4 + r;
                float v = acc[m][n][r] + bv;
                if (RELU) v = fmaxf(v, 0.f);
                smem[row * 136 + col] = f2bu(v);
            }
        }
    }
    __syncthreads();
    if (F8Z0 && !zz) {
        // fp8 output path (value tensor): 8 bf16 -> 8 fp8 per thread-chunk
        #pragma unroll
        for (int i = 0; i < 4; ++i) {
            const int e = tid + i * 256;
            const int row = e >> 4, ch = e & 15;
            if (m0 + row < M) {
                const u32x4 v = *reinterpret_cast<const u32x4*>(&smem[row * 136 + ch * 8]);
                float f[8];
                #pragma unroll
                for (int j = 0; j < 4; ++j) {
                    f[2 * j]     = __uint_as_float(v[j] << 16);
                    f[2 * j + 1] = __uint_as_float(v[j] & 0xFFFF0000u);
                }
                uint2 o;
                o.x = fp8pack4(f[0], f[1], f[2], f[3]);
                o.y = fp8pack4(f[4], f[5], f[6], f[7]);
                *reinterpret_cast<uint2*>(
                    (unsigned char*)Cptr + (size_t)(m0 + row) * N + n0 + ch * 8) = o;
            }
        }
    } else {
        #pragma unroll
        for (int i = 0; i < 4; ++i) {
            const int e = tid + i * 256;
            const int row = e >> 4, ch = e & 15;
            if (m0 + row < M) {
                const u32x4 v = *reinterpret_cast<const u32x4*>(&smem[row * 136 + ch * 8]);
                u32x4* dst = reinterpret_cast<u32x4*>(
                    (ushort*)Cptr + (size_t)(m0 + row) * N + n0 + ch * 8);
                if (NTSTORE) __builtin_nontemporal_store(v, dst);
                else *dst = v;
            }
        }
    }
}

// ---------------------------------------------------------------------------
// Merged one-time prep: weight f32->bf16 pack + cat bias  AND  input cvt.
// ---------------------------------------------------------------------------
__global__ __launch_bounds__(256) void prep_all(
    const float* __restrict__ vw, const float* __restrict__ bw,
    const float* __restrict__ aw, const float* __restrict__ ow,
    const float* __restrict__ l1, const float* __restrict__ l2,
    const float* __restrict__ bb, const float* __restrict__ ab,
    ushort* __restrict__ dstW, float* __restrict__ dstQB,
    const float4* __restrict__ src, const float4* __restrict__ pos,
    ushort4* __restrict__ srcb, ushort4* __restrict__ qb)
{
    const int blk = blockIdx.x;
    if (blk < 2817) {
        const int i = blk * 256 + threadIdx.x;
        if (i < 720896) {
            float v;
            if      (i <  65536) v = vw[i];
            else if (i <  98304) v = bw[i -  65536];
            else if (i < 131072) v = aw[i -  98304];
            else if (i < 196608) v = ow[i - 131072];
            else if (i < 458752) v = l1[i - 196608];
            else                 v = l2[i - 458752];
            dstW[i] = f2bu(v);
        } else if (i < 721152) {
            const int j = i - 720896;
            dstQB[j] = (j < 128) ? bb[j] : ab[j - 128];
        }
    } else {
        const int i = (blk - 2817) * 256 + threadIdx.x;
        if (i >= TOKENS * 64) return;
        const float4 s = src[i], p = pos[i];
        ushort4 us, uq;
        us.x = f2bu(s.x); us.y = f2bu(s.y); us.z = f2bu(s.z); us.w = f2bu(s.w);
        uq.x = f2bu(s.x + p.x); uq.y = f2bu(s.y + p.y);
        uq.z = f2bu(s.z + p.z); uq.w = f2bu(s.w + p.w);
        srcb[i] = us; qb[i] = uq;
    }
}

// ---------------------------------------------------------------------------
// Fused box prep + sample v6 (fp8 value). Block = 8 tokens (64 units).
// value is fp8-e4m3, row = 256 B; per-batch value = 2.88 MB -> fits an XCD's
// 4 MiB L2, so gathers are L2-resident (bf16's 5.76 MB/batch thrashed it).
// LDS: offs = ushort4 spatial idx (8,704 B), wts = f16x4 (8,704 B) -> 17.4 KB.
// Phase 1: thread = (unit, level); 4-lane shfl softmax; box math once/level.
// Phase 2: thread = (unit, 8B-slot): dwordx2 gathers (8 fp8 dims), pairs of
//   points with 8 loads batched (MLP=8); hw cvt_pk_f32_fp8 decode.
// ---------------------------------------------------------------------------
__global__ __launch_bounds__(256) void box_fused(
    const unsigned char* __restrict__ val,  // (B*SLEN, 256) fp8
    const ushort* __restrict__ qout,   // (t,256): off[128] | logits[128] bf16
    const float* __restrict__ refw,    // (t,4)
    const float* __restrict__ vratio,  // (B,4,2)
    ushort* __restrict__ attnout)      // (t,256) bf16
{
    __shared__ ushort4 offs[64 * 17];  // 8,704 B
    __shared__ uint2 wts[64 * 17];     // 8,704 B
    const int tid = threadIdx.x;
    const int t0 = blockIdx.x * 8;

    // ---------------- phase 1 ----------------
    {
        const int u = tid >> 2, lvl = tid & 3;
        const int t = min(t0 + (u >> 3), TOKENS - 1);
        const int h = u & 7;
        const int b = (t >= SLEN) ? 1 : 0;
        const ushort* qr = qout + (size_t)t * 256;

        // this level's 4 logits
        const uint2 lu = *reinterpret_cast<const uint2*>(qr + 128 + h * 16 + lvl * 4);
        float e0 = __uint_as_float(lu.x << 16);
        float e1 = __uint_as_float(lu.x & 0xFFFF0000u);
        float e2 = __uint_as_float(lu.y << 16);
        float e3 = __uint_as_float(lu.y & 0xFFFF0000u);
        float mx = fmaxf(fmaxf(e0, e1), fmaxf(e2, e3));
        mx = fmaxf(mx, __shfl_xor(mx, 1));
        mx = fmaxf(mx, __shfl_xor(mx, 2));
        e0 = __expf(e0 - mx); e1 = __expf(e1 - mx);
        e2 = __expf(e2 - mx); e3 = __expf(e3 - mx);
        float ss = e0 + e1 + e2 + e3;
        ss += __shfl_xor(ss, 1);
        ss += __shfl_xor(ss, 2);
        const float inv = 1.f / ss;
        const float pe[4] = { e0 * inv, e1 * inv, e2 * inv, e3 * inv };

        // this level's 4 box offsets
        const uint2 ou = *reinterpret_cast<const uint2*>(qr + h * 16 + lvl * 4);
        const float o0 = __uint_as_float(ou.x << 16) * 0.125f;
        const float o1 = __uint_as_float(ou.x & 0xFFFF0000u) * 0.125f;
        const float o2 = __uint_as_float(ou.y << 16) * 0.125f;
        const float o3 = __uint_as_float(ou.y & 0xFFFF0000u) * 0.125f;

        const float4 rw = *reinterpret_cast<const float4*>(refw + (size_t)t * 4);
        const int Ww = (lvl == 0) ? 92 : (lvl == 1) ? 46 : (lvl == 2) ? 23 : 12;
        const int s0 = (lvl == 0) ? 0 : (lvl == 1) ? 8464 : (lvl == 2) ? 10580 : 11109;
        const float vrx = vratio[(b * 4 + lvl) * 2 + 0];
        const float vry = vratio[(b * 4 + lvl) * 2 + 1];

        const float bx  = rw.x + o0 * rw.z;
        const float by  = rw.y + o1 * rw.w;
        const float bwd = fmaxf(rw.z + o2 * rw.z, 0.f);
        const float bhd = fmaxf(rw.w + o3 * rw.w, 0.f);

        #pragma unroll
        for (int k = 0; k < 4; ++k) {
            const float jx = (k & 1) ? 0.25f : -0.25f;
            const float iy = (k & 2) ? 0.25f : -0.25f;
            const float px = (bx + jx * bwd) * vrx * (float)Ww - 0.5f;
            const float py = (by + iy * bhd) * vry * (float)Ww - 0.5f;
            const float x0f = floorf(px), y0f = floorf(py);
            const int x0 = (int)x0f, y0 = (int)y0f;
            const float wx = px - x0f, wy = py - y0f;
            const float wp = pe[k];

            const bool vx0 = (x0 >= 0) && (x0 < Ww);
            const bool vx1 = (x0 + 1 >= 0) && (x0 + 1 < Ww);
            const bool vy0 = (y0 >= 0) && (y0 < Ww);
            const bool vy1 = (y0 + 1 >= 0) && (y0 + 1 < Ww);
            const int cx0 = min(max(x0, 0), Ww - 1);
            const int cx1 = min(max(x0 + 1, 0), Ww - 1);
            const int cy0 = min(max(y0, 0), Ww - 1);
            const int cy1 = min(max(y0 + 1, 0), Ww - 1);

            const float w00 = (vx0 && vy0) ? wp * (1.f - wx) * (1.f - wy) : 0.f;
            const float w01 = (vx1 && vy0) ? wp * wx         * (1.f - wy) : 0.f;
            const float w10 = (vx0 && vy1) ? wp * (1.f - wx) * wy         : 0.f;
            const float w11 = (vx1 && vy1) ? wp * wx         * wy         : 0.f;

            ushort4 sp;
            sp.x = (ushort)(s0 + cy0 * Ww + cx0);
            sp.y = (ushort)(s0 + cy0 * Ww + cx1);
            sp.z = (ushort)(s0 + cy1 * Ww + cx0);
            sp.w = (ushort)(s0 + cy1 * Ww + cx1);

            const int p = lvl * 4 + k;
            offs[u * 17 + p] = sp;
            wts[u * 17 + p]  = make_uint2(pkf16(w00, w01), pkf16(w10, w11));
        }
    }
    __syncthreads();

    // ---------------- phase 2 (pairs of points, MLP=8, fp8 gathers) --------
    const int u = tid >> 2, dl = tid & 3;
    const int traw = t0 + (u >> 3);
    const int t = min(traw, TOKENS - 1);
    const int h = u & 7;
    const uint boff = ((t >= SLEN) ? (uint)SLEN * 256u : 0u) + (uint)h * 32u + (uint)dl * 8u;
    const char* base = (const char*)val;

    const ushort4* po = &offs[u * 17];
    const uint2* pw = &wts[u * 17];
    f32x2 a0 = {0.f, 0.f}, a1 = {0.f, 0.f}, a2 = {0.f, 0.f}, a3 = {0.f, 0.f};

    #pragma unroll
    for (int g = 0; g < 8; ++g) {
        const ushort4 sA = po[g * 2 + 0];
        const ushort4 sB = po[g * 2 + 1];
        const uint2 wA = pw[g * 2 + 0];
        const uint2 wB = pw[g * 2 + 1];

        // issue all 8 gathers (independent; stay in flight together)
        const uint2 v0 = *reinterpret_cast<const uint2*>(base + (((uint)sA.x << 8) + boff));
        const uint2 v1 = *reinterpret_cast<const uint2*>(base + (((uint)sA.y << 8) + boff));
        const uint2 v2 = *reinterpret_cast<const uint2*>(base + (((uint)sA.z << 8) + boff));
        const uint2 v3 = *reinterpret_cast<const uint2*>(base + (((uint)sA.w << 8) + boff));
        const uint2 v4 = *reinterpret_cast<const uint2*>(base + (((uint)sB.x << 8) + boff));
        const uint2 v5 = *reinterpret_cast<const uint2*>(base + (((uint)sB.y << 8) + boff));
        const uint2 v6 = *reinterpret_cast<const uint2*>(base + (((uint)sB.z << 8) + boff));
        const uint2 v7 = *reinterpret_cast<const uint2*>(base + (((uint)sB.w << 8) + boff));

        const float2 wAl = __half22float2(*reinterpret_cast<const __half2*>(&wA.x));
        const float2 wAh = __half22float2(*reinterpret_cast<const __half2*>(&wA.y));
        const float2 wBl = __half22float2(*reinterpret_cast<const __half2*>(&wB.x));
        const float2 wBh = __half22float2(*reinterpret_cast<const __half2*>(&wB.y));

        auto accf8 = [&](const uint2 v, const float w) {
            f32x2 wv; wv.x = w; wv.y = w;
            a0 += wv * fp8pair<false>(v.x);
            a1 += wv * fp8pair<true>(v.x);
            a2 += wv * fp8pair<false>(v.y);
            a3 += wv * fp8pair<true>(v.y);
        };
        accf8(v0, wAl.x); accf8(v1, wAl.y); accf8(v2, wAh.x); accf8(v3, wAh.y);
        accf8(v4, wBl.x); accf8(v5, wBl.y); accf8(v6, wBh.x); accf8(v7, wBh.y);
    }

    if (traw < TOKENS) {
        u32x4 o;
        o[0] = (uint)f2bu(a0.x) | ((uint)f2bu(a0.y) << 16);
        o[1] = (uint)f2bu(a1.x) | ((uint)f2bu(a1.y) << 16);
        o[2] = (uint)f2bu(a2.x) | ((uint)f2bu(a2.y) << 16);
        o[3] = (uint)f2bu(a3.x) | ((uint)f2bu(a3.y) << 16);
        *reinterpret_cast<u32x4*>(attnout + (size_t)t * 256 + h * 32 + dl * 8) = o;
    }
}

// ---------------------------------------------------------------------------
// LayerNorm(a + b): wave per row, thread handles 4 cols, shuffle reduction,
// 4 rows/block. b always bf16. AF32: a f32 vs bf16. OUTF32: f32 vs bf16 out.
// ---------------------------------------------------------------------------
template<bool AF32, bool OUTF32>
__global__ __launch_bounds__(256) void ln_add2(
    const void* __restrict__ aptr, const ushort* __restrict__ bptr,
    const float* __restrict__ w, const float* __restrict__ bias,
    void* __restrict__ outp, int nrows)
{
    const int lane = threadIdx.x & 63, wv = threadIdx.x >> 6;
    const int row = blockIdx.x * 4 + wv;
    if (row >= nrows) return;
    const size_t base = (size_t)row * 256 + lane * 4;

    float4 av;
    if (AF32) {
        av = *reinterpret_cast<const float4*>((const float*)aptr + base);
    } else {
        const ushort4 u = *reinterpret_cast<const ushort4*>((const ushort*)aptr + base);
        av = make_float4(bu2f(u.x), bu2f(u.y), bu2f(u.z), bu2f(u.w));
    }
    const ushort4 ub = *reinterpret_cast<const ushort4*>(bptr + base);
    const float v0 = av.x + bu2f(ub.x), v1 = av.y + bu2f(ub.y);
    const float v2 = av.z + bu2f(ub.z), v3 = av.w + bu2f(ub.w);

    float s = v0 + v1 + v2 + v3;
    #pragma unroll
    for (int o = 32; o; o >>= 1) s += __shfl_xor(s, o);
    const float mu = s * (1.f / 256.f);
    const float d0 = v0 - mu, d1 = v1 - mu, d2 = v2 - mu, d3 = v3 - mu;
    float s2 = d0 * d0 + d1 * d1 + d2 * d2 + d3 * d3;
    #pragma unroll
    for (int o = 32; o; o >>= 1) s2 += __shfl_xor(s2, o);
    const float rs = rsqrtf(s2 * (1.f / 256.f) + 1e-5f);

    const float4 w4 = *reinterpret_cast<const float4*>(w + lane * 4);
    const float4 g4 = *reinterpret_cast<const float4*>(bias + lane * 4);
    const float r0 = d0 * rs * w4.x + g4.x;
    const float r1 = d1 * rs * w4.y + g4.y;
    const float r2 = d2 * rs * w4.z + g4.z;
    const float r3 = d3 * rs * w4.w + g4.w;
    if (OUTF32) {
        *reinterpret_cast<float4*>((float*)outp + base) = make_float4(r0, r1, r2, r3);
    } else {
        ushort4 u;
        u.x = f2bu(r0); u.y = f2bu(r1); u.z = f2bu(r2); u.w = f2bu(r3);
        *reinterpret_cast<ushort4*>((ushort*)outp + base) = u;
    }
}

// ---------------------------------------------------------------------------
extern "C" void kernel_launch(void* const* d_in, const int* in_sizes, int n_in,
                              void* d_out, int out_size, void* d_ws, size_t ws_size,
                              hipStream_t stream)
{
    const float* src     = (const float*)d_in[0];
    const float* pos     = (const float*)d_in[1];
    const float* vratio  = (const float*)d_in[5];
    const float* refw    = (const float*)d_in[6];
    const float* value_w = (const float*)d_in[7];
    const float* value_b = (const float*)d_in[8];
    const float* out_w   = (const float*)d_in[9];
    const float* out_b   = (const float*)d_in[10];
    const float* box_w   = (const float*)d_in[11];
    const float* box_b   = (const float*)d_in[12];
    const float* attn_w  = (const float*)d_in[13];
    const float* attn_b  = (const float*)d_in[14];
    const float* lin1_w  = (const float*)d_in[15];
    const float* lin1_b  = (const float*)d_in[16];
    const float* lin2_w  = (const float*)d_in[17];
    const float* lin2_b  = (const float*)d_in[18];
    const float* n1w     = (const float*)d_in[19];
    const float* n1b     = (const float*)d_in[20];
    const float* n2w     = (const float*)d_in[21];
    const float* n2b     = (const float*)d_in[22];

    // flat workspace layout (~140 MB of 256 MiB)
    char* wsb = (char*)d_ws;
    ushort* Wb    = (ushort*)(wsb);                  // 1,441,792 B
    float*  qcb   = (float*)(wsb + 1441792);         // 1 KB
    ushort* srcb  = (ushort*)(wsb + 1442816);        // 11.5 MB bf16 src
    ushort* qb    = (ushort*)(wsb + 12965888);       // 11.5 MB bf16 src+pos
    unsigned char* valb = (unsigned char*)(wsb + 24488960);  // 5.76 MB fp8 value
    ushort* qoutb = (ushort*)(wsb + 36012032);       // 11.5 MB off+logits
    ushort* attb  = (ushort*)(wsb + 47535104);       // 11.5 MB attn out
    ushort* src2b = (ushort*)(wsb + 59058176);       // 11.5 MB src2 bf16
    ushort* xbb   = (ushort*)(wsb + 70581248);       // 11.5 MB x bf16
    ushort* hb    = (ushort*)(wsb + 82104320);       // 46.1 MB hidden
    ushort* yb    = (ushort*)(wsb + 128196608);      // 11.5 MB y bf16

    const dim3 blk(256);

    // one-time prep (weights + input cvt) in a single launch
    prep_all<<<dim3(8444), blk, 0, stream>>>(
        value_w, box_w, attn_w, out_w, lin1_w, lin2_w, box_b, attn_b, Wb, qcb,
        (const float4*)src, (const float4*)pos, (ushort4*)srcb, (ushort4*)qb);

    // merged: z=0 value(fp8) = src @ value_w^T ; z=1 qout = q @ [box;attn]^T
    gemm_small<false, false, true><<<dim3(352, 2, 2), blk, 0, stream>>>(
        srcb, Wb, value_b, valb,
        qb, Wb + 65536, qcb, qoutb, TOKENS, 256, 256);

    // fused prep + gather (8 tokens/block, fp8 value)
    box_fused<<<dim3((TOKENS + 7) / 8), blk, 0, stream>>>(
        valb, qoutb, refw, vratio, attb);

    // src2 = attnout @ out_w^T + b -> bf16
    gemm_small<false, false, false><<<dim3(352, 2, 1), blk, 0, stream>>>(
        attb, Wb + 131072, out_b, src2b,
        attb, Wb + 131072, out_b, src2b, TOKENS, 256, 256);
    // x = LN1(src + src2) -> bf16
    ln_add2<true, false><<<dim3((TOKENS + 3) / 4), blk, 0, stream>>>(
        src, src2b, n1w, n1b, xbb, TOKENS);
    // h = relu(x @ lin1_w^T + b) -> bf16 (64x128 tiles, NT C stores)
    gemm_small<true, true, false><<<dim3(352, 8, 1), blk, 0, stream>>>(
        xbb, Wb + 196608, lin1_b, hb,
        xbb, Wb + 196608, lin1_b, hb, TOKENS, 1024, 256);
    // y = h @ lin2_w^T + b -> bf16
    gemm_small<false, false, false><<<dim3(352, 2, 1), blk, 0, stream>>>(
        hb, Wb + 458752, lin2_b, yb,
        hb, Wb + 458752, lin2_b, yb, TOKENS, 256, 1024);
    // out = LN2(x + y) -> f32
    ln_add2<false, true><<<dim3((TOKENS + 3) / 4), blk, 0, stream>>>(
        xbb, yb, n2w, n2b, (float*)d_out, TOKENS);
}